// Round 1
// baseline (1453.788 us; speedup 1.0000x reference)
//
#include <hip/hip_runtime.h>
#include <math.h>

// ---------------------------------------------------------------------------
// ImprovedCrossBorderGNN: 3-layer edge-conditioned GAT, N=50000, E=1.6M, H=128
// Strategy: build CSR (dst-grouped) once per launch, reuse for 3 layers.
// Per layer: fp32 GEMM g = h@W with fused a_src/a_dst epilogue, then a
// wave-per-node online-softmax gather (no fp32 atomics anywhere in aggregation).
// ---------------------------------------------------------------------------

#define H 128
#define NF 8

__device__ __forceinline__ float wred_sum(float x) {
#pragma unroll
    for (int m = 32; m >= 1; m >>= 1) x += __shfl_xor(x, m, 64);
    return x;
}
__device__ __forceinline__ float wred_max(float x) {
#pragma unroll
    for (int m = 32; m >= 1; m >>= 1) x = fmaxf(x, __shfl_xor(x, m, 64));
    return x;
}

// ---- CSR build -------------------------------------------------------------

// degree count (into cursor[]) + edge_attr column-mean partial sums
__global__ void k_edge_count_mean(const int* __restrict__ ei, const float* __restrict__ ea,
                                  int E, int* __restrict__ deg, float* __restrict__ meanacc) {
    int e = blockIdx.x * 256 + threadIdx.x;
    float px = 0.f, py = 0.f;
    if (e < E) {
        int d = ei[E + e];
        atomicAdd(&deg[d], 1);
        const float2 z = *(const float2*)(ea + 2 * (size_t)e);
        px = z.x; py = z.y;
    }
    px = wred_sum(px); py = wred_sum(py);
    if ((threadIdx.x & 63) == 0) {
        atomicAdd(&meanacc[0], px);
        atomicAdd(&meanacc[1], py);
    }
}

__global__ void k_scan1(const int* __restrict__ deg, int* __restrict__ rowptr,
                        int* __restrict__ bsum, int n) {
    __shared__ int tmp[512];
    int t = threadIdx.x;
    int i = blockIdx.x * 512 + t;
    int v = (i < n) ? deg[i] : 0;
    tmp[t] = v;
    __syncthreads();
    for (int off = 1; off < 512; off <<= 1) {
        int q = (t >= off) ? tmp[t - off] : 0;
        __syncthreads();
        tmp[t] += q;
        __syncthreads();
    }
    if (i < n) rowptr[i] = tmp[t] - v;  // exclusive scan (block-local)
    if (t == 511) bsum[blockIdx.x] = tmp[511];
}

__global__ void k_scan2(const int* __restrict__ bsum, int* __restrict__ boff, int nb) {
    if (threadIdx.x == 0 && blockIdx.x == 0) {
        int run = 0;
        for (int b = 0; b < nb; ++b) { boff[b] = run; run += bsum[b]; }
    }
}

__global__ void k_scan3(int* __restrict__ rowptr, const int* __restrict__ boff,
                        int* __restrict__ cursor, int n, int E) {
    int t = threadIdx.x;
    int i = blockIdx.x * 512 + t;
    if (i < n) {
        int r = rowptr[i] + boff[blockIdx.x];
        rowptr[i] = r;
        cursor[i] = r;
    }
    if (i == 0) rowptr[n] = E;
}

__global__ void k_scatter(const int* __restrict__ ei, const float* __restrict__ ea, int E,
                          int* __restrict__ cursor, int* __restrict__ srcs,
                          float2* __restrict__ eattr) {
    int e = blockIdx.x * 256 + threadIdx.x;
    if (e >= E) return;
    int s = ei[e];
    int d = ei[E + e];
    int p = atomicAdd(&cursor[d], 1);
    srcs[p] = s;
    eattr[p] = *(const float2*)(ea + 2 * (size_t)e);
}

// ---- per-layer scalar setup: c_l = We_l @ ae_l (length-2), self-loop term --
__global__ void k_setup(const float* __restrict__ We1, const float* __restrict__ ae1,
                        const float* __restrict__ We2, const float* __restrict__ ae2,
                        const float* __restrict__ We3, const float* __restrict__ ae3,
                        const float* __restrict__ meanacc, float invE,
                        float* __restrict__ park) {
    int l = blockIdx.x;
    int t = threadIdx.x;  // 64 threads
    const float* We = (l == 0) ? We1 : ((l == 1) ? We2 : We3);
    const float* ae = (l == 0) ? ae1 : ((l == 1) ? ae2 : ae3);
    float p0 = We[t] * ae[t] + We[t + 64] * ae[t + 64];
    float p1 = We[H + t] * ae[t] + We[H + t + 64] * ae[t + 64];
    float c0 = wred_sum(p0);
    float c1 = wred_sum(p1);
    if (t == 0) {
        float m0 = meanacc[0] * invE;
        float m1 = meanacc[1] * invE;
        park[l * 3 + 0] = c0;
        park[l * 3 + 1] = c1;
        park[l * 3 + 2] = m0 * c0 + m1 * c1;  // self-loop edge-attention scalar
    }
}

// ---- encoder: h0 = relu((x @ enc_W + b) * bn_g*inv + bn_b) -----------------
__global__ void k_encoder(const float* __restrict__ x, const float* __restrict__ encW,
                          const float* __restrict__ encb, const float* __restrict__ bng,
                          const float* __restrict__ bnb, float* __restrict__ h0, int N) {
    __shared__ float xs[8 * NF];
    int tid = threadIdx.x;
    int nb = blockIdx.x * 8;
    if (tid < 64) {
        size_t idx = (size_t)nb * NF + tid;
        xs[tid] = (idx < (size_t)N * NF) ? x[idx] : 0.f;
    }
    __syncthreads();
    int jt = tid & 31, i = tid >> 5;
    int node = nb + i;
    int j4 = jt * 4;
    float ax = 0.f, ay = 0.f, az = 0.f, aw = 0.f;
#pragma unroll
    for (int k = 0; k < NF; ++k) {
        float hx = xs[i * NF + k];
        const float4 w = *(const float4*)(encW + k * H + j4);
        ax = fmaf(hx, w.x, ax); ay = fmaf(hx, w.y, ay);
        az = fmaf(hx, w.z, az); aw = fmaf(hx, w.w, aw);
    }
    if (node < N) {
        const float inv = 0.9999950000374997f;  // 1/sqrt(1+1e-5)
        const float4 eb = *(const float4*)(encb + j4);
        const float4 gg = *(const float4*)(bng + j4);
        const float4 bb = *(const float4*)(bnb + j4);
        float4 o;
        o.x = fmaxf(0.f, (ax + eb.x) * (gg.x * inv) + bb.x);
        o.y = fmaxf(0.f, (ay + eb.y) * (gg.y * inv) + bb.y);
        o.z = fmaxf(0.f, (az + eb.z) * (gg.z * inv) + bb.z);
        o.w = fmaxf(0.f, (aw + eb.w) * (gg.w * inv) + bb.w);
        *(float4*)(h0 + (size_t)node * H + j4) = o;
    }
}

// ---- per-layer GEMM: g = h @ W, fused a_src/a_dst epilogue ----------------
__global__ void k_gemm(const float* __restrict__ h, const float* __restrict__ W,
                       const float* __restrict__ avs, const float* __restrict__ avd,
                       float* __restrict__ g, float* __restrict__ a_src,
                       float* __restrict__ a_dst, int N) {
    __shared__ float hs[8 * H];
    int tid = threadIdx.x;
    int nb = blockIdx.x * 8;
    {
        int r = tid >> 5, c4 = (tid & 31) * 4;
        int node = nb + r;
        float4 v = make_float4(0.f, 0.f, 0.f, 0.f);
        if (node < N) v = *(const float4*)(h + (size_t)node * H + c4);
        *(float4*)(hs + r * H + c4) = v;
    }
    __syncthreads();
    int jt = tid & 31, i = tid >> 5;
    int node = nb + i;
    int j4 = jt * 4;
    float ax = 0.f, ay = 0.f, az = 0.f, aw = 0.f;
    for (int k = 0; k < H; k += 4) {
        const float4 hv = *(const float4*)(hs + i * H + k);
        const float4 w0 = *(const float4*)(W + (k + 0) * H + j4);
        const float4 w1 = *(const float4*)(W + (k + 1) * H + j4);
        const float4 w2 = *(const float4*)(W + (k + 2) * H + j4);
        const float4 w3 = *(const float4*)(W + (k + 3) * H + j4);
        ax = fmaf(hv.x, w0.x, ax); ay = fmaf(hv.x, w0.y, ay);
        az = fmaf(hv.x, w0.z, az); aw = fmaf(hv.x, w0.w, aw);
        ax = fmaf(hv.y, w1.x, ax); ay = fmaf(hv.y, w1.y, ay);
        az = fmaf(hv.y, w1.z, az); aw = fmaf(hv.y, w1.w, aw);
        ax = fmaf(hv.z, w2.x, ax); ay = fmaf(hv.z, w2.y, ay);
        az = fmaf(hv.z, w2.z, az); aw = fmaf(hv.z, w2.w, aw);
        ax = fmaf(hv.w, w3.x, ax); ay = fmaf(hv.w, w3.y, ay);
        az = fmaf(hv.w, w3.z, az); aw = fmaf(hv.w, w3.w, aw);
    }
    // epilogue: store g row slice + reduce attention dots within the 32-lane group
    const float4 s4 = *(const float4*)(avs + j4);
    const float4 d4 = *(const float4*)(avd + j4);
    float ps = ax * s4.x + ay * s4.y + az * s4.z + aw * s4.w;
    float pd = ax * d4.x + ay * d4.y + az * d4.z + aw * d4.w;
#pragma unroll
    for (int mm = 16; mm >= 1; mm >>= 1) {
        ps += __shfl_xor(ps, mm, 64);
        pd += __shfl_xor(pd, mm, 64);
    }
    if (node < N) {
        float4 o = make_float4(ax, ay, az, aw);
        *(float4*)(g + (size_t)node * H + j4) = o;
        if (jt == 0) {
            a_src[node] = ps;
            a_dst[node] = pd;
        }
    }
}

// ---- aggregation: wave per node, online softmax, unnormalized gather ------
template <int RELU, int ADDH0>
__global__ void k_agg(const float* __restrict__ g, const float* __restrict__ a_src,
                      const float* __restrict__ a_dst, const int* __restrict__ rowptr,
                      const int* __restrict__ srcs, const float2* __restrict__ eattr,
                      const float* __restrict__ park, int layer,
                      const float* __restrict__ bias, const float* __restrict__ h0,
                      float* __restrict__ out, int N) {
    int wv = threadIdx.x >> 6;
    int lane = threadIdx.x & 63;
    int v = blockIdx.x * 4 + wv;
    if (v >= N) return;

    const float c0 = park[layer * 3 + 0];
    const float c1 = park[layer * 3 + 1];
    const float sa = park[layer * 3 + 2];

    const float adv = a_dst[v];
    float lself = a_src[v] + adv + sa;
    lself = (lself > 0.f) ? lself : 0.2f * lself;

    float m = lself;   // running max (self-loop included)
    float s = 1.f;     // running sum, w_self = exp(0) = 1
    const int ch = lane * 2;
    const float2 gv = *(const float2*)(g + (size_t)v * H + ch);
    float acc0 = gv.x, acc1 = gv.y;  // self-loop contribution, weight 1

    const int rs = rowptr[v];
    const int re = rowptr[v + 1];
    for (int p0 = rs; p0 < re; p0 += 64) {
        int e = p0 + lane;
        bool val = e < re;
        int sv = val ? srcs[e] : 0;
        float lg;
        if (val) {
            const float2 ez = eattr[e];
            lg = a_src[sv] + adv + c0 * ez.x + c1 * ez.y;
            lg = (lg > 0.f) ? lg : 0.2f * lg;
        } else {
            lg = -INFINITY;
        }
        float cm = wred_max(lg);
        float nm = fmaxf(m, cm);
        float f = __expf(m - nm);
        float w = val ? __expf(lg - nm) : 0.f;
        float ws = wred_sum(w);
        s = s * f + ws;
        acc0 *= f;
        acc1 *= f;
        m = nm;
        int cnt = re - p0;
        if (cnt > 64) cnt = 64;
        for (int j = 0; j < cnt; ++j) {
            float wj = __int_as_float(__builtin_amdgcn_readlane(__float_as_int(w), j));
            int sj = __builtin_amdgcn_readlane(sv, j);
            const float2 gz = *(const float2*)(g + (size_t)sj * H + ch);
            acc0 = fmaf(wj, gz.x, acc0);
            acc1 = fmaf(wj, gz.y, acc1);
        }
    }
    const float is = 1.f / s;
    const float2 bz = *(const float2*)(bias + ch);
    float o0 = acc0 * is + bz.x;
    float o1 = acc1 * is + bz.y;
    if (ADDH0) {
        const float2 hz = *(const float2*)(h0 + (size_t)v * H + ch);
        o0 += hz.x;
        o1 += hz.y;
    }
    if (RELU) {
        o0 = fmaxf(o0, 0.f);
        o1 = fmaxf(o1, 0.f);
    }
    *(float2*)(out + (size_t)v * H + ch) = make_float2(o0, o1);
}

// ---------------------------------------------------------------------------

extern "C" void kernel_launch(void* const* d_in, const int* in_sizes, int n_in,
                              void* d_out, int out_size, void* d_ws, size_t ws_size,
                              hipStream_t stream) {
    const float* x    = (const float*)d_in[0];
    const int*   ei   = (const int*)d_in[1];
    const float* ea   = (const float*)d_in[2];
    const float* encW = (const float*)d_in[3];
    const float* encb = (const float*)d_in[4];
    const float* bng  = (const float*)d_in[5];
    const float* bnb  = (const float*)d_in[6];
    const float *W[3], *asrc[3], *adst[3], *We[3], *aev[3], *bias[3];
    for (int l = 0; l < 3; ++l) {
        W[l]    = (const float*)d_in[7 + l * 6 + 0];
        asrc[l] = (const float*)d_in[7 + l * 6 + 1];
        adst[l] = (const float*)d_in[7 + l * 6 + 2];
        We[l]   = (const float*)d_in[7 + l * 6 + 3];
        aev[l]  = (const float*)d_in[7 + l * 6 + 4];
        bias[l] = (const float*)d_in[7 + l * 6 + 5];
    }
    const int N = in_sizes[0] / NF;
    const int E = in_sizes[1] / 2;
    float* out = (float*)d_out;

    // workspace carve-up (256B aligned)
    char* wp = (char*)d_ws;
    auto alloc = [&](size_t bytes) -> char* {
        char* p = wp;
        wp += (bytes + 255) & ~(size_t)255;
        return p;
    };
    float* h0     = (float*)alloc((size_t)N * H * 4);
    float* hA     = (float*)alloc((size_t)N * H * 4);
    float* g      = (float*)alloc((size_t)N * H * 4);
    float* a_src  = (float*)alloc((size_t)N * 4);
    float* a_dst  = (float*)alloc((size_t)N * 4);
    int*   rowptr = (int*)alloc((size_t)(N + 1) * 4);
    int*   cursor = (int*)alloc((size_t)N * 4 + 8);  // cursor + meanacc contiguous (zeroed together)
    float* meanacc = (float*)(cursor + N);
    float* park   = (float*)alloc(64);
    int*   bsum   = (int*)alloc(512);
    int*   boff   = (int*)alloc(512);
    int*   srcs   = (int*)alloc((size_t)E * 4);
    float2* eattr = (float2*)alloc((size_t)E * 8);

    hipMemsetAsync(cursor, 0, (size_t)N * 4 + 8, stream);

    const int EB = (E + 255) / 256;
    const int NB512 = (N + 511) / 512;
    k_edge_count_mean<<<EB, 256, 0, stream>>>(ei, ea, E, cursor, meanacc);
    k_scan1<<<NB512, 512, 0, stream>>>(cursor, rowptr, bsum, N);
    k_scan2<<<1, 64, 0, stream>>>(bsum, boff, NB512);
    k_scan3<<<NB512, 512, 0, stream>>>(rowptr, boff, cursor, N, E);
    k_scatter<<<EB, 256, 0, stream>>>(ei, ea, E, cursor, srcs, eattr);
    k_setup<<<3, 64, 0, stream>>>(We[0], aev[0], We[1], aev[1], We[2], aev[2],
                                  meanacc, 1.0f / (float)E, park);

    const int GB = (N + 7) / 8;
    const int AB = (N + 3) / 4;
    k_encoder<<<GB, 256, 0, stream>>>(x, encW, encb, bng, bnb, h0, N);

    // layer 1: h0 -> hA
    k_gemm<<<GB, 256, 0, stream>>>(h0, W[0], asrc[0], adst[0], g, a_src, a_dst, N);
    k_agg<1, 0><<<AB, 256, 0, stream>>>(g, a_src, a_dst, rowptr, srcs, eattr, park, 0,
                                        bias[0], nullptr, hA, N);
    // layer 2: hA -> hA
    k_gemm<<<GB, 256, 0, stream>>>(hA, W[1], asrc[1], adst[1], g, a_src, a_dst, N);
    k_agg<1, 0><<<AB, 256, 0, stream>>>(g, a_src, a_dst, rowptr, srcs, eattr, park, 1,
                                        bias[1], nullptr, hA, N);
    // layer 3: hA -> out (+h0, no relu)
    k_gemm<<<GB, 256, 0, stream>>>(hA, W[2], asrc[2], adst[2], g, a_src, a_dst, N);
    k_agg<0, 1><<<AB, 256, 0, stream>>>(g, a_src, a_dst, rowptr, srcs, eattr, park, 2,
                                        bias[2], h0, out, N);
}

// Round 2
// 869.019 us; speedup vs baseline: 1.6729x; 1.6729x over previous
//
#include <hip/hip_runtime.h>
#include <math.h>

// ---------------------------------------------------------------------------
// ImprovedCrossBorderGNN: 3-layer edge-conditioned GAT, N=50000, E=1.6M, H=128
// Strategy: build CSR (dst-grouped) once per launch, reuse for 3 layers.
// Per layer: fp32 GEMM g = h@W with fused a_src/a_dst epilogue, then a
// wave-per-node online-softmax gather (no fp32 atomics anywhere in aggregation).
// R1 fix: edge_attr mean via two-stage partial-sum reduction (the per-wave
// fp32 atomicAdd to a single address was a 644us serialized hot-spot chain).
// ---------------------------------------------------------------------------

#define H 128
#define NF 8

__device__ __forceinline__ float wred_sum(float x) {
#pragma unroll
    for (int m = 32; m >= 1; m >>= 1) x += __shfl_xor(x, m, 64);
    return x;
}
__device__ __forceinline__ float wred_max(float x) {
#pragma unroll
    for (int m = 32; m >= 1; m >>= 1) x = fmaxf(x, __shfl_xor(x, m, 64));
    return x;
}

// ---- CSR build -------------------------------------------------------------

// degree count (into deg[]) + edge_attr column-mean per-block partials
__global__ void k_edge_count_mean(const int* __restrict__ ei, const float* __restrict__ ea,
                                  int E, int* __restrict__ deg, float2* __restrict__ pmean) {
    __shared__ float sx[4], sy[4];
    int e = blockIdx.x * 256 + threadIdx.x;
    float px = 0.f, py = 0.f;
    if (e < E) {
        int d = ei[E + e];
        atomicAdd(&deg[d], 1);
        const float2 z = *(const float2*)(ea + 2 * (size_t)e);
        px = z.x; py = z.y;
    }
    px = wred_sum(px); py = wred_sum(py);
    int w = threadIdx.x >> 6;
    if ((threadIdx.x & 63) == 0) { sx[w] = px; sy[w] = py; }
    __syncthreads();
    if (threadIdx.x == 0) {
        pmean[blockIdx.x] = make_float2(sx[0] + sx[1] + sx[2] + sx[3],
                                        sy[0] + sy[1] + sy[2] + sy[3]);
    }
}

// single-block reduce of per-block partials -> meanacc[0..1]
__global__ void k_reduce_mean(const float2* __restrict__ pmean, int nb,
                              float* __restrict__ meanacc) {
    __shared__ float sx[16], sy[16];
    float px = 0.f, py = 0.f;
    for (int i = threadIdx.x; i < nb; i += 1024) {
        float2 z = pmean[i];
        px += z.x; py += z.y;
    }
    px = wred_sum(px); py = wred_sum(py);
    int w = threadIdx.x >> 6;
    if ((threadIdx.x & 63) == 0) { sx[w] = px; sy[w] = py; }
    __syncthreads();
    if (threadIdx.x == 0) {
        float tx = 0.f, ty = 0.f;
#pragma unroll
        for (int i = 0; i < 16; ++i) { tx += sx[i]; ty += sy[i]; }
        meanacc[0] = tx;
        meanacc[1] = ty;
    }
}

__global__ void k_scan1(const int* __restrict__ deg, int* __restrict__ rowptr,
                        int* __restrict__ bsum, int n) {
    __shared__ int tmp[512];
    int t = threadIdx.x;
    int i = blockIdx.x * 512 + t;
    int v = (i < n) ? deg[i] : 0;
    tmp[t] = v;
    __syncthreads();
    for (int off = 1; off < 512; off <<= 1) {
        int q = (t >= off) ? tmp[t - off] : 0;
        __syncthreads();
        tmp[t] += q;
        __syncthreads();
    }
    if (i < n) rowptr[i] = tmp[t] - v;  // exclusive scan (block-local)
    if (t == 511) bsum[blockIdx.x] = tmp[511];
}

__global__ void k_scan2(const int* __restrict__ bsum, int* __restrict__ boff, int nb) {
    if (threadIdx.x == 0 && blockIdx.x == 0) {
        int run = 0;
        for (int b = 0; b < nb; ++b) { boff[b] = run; run += bsum[b]; }
    }
}

__global__ void k_scan3(int* __restrict__ rowptr, const int* __restrict__ boff,
                        int* __restrict__ cursor, int n, int E) {
    int t = threadIdx.x;
    int i = blockIdx.x * 512 + t;
    if (i < n) {
        int r = rowptr[i] + boff[blockIdx.x];
        rowptr[i] = r;
        cursor[i] = r;
    }
    if (i == 0) rowptr[n] = E;
}

__global__ void k_scatter(const int* __restrict__ ei, const float* __restrict__ ea, int E,
                          int* __restrict__ cursor, int* __restrict__ srcs,
                          float2* __restrict__ eattr) {
    int e = blockIdx.x * 256 + threadIdx.x;
    if (e >= E) return;
    int s = ei[e];
    int d = ei[E + e];
    int p = atomicAdd(&cursor[d], 1);
    srcs[p] = s;
    eattr[p] = *(const float2*)(ea + 2 * (size_t)e);
}

// ---- per-layer scalar setup: c_l = We_l @ ae_l (length-2), self-loop term --
__global__ void k_setup(const float* __restrict__ We1, const float* __restrict__ ae1,
                        const float* __restrict__ We2, const float* __restrict__ ae2,
                        const float* __restrict__ We3, const float* __restrict__ ae3,
                        const float* __restrict__ meanacc, float invE,
                        float* __restrict__ park) {
    int l = blockIdx.x;
    int t = threadIdx.x;  // 64 threads
    const float* We = (l == 0) ? We1 : ((l == 1) ? We2 : We3);
    const float* ae = (l == 0) ? ae1 : ((l == 1) ? ae2 : ae3);
    float p0 = We[t] * ae[t] + We[t + 64] * ae[t + 64];
    float p1 = We[H + t] * ae[t] + We[H + t + 64] * ae[t + 64];
    float c0 = wred_sum(p0);
    float c1 = wred_sum(p1);
    if (t == 0) {
        float m0 = meanacc[0] * invE;
        float m1 = meanacc[1] * invE;
        park[l * 3 + 0] = c0;
        park[l * 3 + 1] = c1;
        park[l * 3 + 2] = m0 * c0 + m1 * c1;  // self-loop edge-attention scalar
    }
}

// ---- encoder: h0 = relu((x @ enc_W + b) * bn_g*inv + bn_b) -----------------
__global__ void k_encoder(const float* __restrict__ x, const float* __restrict__ encW,
                          const float* __restrict__ encb, const float* __restrict__ bng,
                          const float* __restrict__ bnb, float* __restrict__ h0, int N) {
    __shared__ float xs[8 * NF];
    int tid = threadIdx.x;
    int nb = blockIdx.x * 8;
    if (tid < 64) {
        size_t idx = (size_t)nb * NF + tid;
        xs[tid] = (idx < (size_t)N * NF) ? x[idx] : 0.f;
    }
    __syncthreads();
    int jt = tid & 31, i = tid >> 5;
    int node = nb + i;
    int j4 = jt * 4;
    float ax = 0.f, ay = 0.f, az = 0.f, aw = 0.f;
#pragma unroll
    for (int k = 0; k < NF; ++k) {
        float hx = xs[i * NF + k];
        const float4 w = *(const float4*)(encW + k * H + j4);
        ax = fmaf(hx, w.x, ax); ay = fmaf(hx, w.y, ay);
        az = fmaf(hx, w.z, az); aw = fmaf(hx, w.w, aw);
    }
    if (node < N) {
        const float inv = 0.9999950000374997f;  // 1/sqrt(1+1e-5)
        const float4 eb = *(const float4*)(encb + j4);
        const float4 gg = *(const float4*)(bng + j4);
        const float4 bb = *(const float4*)(bnb + j4);
        float4 o;
        o.x = fmaxf(0.f, (ax + eb.x) * (gg.x * inv) + bb.x);
        o.y = fmaxf(0.f, (ay + eb.y) * (gg.y * inv) + bb.y);
        o.z = fmaxf(0.f, (az + eb.z) * (gg.z * inv) + bb.z);
        o.w = fmaxf(0.f, (aw + eb.w) * (gg.w * inv) + bb.w);
        *(float4*)(h0 + (size_t)node * H + j4) = o;
    }
}

// ---- per-layer GEMM: g = h @ W, fused a_src/a_dst epilogue ----------------
__global__ void k_gemm(const float* __restrict__ h, const float* __restrict__ W,
                       const float* __restrict__ avs, const float* __restrict__ avd,
                       float* __restrict__ g, float* __restrict__ a_src,
                       float* __restrict__ a_dst, int N) {
    __shared__ float hs[8 * H];
    int tid = threadIdx.x;
    int nb = blockIdx.x * 8;
    {
        int r = tid >> 5, c4 = (tid & 31) * 4;
        int node = nb + r;
        float4 v = make_float4(0.f, 0.f, 0.f, 0.f);
        if (node < N) v = *(const float4*)(h + (size_t)node * H + c4);
        *(float4*)(hs + r * H + c4) = v;
    }
    __syncthreads();
    int jt = tid & 31, i = tid >> 5;
    int node = nb + i;
    int j4 = jt * 4;
    float ax = 0.f, ay = 0.f, az = 0.f, aw = 0.f;
    for (int k = 0; k < H; k += 4) {
        const float4 hv = *(const float4*)(hs + i * H + k);
        const float4 w0 = *(const float4*)(W + (k + 0) * H + j4);
        const float4 w1 = *(const float4*)(W + (k + 1) * H + j4);
        const float4 w2 = *(const float4*)(W + (k + 2) * H + j4);
        const float4 w3 = *(const float4*)(W + (k + 3) * H + j4);
        ax = fmaf(hv.x, w0.x, ax); ay = fmaf(hv.x, w0.y, ay);
        az = fmaf(hv.x, w0.z, az); aw = fmaf(hv.x, w0.w, aw);
        ax = fmaf(hv.y, w1.x, ax); ay = fmaf(hv.y, w1.y, ay);
        az = fmaf(hv.y, w1.z, az); aw = fmaf(hv.y, w1.w, aw);
        ax = fmaf(hv.z, w2.x, ax); ay = fmaf(hv.z, w2.y, ay);
        az = fmaf(hv.z, w2.z, az); aw = fmaf(hv.z, w2.w, aw);
        ax = fmaf(hv.w, w3.x, ax); ay = fmaf(hv.w, w3.y, ay);
        az = fmaf(hv.w, w3.z, az); aw = fmaf(hv.w, w3.w, aw);
    }
    // epilogue: store g row slice + reduce attention dots within the 32-lane group
    const float4 s4 = *(const float4*)(avs + j4);
    const float4 d4 = *(const float4*)(avd + j4);
    float ps = ax * s4.x + ay * s4.y + az * s4.z + aw * s4.w;
    float pd = ax * d4.x + ay * d4.y + az * d4.z + aw * d4.w;
#pragma unroll
    for (int mm = 16; mm >= 1; mm >>= 1) {
        ps += __shfl_xor(ps, mm, 64);
        pd += __shfl_xor(pd, mm, 64);
    }
    if (node < N) {
        float4 o = make_float4(ax, ay, az, aw);
        *(float4*)(g + (size_t)node * H + j4) = o;
        if (jt == 0) {
            a_src[node] = ps;
            a_dst[node] = pd;
        }
    }
}

// ---- aggregation: wave per node, online softmax, unnormalized gather ------
template <int RELU, int ADDH0>
__global__ void k_agg(const float* __restrict__ g, const float* __restrict__ a_src,
                      const float* __restrict__ a_dst, const int* __restrict__ rowptr,
                      const int* __restrict__ srcs, const float2* __restrict__ eattr,
                      const float* __restrict__ park, int layer,
                      const float* __restrict__ bias, const float* __restrict__ h0,
                      float* __restrict__ out, int N) {
    int wv = threadIdx.x >> 6;
    int lane = threadIdx.x & 63;
    int v = blockIdx.x * 4 + wv;
    if (v >= N) return;

    const float c0 = park[layer * 3 + 0];
    const float c1 = park[layer * 3 + 1];
    const float sa = park[layer * 3 + 2];

    const float adv = a_dst[v];
    float lself = a_src[v] + adv + sa;
    lself = (lself > 0.f) ? lself : 0.2f * lself;

    float m = lself;   // running max (self-loop included)
    float s = 1.f;     // running sum, w_self = exp(0) = 1
    const int ch = lane * 2;
    const float2 gv = *(const float2*)(g + (size_t)v * H + ch);
    float acc0 = gv.x, acc1 = gv.y;  // self-loop contribution, weight 1

    const int rs = rowptr[v];
    const int re = rowptr[v + 1];
    for (int p0 = rs; p0 < re; p0 += 64) {
        int e = p0 + lane;
        bool val = e < re;
        int sv = val ? srcs[e] : 0;
        float lg;
        if (val) {
            const float2 ez = eattr[e];
            lg = a_src[sv] + adv + c0 * ez.x + c1 * ez.y;
            lg = (lg > 0.f) ? lg : 0.2f * lg;
        } else {
            lg = -INFINITY;
        }
        float cm = wred_max(lg);
        float nm = fmaxf(m, cm);
        float f = __expf(m - nm);
        float w = val ? __expf(lg - nm) : 0.f;
        float ws = wred_sum(w);
        s = s * f + ws;
        acc0 *= f;
        acc1 *= f;
        m = nm;
        int cnt = re - p0;
        if (cnt > 64) cnt = 64;
        for (int j = 0; j < cnt; ++j) {
            float wj = __int_as_float(__builtin_amdgcn_readlane(__float_as_int(w), j));
            int sj = __builtin_amdgcn_readlane(sv, j);
            const float2 gz = *(const float2*)(g + (size_t)sj * H + ch);
            acc0 = fmaf(wj, gz.x, acc0);
            acc1 = fmaf(wj, gz.y, acc1);
        }
    }
    const float is = 1.f / s;
    const float2 bz = *(const float2*)(bias + ch);
    float o0 = acc0 * is + bz.x;
    float o1 = acc1 * is + bz.y;
    if (ADDH0) {
        const float2 hz = *(const float2*)(h0 + (size_t)v * H + ch);
        o0 += hz.x;
        o1 += hz.y;
    }
    if (RELU) {
        o0 = fmaxf(o0, 0.f);
        o1 = fmaxf(o1, 0.f);
    }
    *(float2*)(out + (size_t)v * H + ch) = make_float2(o0, o1);
}

// ---------------------------------------------------------------------------

extern "C" void kernel_launch(void* const* d_in, const int* in_sizes, int n_in,
                              void* d_out, int out_size, void* d_ws, size_t ws_size,
                              hipStream_t stream) {
    const float* x    = (const float*)d_in[0];
    const int*   ei   = (const int*)d_in[1];
    const float* ea   = (const float*)d_in[2];
    const float* encW = (const float*)d_in[3];
    const float* encb = (const float*)d_in[4];
    const float* bng  = (const float*)d_in[5];
    const float* bnb  = (const float*)d_in[6];
    const float *W[3], *asrc[3], *adst[3], *We[3], *aev[3], *bias[3];
    for (int l = 0; l < 3; ++l) {
        W[l]    = (const float*)d_in[7 + l * 6 + 0];
        asrc[l] = (const float*)d_in[7 + l * 6 + 1];
        adst[l] = (const float*)d_in[7 + l * 6 + 2];
        We[l]   = (const float*)d_in[7 + l * 6 + 3];
        aev[l]  = (const float*)d_in[7 + l * 6 + 4];
        bias[l] = (const float*)d_in[7 + l * 6 + 5];
    }
    const int N = in_sizes[0] / NF;
    const int E = in_sizes[1] / 2;
    float* out = (float*)d_out;

    // workspace carve-up (256B aligned)
    char* wp = (char*)d_ws;
    auto alloc = [&](size_t bytes) -> char* {
        char* p = wp;
        wp += (bytes + 255) & ~(size_t)255;
        return p;
    };
    float* h0     = (float*)alloc((size_t)N * H * 4);
    float* hA     = (float*)alloc((size_t)N * H * 4);
    float* g      = (float*)alloc((size_t)N * H * 4);
    float* a_src  = (float*)alloc((size_t)N * 4);
    float* a_dst  = (float*)alloc((size_t)N * 4);
    int*   rowptr = (int*)alloc((size_t)(N + 1) * 4);
    int*   cursor = (int*)alloc((size_t)N * 4);
    float* meanacc = (float*)alloc(8);
    float* park   = (float*)alloc(64);
    int*   bsum   = (int*)alloc(512);
    int*   boff   = (int*)alloc(512);
    int*   srcs   = (int*)alloc((size_t)E * 4);
    float2* eattr = (float2*)alloc((size_t)E * 8);
    const int EB = (E + 255) / 256;
    float2* pmean = (float2*)alloc((size_t)EB * 8);

    hipMemsetAsync(cursor, 0, (size_t)N * 4, stream);

    const int NB512 = (N + 511) / 512;
    k_edge_count_mean<<<EB, 256, 0, stream>>>(ei, ea, E, cursor, pmean);
    k_reduce_mean<<<1, 1024, 0, stream>>>(pmean, EB, meanacc);
    k_scan1<<<NB512, 512, 0, stream>>>(cursor, rowptr, bsum, N);
    k_scan2<<<1, 64, 0, stream>>>(bsum, boff, NB512);
    k_scan3<<<NB512, 512, 0, stream>>>(rowptr, boff, cursor, N, E);
    k_scatter<<<EB, 256, 0, stream>>>(ei, ea, E, cursor, srcs, eattr);
    k_setup<<<3, 64, 0, stream>>>(We[0], aev[0], We[1], aev[1], We[2], aev[2],
                                  meanacc, 1.0f / (float)E, park);

    const int GB = (N + 7) / 8;
    const int AB = (N + 3) / 4;
    k_encoder<<<GB, 256, 0, stream>>>(x, encW, encb, bng, bnb, h0, N);

    // layer 1: h0 -> hA
    k_gemm<<<GB, 256, 0, stream>>>(h0, W[0], asrc[0], adst[0], g, a_src, a_dst, N);
    k_agg<1, 0><<<AB, 256, 0, stream>>>(g, a_src, a_dst, rowptr, srcs, eattr, park, 0,
                                        bias[0], nullptr, hA, N);
    // layer 2: hA -> hA
    k_gemm<<<GB, 256, 0, stream>>>(hA, W[1], asrc[1], adst[1], g, a_src, a_dst, N);
    k_agg<1, 0><<<AB, 256, 0, stream>>>(g, a_src, a_dst, rowptr, srcs, eattr, park, 1,
                                        bias[1], nullptr, hA, N);
    // layer 3: hA -> out (+h0, no relu)
    k_gemm<<<GB, 256, 0, stream>>>(hA, W[2], asrc[2], adst[2], g, a_src, a_dst, N);
    k_agg<0, 1><<<AB, 256, 0, stream>>>(g, a_src, a_dst, rowptr, srcs, eattr, park, 2,
                                        bias[2], h0, out, N);
}

// Round 3
// 793.414 us; speedup vs baseline: 1.8323x; 1.0953x over previous
//
#include <hip/hip_runtime.h>
#include <math.h>

// ---------------------------------------------------------------------------
// ImprovedCrossBorderGNN: 3-layer edge-conditioned GAT, N=50000, E=1.6M, H=128
// CSR (dst-grouped) built once; per layer: fp32 GEMM g=h@W (fused a_src/a_dst
// epilogue, bf16 g output), then wave-per-node online-softmax gather.
// R1: mean() via two-stage reduction (fp32 same-address atomics were 644us).
// R2: bf16 g gather payload (halves agg FETCH); single int4 edge record with
//     per-layer precomputed edge-attention scalars (halves scatter lines);
//     parallel block-sum scan; merged setup kernel.
// ---------------------------------------------------------------------------

#define H 128
#define NF 8

__device__ __forceinline__ float wred_sum(float x) {
#pragma unroll
    for (int m = 32; m >= 1; m >>= 1) x += __shfl_xor(x, m, 64);
    return x;
}
__device__ __forceinline__ float wred_max(float x) {
#pragma unroll
    for (int m = 32; m >= 1; m >>= 1) x = fmaxf(x, __shfl_xor(x, m, 64));
    return x;
}
__device__ __forceinline__ ushort f2bf(float f) {
    uint u = __float_as_uint(f);
    uint r = (u + 0x7FFFu + ((u >> 16) & 1u)) >> 16;  // round-to-nearest-even
    return (ushort)r;
}

// ---- CSR build -------------------------------------------------------------

// degree histogram (into deg[]) + edge_attr column-sum per-block partials
__global__ void k_edge_count_mean(const int* __restrict__ ei, const float* __restrict__ ea,
                                  int E, int* __restrict__ deg, float2* __restrict__ pmean) {
    __shared__ float sx[4], sy[4];
    int e = blockIdx.x * 256 + threadIdx.x;
    float px = 0.f, py = 0.f;
    if (e < E) {
        int d = ei[E + e];
        atomicAdd(&deg[d], 1);
        const float2 z = *(const float2*)(ea + 2 * (size_t)e);
        px = z.x; py = z.y;
    }
    px = wred_sum(px); py = wred_sum(py);
    int w = threadIdx.x >> 6;
    if ((threadIdx.x & 63) == 0) { sx[w] = px; sy[w] = py; }
    __syncthreads();
    if (threadIdx.x == 0) {
        pmean[blockIdx.x] = make_float2(sx[0] + sx[1] + sx[2] + sx[3],
                                        sy[0] + sy[1] + sy[2] + sy[3]);
    }
}

// one block: reduce pmean -> mean; compute c_l = We_l @ ae_l and self-loop term
__global__ void k_setup_all(const float2* __restrict__ pmean, int nb, float invE,
                            const float* __restrict__ We1, const float* __restrict__ ae1,
                            const float* __restrict__ We2, const float* __restrict__ ae2,
                            const float* __restrict__ We3, const float* __restrict__ ae3,
                            float* __restrict__ park) {
    __shared__ float2 sp[4];
    __shared__ float smean[2];
    int t = threadIdx.x;  // 256
    float ax = 0.f, ay = 0.f;
    for (int i = t; i < nb; i += 256) {
        float2 z = pmean[i];
        ax += z.x; ay += z.y;
    }
    ax = wred_sum(ax); ay = wred_sum(ay);
    if ((t & 63) == 0) sp[t >> 6] = make_float2(ax, ay);
    __syncthreads();
    if (t == 0) {
        smean[0] = (sp[0].x + sp[1].x + sp[2].x + sp[3].x) * invE;
        smean[1] = (sp[0].y + sp[1].y + sp[2].y + sp[3].y) * invE;
    }
    __syncthreads();
    if (t < 192) {
        int l = t >> 6, q = t & 63;
        const float* We = (l == 0) ? We1 : ((l == 1) ? We2 : We3);
        const float* ae = (l == 0) ? ae1 : ((l == 1) ? ae2 : ae3);
        float p0 = We[q] * ae[q] + We[q + 64] * ae[q + 64];
        float p1 = We[H + q] * ae[q] + We[H + q + 64] * ae[q + 64];
        p0 = wred_sum(p0);
        p1 = wred_sum(p1);
        if (q == 0) {
            park[l * 3 + 0] = p0;
            park[l * 3 + 1] = p1;
            park[l * 3 + 2] = smean[0] * p0 + smean[1] * p1;
        }
    }
}

__global__ void k_scan1(const int* __restrict__ deg, int* __restrict__ rowptr,
                        int* __restrict__ bsum, int n) {
    __shared__ int tmp[512];
    int t = threadIdx.x;
    int i = blockIdx.x * 512 + t;
    int v = (i < n) ? deg[i] : 0;
    tmp[t] = v;
    __syncthreads();
    for (int off = 1; off < 512; off <<= 1) {
        int q = (t >= off) ? tmp[t - off] : 0;
        __syncthreads();
        tmp[t] += q;
        __syncthreads();
    }
    if (i < n) rowptr[i] = tmp[t] - v;  // exclusive (block-local)
    if (t == 511) bsum[blockIdx.x] = tmp[511];
}

__global__ void k_scan2p(const int* __restrict__ bsum, int* __restrict__ boff, int nb) {
    __shared__ int tmp[512];
    int t = threadIdx.x;
    int v = (t < nb) ? bsum[t] : 0;
    tmp[t] = v;
    __syncthreads();
    for (int off = 1; off < 512; off <<= 1) {
        int q = (t >= off) ? tmp[t - off] : 0;
        __syncthreads();
        tmp[t] += q;
        __syncthreads();
    }
    if (t < nb) boff[t] = tmp[t] - v;  // exclusive
}

__global__ void k_scan3(int* __restrict__ rowptr, const int* __restrict__ boff,
                        int* __restrict__ cursor, int n, int E) {
    int t = threadIdx.x;
    int i = blockIdx.x * 512 + t;
    if (i < n) {
        int r = rowptr[i] + boff[blockIdx.x];
        rowptr[i] = r;
        cursor[i] = r;
    }
    if (i == 0) rowptr[n] = E;
}

// scatter one 16B record per edge: {src, ae_l1, ae_l2, ae_l3}
__global__ void k_scatter(const int* __restrict__ ei, const float* __restrict__ ea, int E,
                          const float* __restrict__ park, int* __restrict__ cursor,
                          int4* __restrict__ erec) {
    int e = blockIdx.x * 256 + threadIdx.x;
    if (e >= E) return;
    int s = ei[e];
    int d = ei[E + e];
    const float2 z = *(const float2*)(ea + 2 * (size_t)e);
    float f0 = park[0] * z.x + park[1] * z.y;
    float f1 = park[3] * z.x + park[4] * z.y;
    float f2 = park[6] * z.x + park[7] * z.y;
    int p = atomicAdd(&cursor[d], 1);
    erec[p] = make_int4(s, __float_as_int(f0), __float_as_int(f1), __float_as_int(f2));
}

// ---- encoder: h0 = relu((x @ enc_W + b) * bn_g*inv + bn_b) -----------------
__global__ void k_encoder(const float* __restrict__ x, const float* __restrict__ encW,
                          const float* __restrict__ encb, const float* __restrict__ bng,
                          const float* __restrict__ bnb, float* __restrict__ h0, int N) {
    __shared__ float xs[8 * NF];
    int tid = threadIdx.x;
    int nb = blockIdx.x * 8;
    if (tid < 64) {
        size_t idx = (size_t)nb * NF + tid;
        xs[tid] = (idx < (size_t)N * NF) ? x[idx] : 0.f;
    }
    __syncthreads();
    int jt = tid & 31, i = tid >> 5;
    int node = nb + i;
    int j4 = jt * 4;
    float ax = 0.f, ay = 0.f, az = 0.f, aw = 0.f;
#pragma unroll
    for (int k = 0; k < NF; ++k) {
        float hx = xs[i * NF + k];
        const float4 w = *(const float4*)(encW + k * H + j4);
        ax = fmaf(hx, w.x, ax); ay = fmaf(hx, w.y, ay);
        az = fmaf(hx, w.z, az); aw = fmaf(hx, w.w, aw);
    }
    if (node < N) {
        const float inv = 0.9999950000374997f;  // 1/sqrt(1+1e-5)
        const float4 eb = *(const float4*)(encb + j4);
        const float4 gg = *(const float4*)(bng + j4);
        const float4 bb = *(const float4*)(bnb + j4);
        float4 o;
        o.x = fmaxf(0.f, (ax + eb.x) * (gg.x * inv) + bb.x);
        o.y = fmaxf(0.f, (ay + eb.y) * (gg.y * inv) + bb.y);
        o.z = fmaxf(0.f, (az + eb.z) * (gg.z * inv) + bb.z);
        o.w = fmaxf(0.f, (aw + eb.w) * (gg.w * inv) + bb.w);
        *(float4*)(h0 + (size_t)node * H + j4) = o;
    }
}

// ---- per-layer GEMM: g = h @ W (bf16 out), fused a_src/a_dst epilogue ------
__global__ void k_gemm(const float* __restrict__ h, const float* __restrict__ W,
                       const float* __restrict__ avs, const float* __restrict__ avd,
                       ushort* __restrict__ gb, float* __restrict__ a_src,
                       float* __restrict__ a_dst, int N) {
    __shared__ float hs[8 * H];
    int tid = threadIdx.x;
    int nb = blockIdx.x * 8;
    {
        int r = tid >> 5, c4 = (tid & 31) * 4;
        int node = nb + r;
        float4 v = make_float4(0.f, 0.f, 0.f, 0.f);
        if (node < N) v = *(const float4*)(h + (size_t)node * H + c4);
        *(float4*)(hs + r * H + c4) = v;
    }
    __syncthreads();
    int jt = tid & 31, i = tid >> 5;
    int node = nb + i;
    int j4 = jt * 4;
    float ax = 0.f, ay = 0.f, az = 0.f, aw = 0.f;
    for (int k = 0; k < H; k += 4) {
        const float4 hv = *(const float4*)(hs + i * H + k);
        const float4 w0 = *(const float4*)(W + (k + 0) * H + j4);
        const float4 w1 = *(const float4*)(W + (k + 1) * H + j4);
        const float4 w2 = *(const float4*)(W + (k + 2) * H + j4);
        const float4 w3 = *(const float4*)(W + (k + 3) * H + j4);
        ax = fmaf(hv.x, w0.x, ax); ay = fmaf(hv.x, w0.y, ay);
        az = fmaf(hv.x, w0.z, az); aw = fmaf(hv.x, w0.w, aw);
        ax = fmaf(hv.y, w1.x, ax); ay = fmaf(hv.y, w1.y, ay);
        az = fmaf(hv.y, w1.z, az); aw = fmaf(hv.y, w1.w, aw);
        ax = fmaf(hv.z, w2.x, ax); ay = fmaf(hv.z, w2.y, ay);
        az = fmaf(hv.z, w2.z, az); aw = fmaf(hv.z, w2.w, aw);
        ax = fmaf(hv.w, w3.x, ax); ay = fmaf(hv.w, w3.y, ay);
        az = fmaf(hv.w, w3.z, az); aw = fmaf(hv.w, w3.w, aw);
    }
    const float4 s4 = *(const float4*)(avs + j4);
    const float4 d4 = *(const float4*)(avd + j4);
    float ps = ax * s4.x + ay * s4.y + az * s4.z + aw * s4.w;
    float pd = ax * d4.x + ay * d4.y + az * d4.z + aw * d4.w;
#pragma unroll
    for (int mm = 16; mm >= 1; mm >>= 1) {
        ps += __shfl_xor(ps, mm, 64);
        pd += __shfl_xor(pd, mm, 64);
    }
    if (node < N) {
        ushort4 o;
        o.x = f2bf(ax); o.y = f2bf(ay); o.z = f2bf(az); o.w = f2bf(aw);
        *(ushort4*)(gb + (size_t)node * H + j4) = o;
        if (jt == 0) {
            a_src[node] = ps;
            a_dst[node] = pd;
        }
    }
}

// ---- aggregation: wave per node, online softmax, bf16 gather --------------
template <int RELU, int ADDH0, int LAYER>
__global__ void k_agg(const ushort* __restrict__ gb, const float* __restrict__ a_src,
                      const float* __restrict__ a_dst, const int* __restrict__ rowptr,
                      const int4* __restrict__ erec, const float* __restrict__ park,
                      const float* __restrict__ bias, const float* __restrict__ h0,
                      float* __restrict__ out, int N) {
    int wv = threadIdx.x >> 6;
    int lane = threadIdx.x & 63;
    int v = blockIdx.x * 4 + wv;
    if (v >= N) return;

    const float sa = park[LAYER * 3 + 2];
    const float adv = a_dst[v];
    float lself = a_src[v] + adv + sa;
    lself = (lself > 0.f) ? lself : 0.2f * lself;

    float m = lself;   // running max (self-loop included)
    float s = 1.f;     // running sum, w_self = exp(0) = 1
    const int ch = lane * 2;
    {
        // self-loop contribution, weight 1 (bf16, same quantization as neighbors)
    }
    uint qv = *(const uint*)(gb + (size_t)v * H + ch);
    float acc0 = __uint_as_float(qv << 16);
    float acc1 = __uint_as_float(qv & 0xffff0000u);

    const int rs = rowptr[v];
    const int re = rowptr[v + 1];
    for (int p0 = rs; p0 < re; p0 += 64) {
        int e = p0 + lane;
        bool val = e < re;
        int4 rec = val ? erec[e] : make_int4(0, 0, 0, 0);
        int sv = rec.x;
        float lg;
        if (val) {
            float aef = __int_as_float(LAYER == 0 ? rec.y : (LAYER == 1 ? rec.z : rec.w));
            lg = a_src[sv] + adv + aef;
            lg = (lg > 0.f) ? lg : 0.2f * lg;
        } else {
            lg = -INFINITY;
        }
        float cm = wred_max(lg);
        float nm = fmaxf(m, cm);
        float f = __expf(m - nm);
        float w = val ? __expf(lg - nm) : 0.f;
        float ws = wred_sum(w);
        s = s * f + ws;
        acc0 *= f;
        acc1 *= f;
        m = nm;
        int cnt = re - p0;
        if (cnt > 64) cnt = 64;
        for (int j = 0; j < cnt; ++j) {
            float wj = __int_as_float(__builtin_amdgcn_readlane(__float_as_int(w), j));
            int sj = __builtin_amdgcn_readlane(sv, j);
            uint q = *(const uint*)(gb + (size_t)sj * H + ch);
            acc0 = fmaf(wj, __uint_as_float(q << 16), acc0);
            acc1 = fmaf(wj, __uint_as_float(q & 0xffff0000u), acc1);
        }
    }
    const float is = 1.f / s;
    const float2 bz = *(const float2*)(bias + ch);
    float o0 = acc0 * is + bz.x;
    float o1 = acc1 * is + bz.y;
    if (ADDH0) {
        const float2 hz = *(const float2*)(h0 + (size_t)v * H + ch);
        o0 += hz.x;
        o1 += hz.y;
    }
    if (RELU) {
        o0 = fmaxf(o0, 0.f);
        o1 = fmaxf(o1, 0.f);
    }
    *(float2*)(out + (size_t)v * H + ch) = make_float2(o0, o1);
}

// ---------------------------------------------------------------------------

extern "C" void kernel_launch(void* const* d_in, const int* in_sizes, int n_in,
                              void* d_out, int out_size, void* d_ws, size_t ws_size,
                              hipStream_t stream) {
    const float* x    = (const float*)d_in[0];
    const int*   ei   = (const int*)d_in[1];
    const float* ea   = (const float*)d_in[2];
    const float* encW = (const float*)d_in[3];
    const float* encb = (const float*)d_in[4];
    const float* bng  = (const float*)d_in[5];
    const float* bnb  = (const float*)d_in[6];
    const float *W[3], *asrc[3], *adst[3], *We[3], *aev[3], *bias[3];
    for (int l = 0; l < 3; ++l) {
        W[l]    = (const float*)d_in[7 + l * 6 + 0];
        asrc[l] = (const float*)d_in[7 + l * 6 + 1];
        adst[l] = (const float*)d_in[7 + l * 6 + 2];
        We[l]   = (const float*)d_in[7 + l * 6 + 3];
        aev[l]  = (const float*)d_in[7 + l * 6 + 4];
        bias[l] = (const float*)d_in[7 + l * 6 + 5];
    }
    const int N = in_sizes[0] / NF;
    const int E = in_sizes[1] / 2;
    float* out = (float*)d_out;

    // workspace carve-up (256B aligned)
    char* wp = (char*)d_ws;
    auto alloc = [&](size_t bytes) -> char* {
        char* p = wp;
        wp += (bytes + 255) & ~(size_t)255;
        return p;
    };
    float*  h0     = (float*)alloc((size_t)N * H * 4);
    float*  hA     = (float*)alloc((size_t)N * H * 4);
    ushort* gb     = (ushort*)alloc((size_t)N * H * 2);
    float*  a_src  = (float*)alloc((size_t)N * 4);
    float*  a_dst  = (float*)alloc((size_t)N * 4);
    int*    rowptr = (int*)alloc((size_t)(N + 1) * 4);
    int*    cursor = (int*)alloc((size_t)N * 4);
    float*  park   = (float*)alloc(64);
    int*    bsum   = (int*)alloc(2048);
    int*    boff   = (int*)alloc(2048);
    int4*   erec   = (int4*)alloc((size_t)E * 16);
    const int EB = (E + 255) / 256;
    float2* pmean  = (float2*)alloc((size_t)EB * 8);

    hipMemsetAsync(cursor, 0, (size_t)N * 4, stream);

    const int NB512 = (N + 511) / 512;
    k_edge_count_mean<<<EB, 256, 0, stream>>>(ei, ea, E, cursor, pmean);
    k_setup_all<<<1, 256, 0, stream>>>(pmean, EB, 1.0f / (float)E,
                                       We[0], aev[0], We[1], aev[1], We[2], aev[2], park);
    k_scan1<<<NB512, 512, 0, stream>>>(cursor, rowptr, bsum, N);
    k_scan2p<<<1, 512, 0, stream>>>(bsum, boff, NB512);
    k_scan3<<<NB512, 512, 0, stream>>>(rowptr, boff, cursor, N, E);
    k_scatter<<<EB, 256, 0, stream>>>(ei, ea, E, park, cursor, erec);

    const int GB = (N + 7) / 8;
    const int AB = (N + 3) / 4;
    k_encoder<<<GB, 256, 0, stream>>>(x, encW, encb, bng, bnb, h0, N);

    // layer 1: h0 -> hA
    k_gemm<<<GB, 256, 0, stream>>>(h0, W[0], asrc[0], adst[0], gb, a_src, a_dst, N);
    k_agg<1, 0, 0><<<AB, 256, 0, stream>>>(gb, a_src, a_dst, rowptr, erec, park,
                                           bias[0], nullptr, hA, N);
    // layer 2: hA -> hA
    k_gemm<<<GB, 256, 0, stream>>>(hA, W[1], asrc[1], adst[1], gb, a_src, a_dst, N);
    k_agg<1, 0, 1><<<AB, 256, 0, stream>>>(gb, a_src, a_dst, rowptr, erec, park,
                                           bias[1], nullptr, hA, N);
    // layer 3: hA -> out (+h0, no relu)
    k_gemm<<<GB, 256, 0, stream>>>(hA, W[2], asrc[2], adst[2], gb, a_src, a_dst, N);
    k_agg<0, 1, 2><<<AB, 256, 0, stream>>>(gb, a_src, a_dst, rowptr, erec, park,
                                           bias[2], h0, out, N);
}

// Round 4
// 666.976 us; speedup vs baseline: 2.1797x; 1.1896x over previous
//
#include <hip/hip_runtime.h>
#include <math.h>

// ---------------------------------------------------------------------------
// ImprovedCrossBorderGNN: 3-layer edge-conditioned GAT, N=50000, E=1.6M, H=128
// CSR (dst-grouped) built once; per layer: fp32 GEMM g=h@W (fused a_src/a_dst
// epilogue, bf16 g output), then wave-per-node online-softmax gather.
// R1: mean() via two-stage reduction (same-address fp32 atomics were 644us).
// R2: bf16 g gather payload; int4 edge record; parallel scans.
// R3 -> R4: CSR build was atomic-throughput-bound (~14G atomics/s; 2x 1.6M
//   global atomics ~ 220us). Replaced with two-level counting sort:
//   K1 LDS-histogram count (77k global atomics), K2 scan+park, K3 place
//   (zero global atomics), K4 per-bucket fine CSR (single-XCD L2 writes).
// ---------------------------------------------------------------------------

#define H 128
#define NF 8
#define EPB 4096  // edges per block in K1/K3 (256 threads x 16)

__device__ __forceinline__ float wred_sum(float x) {
#pragma unroll
    for (int m = 32; m >= 1; m >>= 1) x += __shfl_xor(x, m, 64);
    return x;
}
__device__ __forceinline__ float wred_max(float x) {
#pragma unroll
    for (int m = 32; m >= 1; m >>= 1) x = fmaxf(x, __shfl_xor(x, m, 64));
    return x;
}
__device__ __forceinline__ ushort f2bf(float f) {
    uint u = __float_as_uint(f);
    uint r = (u + 0x7FFFu + ((u >> 16) & 1u)) >> 16;  // round-to-nearest-even
    return (ushort)r;
}

// ---- CSR build: two-level counting sort (no per-edge global atomics) -------

// K1: coarse count. LDS histogram of 196 buckets (dst>>8); one global atomic
// per (block,bucket); also edge_attr column-sum per-block partials.
__global__ void k_count(const int* __restrict__ ei, const float* __restrict__ ea,
                        int E, int nblk, int nbuckets, int* __restrict__ bucketTotal,
                        int* __restrict__ blockBase, float2* __restrict__ pmean) {
    __shared__ int hist[256];
    __shared__ float sx[4], sy[4];
    int t = threadIdx.x;  // 256
    int blk = blockIdx.x;
    hist[t] = 0;
    __syncthreads();
    int base = blk * EPB;
    float px = 0.f, py = 0.f;
#pragma unroll
    for (int i = 0; i < 16; ++i) {
        int e = base + i * 256 + t;
        if (e < E) {
            int d = ei[E + e];
            atomicAdd(&hist[d >> 8], 1);
            const float2 z = *(const float2*)(ea + 2 * (size_t)e);
            px += z.x; py += z.y;
        }
    }
    px = wred_sum(px); py = wred_sum(py);
    if ((t & 63) == 0) { sx[t >> 6] = px; sy[t >> 6] = py; }
    __syncthreads();
    if (t == 0) {
        pmean[blk] = make_float2(sx[0] + sx[1] + sx[2] + sx[3],
                                 sy[0] + sy[1] + sy[2] + sy[3]);
    }
    if (t < nbuckets) {
        int c = hist[t];
        int old = (c > 0) ? atomicAdd(&bucketTotal[t], c) : 0;
        blockBase[t * nblk + blk] = old;
    }
}

// K2: one block. Reduce pmean -> mean; exclusive scan of bucket totals;
// rowptr[N]=E; compute park (c_l = We_l @ ae_l, self-loop scalar).
__global__ void k_scan_park(const int* __restrict__ bucketTotal, int nbuckets,
                            int* __restrict__ bucketBase, int* __restrict__ rowptr,
                            int N, int E, const float2* __restrict__ pmean, int nblk,
                            float invE,
                            const float* __restrict__ We1, const float* __restrict__ ae1,
                            const float* __restrict__ We2, const float* __restrict__ ae2,
                            const float* __restrict__ We3, const float* __restrict__ ae3,
                            float* __restrict__ park) {
    __shared__ int tmp[256];
    __shared__ float2 sp[4];
    __shared__ float smean[2];
    int t = threadIdx.x;  // 256
    float ax = 0.f, ay = 0.f;
    for (int i = t; i < nblk; i += 256) {
        float2 z = pmean[i];
        ax += z.x; ay += z.y;
    }
    ax = wred_sum(ax); ay = wred_sum(ay);
    if ((t & 63) == 0) sp[t >> 6] = make_float2(ax, ay);
    int v = (t < nbuckets) ? bucketTotal[t] : 0;
    tmp[t] = v;
    __syncthreads();
    for (int off = 1; off < 256; off <<= 1) {
        int q = (t >= off) ? tmp[t - off] : 0;
        __syncthreads();
        tmp[t] += q;
        __syncthreads();
    }
    bucketBase[t] = tmp[t] - v;  // exclusive; entries >= nbuckets hold E
    if (t == 0) {
        bucketBase[256] = tmp[255];  // == E
        rowptr[N] = E;
        smean[0] = (sp[0].x + sp[1].x + sp[2].x + sp[3].x) * invE;
        smean[1] = (sp[0].y + sp[1].y + sp[2].y + sp[3].y) * invE;
    }
    __syncthreads();
    if (t < 192) {
        int l = t >> 6, q = t & 63;
        const float* We = (l == 0) ? We1 : ((l == 1) ? We2 : We3);
        const float* ae = (l == 0) ? ae1 : ((l == 1) ? ae2 : ae3);
        float p0 = We[q] * ae[q] + We[q + 64] * ae[q + 64];
        float p1 = We[H + q] * ae[q] + We[H + q + 64] * ae[q + 64];
        p0 = wred_sum(p0);
        p1 = wred_sum(p1);
        if (q == 0) {
            park[l * 3 + 0] = p0;
            park[l * 3 + 1] = p1;
            park[l * 3 + 2] = smean[0] * p0 + smean[1] * p1;
        }
    }
}

// K3: place. Same edge->block assignment as K1; LDS rank within (block,bucket);
// write 8B packed record {src:16|dstlo:8, bf16 ea.x | bf16 ea.y}. No global atomics.
__global__ void k_place(const int* __restrict__ ei, const float* __restrict__ ea,
                        int E, int nblk, int nbuckets,
                        const int* __restrict__ bucketBase, const int* __restrict__ blockBase,
                        uint2* __restrict__ temp) {
    __shared__ int cnt[256];
    __shared__ int sbase[256];
    int t = threadIdx.x;  // 256
    int blk = blockIdx.x;
    cnt[t] = 0;
    if (t < nbuckets) sbase[t] = bucketBase[t] + blockBase[t * nblk + blk];
    __syncthreads();
    int base = blk * EPB;
#pragma unroll
    for (int i = 0; i < 16; ++i) {
        int e = base + i * 256 + t;
        if (e < E) {
            int s = ei[e];          // s < 65536 (N=50000)
            int d = ei[E + e];
            int b = d >> 8;
            int r = atomicAdd(&cnt[b], 1);
            const float2 z = *(const float2*)(ea + 2 * (size_t)e);
            uint w0 = (uint)s | ((uint)(d & 255) << 16);
            uint w1 = (uint)f2bf(z.x) | ((uint)f2bf(z.y) << 16);
            temp[sbase[b] + r] = make_uint2(w0, w1);
        }
    }
}

// K4: per-bucket fine CSR. One block per coarse bucket: LDS 256-bin histogram
// over dst low byte, LDS scan, emit rowptr + final 16B records {src,f0,f1,f2}.
__global__ void k_fine(const uint2* __restrict__ temp, const int* __restrict__ bucketBase,
                       const float* __restrict__ park, int N,
                       int4* __restrict__ erec, int* __restrict__ rowptr) {
    __shared__ int hist[256];
    __shared__ int tmp[256];
    __shared__ int fb[256];
    __shared__ int cur[256];
    int b = blockIdx.x;
    int t = threadIdx.x;  // 256
    const int lo = bucketBase[b], hi = bucketBase[b + 1];
    hist[t] = 0;
    __syncthreads();
    for (int e = lo + t; e < hi; e += 256) {
        atomicAdd(&hist[(temp[e].x >> 16) & 255], 1);
    }
    __syncthreads();
    int v = hist[t];
    tmp[t] = v;
    __syncthreads();
    for (int off = 1; off < 256; off <<= 1) {
        int q = (t >= off) ? tmp[t - off] : 0;
        __syncthreads();
        tmp[t] += q;
        __syncthreads();
    }
    fb[t] = tmp[t] - v;  // exclusive within bucket
    cur[t] = 0;
    int dst = b * 256 + t;
    if (dst < N) rowptr[dst] = lo + fb[t];
    __syncthreads();
    const float c00 = park[0], c01 = park[1];
    const float c10 = park[3], c11 = park[4];
    const float c20 = park[6], c21 = park[7];
    for (int e = lo + t; e < hi; e += 256) {
        uint2 w = temp[e];
        int src = (int)(w.x & 0xFFFFu);
        int j = (int)((w.x >> 16) & 255u);
        float ex = __uint_as_float(w.y << 16);
        float ey = __uint_as_float(w.y & 0xffff0000u);
        int r = atomicAdd(&cur[j], 1);
        float f0 = c00 * ex + c01 * ey;
        float f1 = c10 * ex + c11 * ey;
        float f2 = c20 * ex + c21 * ey;
        erec[lo + fb[j] + r] = make_int4(src, __float_as_int(f0),
                                         __float_as_int(f1), __float_as_int(f2));
    }
}

// ---- encoder: h0 = relu((x @ enc_W + b) * bn_g*inv + bn_b) -----------------
__global__ void k_encoder(const float* __restrict__ x, const float* __restrict__ encW,
                          const float* __restrict__ encb, const float* __restrict__ bng,
                          const float* __restrict__ bnb, float* __restrict__ h0, int N) {
    __shared__ float xs[8 * NF];
    int tid = threadIdx.x;
    int nb = blockIdx.x * 8;
    if (tid < 64) {
        size_t idx = (size_t)nb * NF + tid;
        xs[tid] = (idx < (size_t)N * NF) ? x[idx] : 0.f;
    }
    __syncthreads();
    int jt = tid & 31, i = tid >> 5;
    int node = nb + i;
    int j4 = jt * 4;
    float ax = 0.f, ay = 0.f, az = 0.f, aw = 0.f;
#pragma unroll
    for (int k = 0; k < NF; ++k) {
        float hx = xs[i * NF + k];
        const float4 w = *(const float4*)(encW + k * H + j4);
        ax = fmaf(hx, w.x, ax); ay = fmaf(hx, w.y, ay);
        az = fmaf(hx, w.z, az); aw = fmaf(hx, w.w, aw);
    }
    if (node < N) {
        const float inv = 0.9999950000374997f;  // 1/sqrt(1+1e-5)
        const float4 eb = *(const float4*)(encb + j4);
        const float4 gg = *(const float4*)(bng + j4);
        const float4 bb = *(const float4*)(bnb + j4);
        float4 o;
        o.x = fmaxf(0.f, (ax + eb.x) * (gg.x * inv) + bb.x);
        o.y = fmaxf(0.f, (ay + eb.y) * (gg.y * inv) + bb.y);
        o.z = fmaxf(0.f, (az + eb.z) * (gg.z * inv) + bb.z);
        o.w = fmaxf(0.f, (aw + eb.w) * (gg.w * inv) + bb.w);
        *(float4*)(h0 + (size_t)node * H + j4) = o;
    }
}

// ---- per-layer GEMM: g = h @ W (bf16 out), fused a_src/a_dst epilogue ------
__global__ void k_gemm(const float* __restrict__ h, const float* __restrict__ W,
                       const float* __restrict__ avs, const float* __restrict__ avd,
                       ushort* __restrict__ gb, float* __restrict__ a_src,
                       float* __restrict__ a_dst, int N) {
    __shared__ float hs[8 * H];
    int tid = threadIdx.x;
    int nb = blockIdx.x * 8;
    {
        int r = tid >> 5, c4 = (tid & 31) * 4;
        int node = nb + r;
        float4 v = make_float4(0.f, 0.f, 0.f, 0.f);
        if (node < N) v = *(const float4*)(h + (size_t)node * H + c4);
        *(float4*)(hs + r * H + c4) = v;
    }
    __syncthreads();
    int jt = tid & 31, i = tid >> 5;
    int node = nb + i;
    int j4 = jt * 4;
    float ax = 0.f, ay = 0.f, az = 0.f, aw = 0.f;
    for (int k = 0; k < H; k += 4) {
        const float4 hv = *(const float4*)(hs + i * H + k);
        const float4 w0 = *(const float4*)(W + (k + 0) * H + j4);
        const float4 w1 = *(const float4*)(W + (k + 1) * H + j4);
        const float4 w2 = *(const float4*)(W + (k + 2) * H + j4);
        const float4 w3 = *(const float4*)(W + (k + 3) * H + j4);
        ax = fmaf(hv.x, w0.x, ax); ay = fmaf(hv.x, w0.y, ay);
        az = fmaf(hv.x, w0.z, az); aw = fmaf(hv.x, w0.w, aw);
        ax = fmaf(hv.y, w1.x, ax); ay = fmaf(hv.y, w1.y, ay);
        az = fmaf(hv.y, w1.z, az); aw = fmaf(hv.y, w1.w, aw);
        ax = fmaf(hv.z, w2.x, ax); ay = fmaf(hv.z, w2.y, ay);
        az = fmaf(hv.z, w2.z, az); aw = fmaf(hv.z, w2.w, aw);
        ax = fmaf(hv.w, w3.x, ax); ay = fmaf(hv.w, w3.y, ay);
        az = fmaf(hv.w, w3.z, az); aw = fmaf(hv.w, w3.w, aw);
    }
    const float4 s4 = *(const float4*)(avs + j4);
    const float4 d4 = *(const float4*)(avd + j4);
    float ps = ax * s4.x + ay * s4.y + az * s4.z + aw * s4.w;
    float pd = ax * d4.x + ay * d4.y + az * d4.z + aw * d4.w;
#pragma unroll
    for (int mm = 16; mm >= 1; mm >>= 1) {
        ps += __shfl_xor(ps, mm, 64);
        pd += __shfl_xor(pd, mm, 64);
    }
    if (node < N) {
        ushort4 o;
        o.x = f2bf(ax); o.y = f2bf(ay); o.z = f2bf(az); o.w = f2bf(aw);
        *(ushort4*)(gb + (size_t)node * H + j4) = o;
        if (jt == 0) {
            a_src[node] = ps;
            a_dst[node] = pd;
        }
    }
}

// ---- aggregation: wave per node, online softmax, bf16 gather --------------
template <int RELU, int ADDH0, int LAYER>
__global__ void k_agg(const ushort* __restrict__ gb, const float* __restrict__ a_src,
                      const float* __restrict__ a_dst, const int* __restrict__ rowptr,
                      const int4* __restrict__ erec, const float* __restrict__ park,
                      const float* __restrict__ bias, const float* __restrict__ h0,
                      float* __restrict__ out, int N) {
    int wv = threadIdx.x >> 6;
    int lane = threadIdx.x & 63;
    int v = blockIdx.x * 4 + wv;
    if (v >= N) return;

    const float sa = park[LAYER * 3 + 2];
    const float adv = a_dst[v];
    float lself = a_src[v] + adv + sa;
    lself = (lself > 0.f) ? lself : 0.2f * lself;

    float m = lself;   // running max (self-loop included)
    float s = 1.f;     // running sum, w_self = exp(0) = 1
    const int ch = lane * 2;
    uint qv = *(const uint*)(gb + (size_t)v * H + ch);
    float acc0 = __uint_as_float(qv << 16);
    float acc1 = __uint_as_float(qv & 0xffff0000u);

    const int rs = rowptr[v];
    const int re = rowptr[v + 1];
    for (int p0 = rs; p0 < re; p0 += 64) {
        int e = p0 + lane;
        bool val = e < re;
        int4 rec = val ? erec[e] : make_int4(0, 0, 0, 0);
        int sv = rec.x;
        float lg;
        if (val) {
            float aef = __int_as_float(LAYER == 0 ? rec.y : (LAYER == 1 ? rec.z : rec.w));
            lg = a_src[sv] + adv + aef;
            lg = (lg > 0.f) ? lg : 0.2f * lg;
        } else {
            lg = -INFINITY;
        }
        float cm = wred_max(lg);
        float nm = fmaxf(m, cm);
        float f = __expf(m - nm);
        float w = val ? __expf(lg - nm) : 0.f;
        float ws = wred_sum(w);
        s = s * f + ws;
        acc0 *= f;
        acc1 *= f;
        m = nm;
        int cnt = re - p0;
        if (cnt > 64) cnt = 64;
        for (int j = 0; j < cnt; ++j) {
            float wj = __int_as_float(__builtin_amdgcn_readlane(__float_as_int(w), j));
            int sj = __builtin_amdgcn_readlane(sv, j);
            uint q = *(const uint*)(gb + (size_t)sj * H + ch);
            acc0 = fmaf(wj, __uint_as_float(q << 16), acc0);
            acc1 = fmaf(wj, __uint_as_float(q & 0xffff0000u), acc1);
        }
    }
    const float is = 1.f / s;
    const float2 bz = *(const float2*)(bias + ch);
    float o0 = acc0 * is + bz.x;
    float o1 = acc1 * is + bz.y;
    if (ADDH0) {
        const float2 hz = *(const float2*)(h0 + (size_t)v * H + ch);
        o0 += hz.x;
        o1 += hz.y;
    }
    if (RELU) {
        o0 = fmaxf(o0, 0.f);
        o1 = fmaxf(o1, 0.f);
    }
    *(float2*)(out + (size_t)v * H + ch) = make_float2(o0, o1);
}

// ---------------------------------------------------------------------------

extern "C" void kernel_launch(void* const* d_in, const int* in_sizes, int n_in,
                              void* d_out, int out_size, void* d_ws, size_t ws_size,
                              hipStream_t stream) {
    const float* x    = (const float*)d_in[0];
    const int*   ei   = (const int*)d_in[1];
    const float* ea   = (const float*)d_in[2];
    const float* encW = (const float*)d_in[3];
    const float* encb = (const float*)d_in[4];
    const float* bng  = (const float*)d_in[5];
    const float* bnb  = (const float*)d_in[6];
    const float *W[3], *asrc[3], *adst[3], *We[3], *aev[3], *bias[3];
    for (int l = 0; l < 3; ++l) {
        W[l]    = (const float*)d_in[7 + l * 6 + 0];
        asrc[l] = (const float*)d_in[7 + l * 6 + 1];
        adst[l] = (const float*)d_in[7 + l * 6 + 2];
        We[l]   = (const float*)d_in[7 + l * 6 + 3];
        aev[l]  = (const float*)d_in[7 + l * 6 + 4];
        bias[l] = (const float*)d_in[7 + l * 6 + 5];
    }
    const int N = in_sizes[0] / NF;   // 50000 (< 65536: src packs in 16 bits)
    const int E = in_sizes[1] / 2;
    float* out = (float*)d_out;

    const int NBu  = (N + 255) >> 8;          // coarse buckets (196)
    const int nblk = (E + EPB - 1) / EPB;     // K1/K3 blocks (391)

    // workspace carve-up (256B aligned)
    char* wp = (char*)d_ws;
    auto alloc = [&](size_t bytes) -> char* {
        char* p = wp;
        wp += (bytes + 255) & ~(size_t)255;
        return p;
    };
    float*  h0       = (float*)alloc((size_t)N * H * 4);
    float*  hA       = (float*)alloc((size_t)N * H * 4);   // temp overlays here
    ushort* gb       = (ushort*)alloc((size_t)N * H * 2);
    float*  a_src    = (float*)alloc((size_t)N * 4);
    float*  a_dst    = (float*)alloc((size_t)N * 4);
    int*    rowptr   = (int*)alloc((size_t)(N + 1) * 4);
    float*  park     = (float*)alloc(64);
    int*    bucketTotal = (int*)alloc(256 * 4);
    int*    bucketBase  = (int*)alloc(257 * 4);
    int*    blockBase   = (int*)alloc((size_t)NBu * nblk * 4);
    int4*   erec     = (int4*)alloc((size_t)E * 16);
    float2* pmean    = (float2*)alloc((size_t)nblk * 8);
    uint2*  temp     = (uint2*)hA;  // E*8 bytes <= N*H*4; dead before hA is written

    hipMemsetAsync(bucketTotal, 0, 256 * 4, stream);

    k_count<<<nblk, 256, 0, stream>>>(ei, ea, E, nblk, NBu, bucketTotal, blockBase, pmean);
    k_scan_park<<<1, 256, 0, stream>>>(bucketTotal, NBu, bucketBase, rowptr, N, E,
                                       pmean, nblk, 1.0f / (float)E,
                                       We[0], aev[0], We[1], aev[1], We[2], aev[2], park);
    k_place<<<nblk, 256, 0, stream>>>(ei, ea, E, nblk, NBu, bucketBase, blockBase, temp);
    k_fine<<<NBu, 256, 0, stream>>>(temp, bucketBase, park, N, erec, rowptr);

    const int GB = (N + 7) / 8;
    const int AB = (N + 3) / 4;
    k_encoder<<<GB, 256, 0, stream>>>(x, encW, encb, bng, bnb, h0, N);

    // layer 1: h0 -> hA
    k_gemm<<<GB, 256, 0, stream>>>(h0, W[0], asrc[0], adst[0], gb, a_src, a_dst, N);
    k_agg<1, 0, 0><<<AB, 256, 0, stream>>>(gb, a_src, a_dst, rowptr, erec, park,
                                           bias[0], nullptr, hA, N);
    // layer 2: hA -> hA
    k_gemm<<<GB, 256, 0, stream>>>(hA, W[1], asrc[1], adst[1], gb, a_src, a_dst, N);
    k_agg<1, 0, 1><<<AB, 256, 0, stream>>>(gb, a_src, a_dst, rowptr, erec, park,
                                           bias[1], nullptr, hA, N);
    // layer 3: hA -> out (+h0, no relu)
    k_gemm<<<GB, 256, 0, stream>>>(hA, W[2], asrc[2], adst[2], gb, a_src, a_dst, N);
    k_agg<0, 1, 2><<<AB, 256, 0, stream>>>(gb, a_src, a_dst, rowptr, erec, park,
                                           bias[2], h0, out, N);
}

// Round 5
// 483.314 us; speedup vs baseline: 3.0080x; 1.3800x over previous
//
#include <hip/hip_runtime.h>
#include <math.h>

// ---------------------------------------------------------------------------
// ImprovedCrossBorderGNN: 3-layer edge-conditioned GAT, N=50000, E=1.6M, H=128
// CSR (dst-grouped) built once; per layer: fp32 GEMM g=h@W (fused a_src/a_dst
// epilogue, bf16 g output), then wave-per-node online-softmax gather.
// R1: mean() via two-stage reduction (same-address fp32 atomics were 644us).
// R2: bf16 g gather payload; int4 edge record; parallel scans.
// R4: CSR via two-level counting sort (atomic-throughput-bound before).
// R5: GEMM was L1-BW-bound on 8x-redundant W reads (105us @ 15% VALU).
//     Register-blocked: 64 rows/block, 8 rows x 4 cols per thread -> W reuse
//     in registers, W L1 traffic /8. Same fp32 math order (absmax unchanged).
// ---------------------------------------------------------------------------

#define H 128
#define NF 8
#define EPB 4096  // edges per block in K1/K3 (256 threads x 16)
#define GR 64     // rows per GEMM block

__device__ __forceinline__ float wred_sum(float x) {
#pragma unroll
    for (int m = 32; m >= 1; m >>= 1) x += __shfl_xor(x, m, 64);
    return x;
}
__device__ __forceinline__ float wred_max(float x) {
#pragma unroll
    for (int m = 32; m >= 1; m >>= 1) x = fmaxf(x, __shfl_xor(x, m, 64));
    return x;
}
__device__ __forceinline__ ushort f2bf(float f) {
    uint u = __float_as_uint(f);
    uint r = (u + 0x7FFFu + ((u >> 16) & 1u)) >> 16;  // round-to-nearest-even
    return (ushort)r;
}

// ---- CSR build: two-level counting sort (no per-edge global atomics) -------

__global__ void k_count(const int* __restrict__ ei, const float* __restrict__ ea,
                        int E, int nblk, int nbuckets, int* __restrict__ bucketTotal,
                        int* __restrict__ blockBase, float2* __restrict__ pmean) {
    __shared__ int hist[256];
    __shared__ float sx[4], sy[4];
    int t = threadIdx.x;  // 256
    int blk = blockIdx.x;
    hist[t] = 0;
    __syncthreads();
    int base = blk * EPB;
    float px = 0.f, py = 0.f;
#pragma unroll
    for (int i = 0; i < 16; ++i) {
        int e = base + i * 256 + t;
        if (e < E) {
            int d = ei[E + e];
            atomicAdd(&hist[d >> 8], 1);
            const float2 z = *(const float2*)(ea + 2 * (size_t)e);
            px += z.x; py += z.y;
        }
    }
    px = wred_sum(px); py = wred_sum(py);
    if ((t & 63) == 0) { sx[t >> 6] = px; sy[t >> 6] = py; }
    __syncthreads();
    if (t == 0) {
        pmean[blk] = make_float2(sx[0] + sx[1] + sx[2] + sx[3],
                                 sy[0] + sy[1] + sy[2] + sy[3]);
    }
    if (t < nbuckets) {
        int c = hist[t];
        int old = (c > 0) ? atomicAdd(&bucketTotal[t], c) : 0;
        blockBase[t * nblk + blk] = old;
    }
}

__global__ void k_scan_park(const int* __restrict__ bucketTotal, int nbuckets,
                            int* __restrict__ bucketBase, int* __restrict__ rowptr,
                            int N, int E, const float2* __restrict__ pmean, int nblk,
                            float invE,
                            const float* __restrict__ We1, const float* __restrict__ ae1,
                            const float* __restrict__ We2, const float* __restrict__ ae2,
                            const float* __restrict__ We3, const float* __restrict__ ae3,
                            float* __restrict__ park) {
    __shared__ int tmp[256];
    __shared__ float2 sp[4];
    __shared__ float smean[2];
    int t = threadIdx.x;  // 256
    float ax = 0.f, ay = 0.f;
    for (int i = t; i < nblk; i += 256) {
        float2 z = pmean[i];
        ax += z.x; ay += z.y;
    }
    ax = wred_sum(ax); ay = wred_sum(ay);
    if ((t & 63) == 0) sp[t >> 6] = make_float2(ax, ay);
    int v = (t < nbuckets) ? bucketTotal[t] : 0;
    tmp[t] = v;
    __syncthreads();
    for (int off = 1; off < 256; off <<= 1) {
        int q = (t >= off) ? tmp[t - off] : 0;
        __syncthreads();
        tmp[t] += q;
        __syncthreads();
    }
    bucketBase[t] = tmp[t] - v;  // exclusive; entries >= nbuckets hold E
    if (t == 0) {
        bucketBase[256] = tmp[255];  // == E
        rowptr[N] = E;
        smean[0] = (sp[0].x + sp[1].x + sp[2].x + sp[3].x) * invE;
        smean[1] = (sp[0].y + sp[1].y + sp[2].y + sp[3].y) * invE;
    }
    __syncthreads();
    if (t < 192) {
        int l = t >> 6, q = t & 63;
        const float* We = (l == 0) ? We1 : ((l == 1) ? We2 : We3);
        const float* ae = (l == 0) ? ae1 : ((l == 1) ? ae2 : ae3);
        float p0 = We[q] * ae[q] + We[q + 64] * ae[q + 64];
        float p1 = We[H + q] * ae[q] + We[H + q + 64] * ae[q + 64];
        p0 = wred_sum(p0);
        p1 = wred_sum(p1);
        if (q == 0) {
            park[l * 3 + 0] = p0;
            park[l * 3 + 1] = p1;
            park[l * 3 + 2] = smean[0] * p0 + smean[1] * p1;
        }
    }
}

__global__ void k_place(const int* __restrict__ ei, const float* __restrict__ ea,
                        int E, int nblk, int nbuckets,
                        const int* __restrict__ bucketBase, const int* __restrict__ blockBase,
                        uint2* __restrict__ temp) {
    __shared__ int cnt[256];
    __shared__ int sbase[256];
    int t = threadIdx.x;  // 256
    int blk = blockIdx.x;
    cnt[t] = 0;
    if (t < nbuckets) sbase[t] = bucketBase[t] + blockBase[t * nblk + blk];
    __syncthreads();
    int base = blk * EPB;
#pragma unroll
    for (int i = 0; i < 16; ++i) {
        int e = base + i * 256 + t;
        if (e < E) {
            int s = ei[e];          // s < 65536 (N=50000)
            int d = ei[E + e];
            int b = d >> 8;
            int r = atomicAdd(&cnt[b], 1);
            const float2 z = *(const float2*)(ea + 2 * (size_t)e);
            uint w0 = (uint)s | ((uint)(d & 255) << 16);
            uint w1 = (uint)f2bf(z.x) | ((uint)f2bf(z.y) << 16);
            temp[sbase[b] + r] = make_uint2(w0, w1);
        }
    }
}

__global__ void k_fine(const uint2* __restrict__ temp, const int* __restrict__ bucketBase,
                       const float* __restrict__ park, int N,
                       int4* __restrict__ erec, int* __restrict__ rowptr) {
    __shared__ int hist[256];
    __shared__ int tmp[256];
    __shared__ int fb[256];
    __shared__ int cur[256];
    int b = blockIdx.x;
    int t = threadIdx.x;  // 256
    const int lo = bucketBase[b], hi = bucketBase[b + 1];
    hist[t] = 0;
    __syncthreads();
    for (int e = lo + t; e < hi; e += 256) {
        atomicAdd(&hist[(temp[e].x >> 16) & 255], 1);
    }
    __syncthreads();
    int v = hist[t];
    tmp[t] = v;
    __syncthreads();
    for (int off = 1; off < 256; off <<= 1) {
        int q = (t >= off) ? tmp[t - off] : 0;
        __syncthreads();
        tmp[t] += q;
        __syncthreads();
    }
    fb[t] = tmp[t] - v;  // exclusive within bucket
    cur[t] = 0;
    int dst = b * 256 + t;
    if (dst < N) rowptr[dst] = lo + fb[t];
    __syncthreads();
    const float c00 = park[0], c01 = park[1];
    const float c10 = park[3], c11 = park[4];
    const float c20 = park[6], c21 = park[7];
    for (int e = lo + t; e < hi; e += 256) {
        uint2 w = temp[e];
        int src = (int)(w.x & 0xFFFFu);
        int j = (int)((w.x >> 16) & 255u);
        float ex = __uint_as_float(w.y << 16);
        float ey = __uint_as_float(w.y & 0xffff0000u);
        int r = atomicAdd(&cur[j], 1);
        float f0 = c00 * ex + c01 * ey;
        float f1 = c10 * ex + c11 * ey;
        float f2 = c20 * ex + c21 * ey;
        erec[lo + fb[j] + r] = make_int4(src, __float_as_int(f0),
                                         __float_as_int(f1), __float_as_int(f2));
    }
}

// ---- encoder: h0 = relu((x @ enc_W + b) * bn_g*inv + bn_b) -----------------
__global__ void k_encoder(const float* __restrict__ x, const float* __restrict__ encW,
                          const float* __restrict__ encb, const float* __restrict__ bng,
                          const float* __restrict__ bnb, float* __restrict__ h0, int N) {
    __shared__ float xs[8 * NF];
    int tid = threadIdx.x;
    int nb = blockIdx.x * 8;
    if (tid < 64) {
        size_t idx = (size_t)nb * NF + tid;
        xs[tid] = (idx < (size_t)N * NF) ? x[idx] : 0.f;
    }
    __syncthreads();
    int jt = tid & 31, i = tid >> 5;
    int node = nb + i;
    int j4 = jt * 4;
    float ax = 0.f, ay = 0.f, az = 0.f, aw = 0.f;
#pragma unroll
    for (int k = 0; k < NF; ++k) {
        float hx = xs[i * NF + k];
        const float4 w = *(const float4*)(encW + k * H + j4);
        ax = fmaf(hx, w.x, ax); ay = fmaf(hx, w.y, ay);
        az = fmaf(hx, w.z, az); aw = fmaf(hx, w.w, aw);
    }
    if (node < N) {
        const float inv = 0.9999950000374997f;  // 1/sqrt(1+1e-5)
        const float4 eb = *(const float4*)(encb + j4);
        const float4 gg = *(const float4*)(bng + j4);
        const float4 bb = *(const float4*)(bnb + j4);
        float4 o;
        o.x = fmaxf(0.f, (ax + eb.x) * (gg.x * inv) + bb.x);
        o.y = fmaxf(0.f, (ay + eb.y) * (gg.y * inv) + bb.y);
        o.z = fmaxf(0.f, (az + eb.z) * (gg.z * inv) + bb.z);
        o.w = fmaxf(0.f, (aw + eb.w) * (gg.w * inv) + bb.w);
        *(float4*)(h0 + (size_t)node * H + j4) = o;
    }
}

// ---- per-layer GEMM: g = h @ W (bf16 out), register-blocked 8x4 ------------
// 64 rows/block, 256 threads: thread (ig=tid>>5, jt=tid&31) computes rows
// ig*8..ig*8+7 x cols jt*4..jt*4+3. h staged in LDS (broadcast reads, <=2-way
// conflict = free); W streamed from L1 once per block instead of 8x.
__global__ void k_gemm(const float* __restrict__ h, const float* __restrict__ W,
                       const float* __restrict__ avs, const float* __restrict__ avd,
                       ushort* __restrict__ gb, float* __restrict__ a_src,
                       float* __restrict__ a_dst, int N) {
    __shared__ float hs[GR * H];  // 32 KB
    int tid = threadIdx.x;
    int nb = blockIdx.x * GR;
#pragma unroll
    for (int it = 0; it < 8; ++it) {
        int fi = it * 256 + tid;      // float4 index within 64x128 tile
        int r = fi >> 5;              // 32 float4 per row
        int c4 = (fi & 31) * 4;
        int node = nb + r;
        float4 v = make_float4(0.f, 0.f, 0.f, 0.f);
        if (node < N) v = *(const float4*)(h + (size_t)node * H + c4);
        *(float4*)(hs + r * H + c4) = v;
    }
    __syncthreads();
    const int jt = tid & 31;
    const int ig = tid >> 5;
    const int j4 = jt * 4;
    const int r0 = ig * 8;

    float acc[8][4];
#pragma unroll
    for (int r = 0; r < 8; ++r)
#pragma unroll
        for (int c = 0; c < 4; ++c) acc[r][c] = 0.f;

    for (int k = 0; k < H; k += 4) {
        const float4 w0 = *(const float4*)(W + (k + 0) * H + j4);
        const float4 w1 = *(const float4*)(W + (k + 1) * H + j4);
        const float4 w2 = *(const float4*)(W + (k + 2) * H + j4);
        const float4 w3 = *(const float4*)(W + (k + 3) * H + j4);
#pragma unroll
        for (int r = 0; r < 8; ++r) {
            const float4 hv = *(const float4*)(hs + (r0 + r) * H + k);
            acc[r][0] = fmaf(hv.x, w0.x, acc[r][0]);
            acc[r][1] = fmaf(hv.x, w0.y, acc[r][1]);
            acc[r][2] = fmaf(hv.x, w0.z, acc[r][2]);
            acc[r][3] = fmaf(hv.x, w0.w, acc[r][3]);
            acc[r][0] = fmaf(hv.y, w1.x, acc[r][0]);
            acc[r][1] = fmaf(hv.y, w1.y, acc[r][1]);
            acc[r][2] = fmaf(hv.y, w1.z, acc[r][2]);
            acc[r][3] = fmaf(hv.y, w1.w, acc[r][3]);
            acc[r][0] = fmaf(hv.z, w2.x, acc[r][0]);
            acc[r][1] = fmaf(hv.z, w2.y, acc[r][1]);
            acc[r][2] = fmaf(hv.z, w2.z, acc[r][2]);
            acc[r][3] = fmaf(hv.z, w2.w, acc[r][3]);
            acc[r][0] = fmaf(hv.w, w3.x, acc[r][0]);
            acc[r][1] = fmaf(hv.w, w3.y, acc[r][1]);
            acc[r][2] = fmaf(hv.w, w3.z, acc[r][2]);
            acc[r][3] = fmaf(hv.w, w3.w, acc[r][3]);
        }
    }

    // epilogue: attention dots (reduce over the 32 jt-lanes) + bf16 g store
    const float4 s4 = *(const float4*)(avs + j4);
    const float4 d4 = *(const float4*)(avd + j4);
#pragma unroll
    for (int r = 0; r < 8; ++r) {
        int node = nb + r0 + r;
        float ps = acc[r][0] * s4.x + acc[r][1] * s4.y + acc[r][2] * s4.z + acc[r][3] * s4.w;
        float pd = acc[r][0] * d4.x + acc[r][1] * d4.y + acc[r][2] * d4.z + acc[r][3] * d4.w;
#pragma unroll
        for (int mm = 16; mm >= 1; mm >>= 1) {
            ps += __shfl_xor(ps, mm, 64);  // stays within 32-lane half (masks <32)
            pd += __shfl_xor(pd, mm, 64);
        }
        if (node < N) {
            ushort4 o;
            o.x = f2bf(acc[r][0]); o.y = f2bf(acc[r][1]);
            o.z = f2bf(acc[r][2]); o.w = f2bf(acc[r][3]);
            *(ushort4*)(gb + (size_t)node * H + j4) = o;
            if (jt == 0) {
                a_src[node] = ps;
                a_dst[node] = pd;
            }
        }
    }
}

// ---- aggregation: wave per node, online softmax, bf16 gather --------------
template <int RELU, int ADDH0, int LAYER>
__global__ void k_agg(const ushort* __restrict__ gb, const float* __restrict__ a_src,
                      const float* __restrict__ a_dst, const int* __restrict__ rowptr,
                      const int4* __restrict__ erec, const float* __restrict__ park,
                      const float* __restrict__ bias, const float* __restrict__ h0,
                      float* __restrict__ out, int N) {
    int wv = threadIdx.x >> 6;
    int lane = threadIdx.x & 63;
    int v = blockIdx.x * 4 + wv;
    if (v >= N) return;

    const float sa = park[LAYER * 3 + 2];
    const float adv = a_dst[v];
    float lself = a_src[v] + adv + sa;
    lself = (lself > 0.f) ? lself : 0.2f * lself;

    float m = lself;   // running max (self-loop included)
    float s = 1.f;     // running sum, w_self = exp(0) = 1
    const int ch = lane * 2;
    uint qv = *(const uint*)(gb + (size_t)v * H + ch);
    float acc0 = __uint_as_float(qv << 16);
    float acc1 = __uint_as_float(qv & 0xffff0000u);

    const int rs = rowptr[v];
    const int re = rowptr[v + 1];
    for (int p0 = rs; p0 < re; p0 += 64) {
        int e = p0 + lane;
        bool val = e < re;
        int4 rec = val ? erec[e] : make_int4(0, 0, 0, 0);
        int sv = rec.x;
        float lg;
        if (val) {
            float aef = __int_as_float(LAYER == 0 ? rec.y : (LAYER == 1 ? rec.z : rec.w));
            lg = a_src[sv] + adv + aef;
            lg = (lg > 0.f) ? lg : 0.2f * lg;
        } else {
            lg = -INFINITY;
        }
        float cm = wred_max(lg);
        float nm = fmaxf(m, cm);
        float f = __expf(m - nm);
        float w = val ? __expf(lg - nm) : 0.f;
        float ws = wred_sum(w);
        s = s * f + ws;
        acc0 *= f;
        acc1 *= f;
        m = nm;
        int cnt = re - p0;
        if (cnt > 64) cnt = 64;
        for (int j = 0; j < cnt; ++j) {
            float wj = __int_as_float(__builtin_amdgcn_readlane(__float_as_int(w), j));
            int sj = __builtin_amdgcn_readlane(sv, j);
            uint q = *(const uint*)(gb + (size_t)sj * H + ch);
            acc0 = fmaf(wj, __uint_as_float(q << 16), acc0);
            acc1 = fmaf(wj, __uint_as_float(q & 0xffff0000u), acc1);
        }
    }
    const float is = 1.f / s;
    const float2 bz = *(const float2*)(bias + ch);
    float o0 = acc0 * is + bz.x;
    float o1 = acc1 * is + bz.y;
    if (ADDH0) {
        const float2 hz = *(const float2*)(h0 + (size_t)v * H + ch);
        o0 += hz.x;
        o1 += hz.y;
    }
    if (RELU) {
        o0 = fmaxf(o0, 0.f);
        o1 = fmaxf(o1, 0.f);
    }
    *(float2*)(out + (size_t)v * H + ch) = make_float2(o0, o1);
}

// ---------------------------------------------------------------------------

extern "C" void kernel_launch(void* const* d_in, const int* in_sizes, int n_in,
                              void* d_out, int out_size, void* d_ws, size_t ws_size,
                              hipStream_t stream) {
    const float* x    = (const float*)d_in[0];
    const int*   ei   = (const int*)d_in[1];
    const float* ea   = (const float*)d_in[2];
    const float* encW = (const float*)d_in[3];
    const float* encb = (const float*)d_in[4];
    const float* bng  = (const float*)d_in[5];
    const float* bnb  = (const float*)d_in[6];
    const float *W[3], *asrc[3], *adst[3], *We[3], *aev[3], *bias[3];
    for (int l = 0; l < 3; ++l) {
        W[l]    = (const float*)d_in[7 + l * 6 + 0];
        asrc[l] = (const float*)d_in[7 + l * 6 + 1];
        adst[l] = (const float*)d_in[7 + l * 6 + 2];
        We[l]   = (const float*)d_in[7 + l * 6 + 3];
        aev[l]  = (const float*)d_in[7 + l * 6 + 4];
        bias[l] = (const float*)d_in[7 + l * 6 + 5];
    }
    const int N = in_sizes[0] / NF;   // 50000 (< 65536: src packs in 16 bits)
    const int E = in_sizes[1] / 2;
    float* out = (float*)d_out;

    const int NBu  = (N + 255) >> 8;          // coarse buckets (196)
    const int nblk = (E + EPB - 1) / EPB;     // K1/K3 blocks (391)

    // workspace carve-up (256B aligned)
    char* wp = (char*)d_ws;
    auto alloc = [&](size_t bytes) -> char* {
        char* p = wp;
        wp += (bytes + 255) & ~(size_t)255;
        return p;
    };
    float*  h0       = (float*)alloc((size_t)N * H * 4);
    float*  hA       = (float*)alloc((size_t)N * H * 4);   // temp overlays here
    ushort* gb       = (ushort*)alloc((size_t)N * H * 2);
    float*  a_src    = (float*)alloc((size_t)N * 4);
    float*  a_dst    = (float*)alloc((size_t)N * 4);
    int*    rowptr   = (int*)alloc((size_t)(N + 1) * 4);
    float*  park     = (float*)alloc(64);
    int*    bucketTotal = (int*)alloc(256 * 4);
    int*    bucketBase  = (int*)alloc(257 * 4);
    int*    blockBase   = (int*)alloc((size_t)NBu * nblk * 4);
    int4*   erec     = (int4*)alloc((size_t)E * 16);
    float2* pmean    = (float2*)alloc((size_t)nblk * 8);
    uint2*  temp     = (uint2*)hA;  // E*8 bytes <= N*H*4; dead before hA is written

    hipMemsetAsync(bucketTotal, 0, 256 * 4, stream);

    k_count<<<nblk, 256, 0, stream>>>(ei, ea, E, nblk, NBu, bucketTotal, blockBase, pmean);
    k_scan_park<<<1, 256, 0, stream>>>(bucketTotal, NBu, bucketBase, rowptr, N, E,
                                       pmean, nblk, 1.0f / (float)E,
                                       We[0], aev[0], We[1], aev[1], We[2], aev[2], park);
    k_place<<<nblk, 256, 0, stream>>>(ei, ea, E, nblk, NBu, bucketBase, blockBase, temp);
    k_fine<<<NBu, 256, 0, stream>>>(temp, bucketBase, park, N, erec, rowptr);

    const int GB8 = (N + 7) / 8;
    const int GBR = (N + GR - 1) / GR;
    const int AB = (N + 3) / 4;
    k_encoder<<<GB8, 256, 0, stream>>>(x, encW, encb, bng, bnb, h0, N);

    // layer 1: h0 -> hA
    k_gemm<<<GBR, 256, 0, stream>>>(h0, W[0], asrc[0], adst[0], gb, a_src, a_dst, N);
    k_agg<1, 0, 0><<<AB, 256, 0, stream>>>(gb, a_src, a_dst, rowptr, erec, park,
                                           bias[0], nullptr, hA, N);
    // layer 2: hA -> hA
    k_gemm<<<GBR, 256, 0, stream>>>(hA, W[1], asrc[1], adst[1], gb, a_src, a_dst, N);
    k_agg<1, 0, 1><<<AB, 256, 0, stream>>>(gb, a_src, a_dst, rowptr, erec, park,
                                           bias[1], nullptr, hA, N);
    // layer 3: hA -> out (+h0, no relu)
    k_gemm<<<GBR, 256, 0, stream>>>(hA, W[2], asrc[2], adst[2], gb, a_src, a_dst, N);
    k_agg<0, 1, 2><<<AB, 256, 0, stream>>>(gb, a_src, a_dst, rowptr, erec, park,
                                           bias[2], h0, out, N);
}

// Round 6
// 364.547 us; speedup vs baseline: 3.9879x; 1.3258x over previous
//
#include <hip/hip_runtime.h>
#include <math.h>

// ---------------------------------------------------------------------------
// ImprovedCrossBorderGNN: 3-layer edge-conditioned GAT, N=50000, E=1.6M, H=128
// CSR (dst-grouped) built once; per layer: fp32 GEMM g=h@W (fused a_src/a_dst
// epilogue, bf16 g output), then wave-per-node online-softmax gather.
// R1: mean() via two-stage reduction (same-address fp32 atomics were 644us).
// R2: bf16 g gather payload; int4 edge record; parallel scans.
// R4: CSR via two-level counting sort (atomic-throughput-bound before).
// R5: register-blocked GEMM (was L1-BW-bound on 8x-redundant W reads).
// R6: agg gather was memory-latency/MLP-bound (31% VALU, 26% HBM, 4B/lane
//     loads). Serial loop now processes 4 edges/iter: 16 lanes x 16B per row,
//     4x outstanding bytes per vmcnt slot; w/src spread via bpermute shfl.
// ---------------------------------------------------------------------------

#define H 128
#define NF 8
#define EPB 4096  // edges per block in K1/K3 (256 threads x 16)
#define GR 64     // rows per GEMM block

__device__ __forceinline__ float wred_sum(float x) {
#pragma unroll
    for (int m = 32; m >= 1; m >>= 1) x += __shfl_xor(x, m, 64);
    return x;
}
__device__ __forceinline__ float wred_max(float x) {
#pragma unroll
    for (int m = 32; m >= 1; m >>= 1) x = fmaxf(x, __shfl_xor(x, m, 64));
    return x;
}
__device__ __forceinline__ ushort f2bf(float f) {
    uint u = __float_as_uint(f);
    uint r = (u + 0x7FFFu + ((u >> 16) & 1u)) >> 16;  // round-to-nearest-even
    return (ushort)r;
}

// ---- CSR build: two-level counting sort (no per-edge global atomics) -------

__global__ void k_count(const int* __restrict__ ei, const float* __restrict__ ea,
                        int E, int nblk, int nbuckets, int* __restrict__ bucketTotal,
                        int* __restrict__ blockBase, float2* __restrict__ pmean) {
    __shared__ int hist[256];
    __shared__ float sx[4], sy[4];
    int t = threadIdx.x;  // 256
    int blk = blockIdx.x;
    hist[t] = 0;
    __syncthreads();
    int base = blk * EPB;
    float px = 0.f, py = 0.f;
#pragma unroll
    for (int i = 0; i < 16; ++i) {
        int e = base + i * 256 + t;
        if (e < E) {
            int d = ei[E + e];
            atomicAdd(&hist[d >> 8], 1);
            const float2 z = *(const float2*)(ea + 2 * (size_t)e);
            px += z.x; py += z.y;
        }
    }
    px = wred_sum(px); py = wred_sum(py);
    if ((t & 63) == 0) { sx[t >> 6] = px; sy[t >> 6] = py; }
    __syncthreads();
    if (t == 0) {
        pmean[blk] = make_float2(sx[0] + sx[1] + sx[2] + sx[3],
                                 sy[0] + sy[1] + sy[2] + sy[3]);
    }
    if (t < nbuckets) {
        int c = hist[t];
        int old = (c > 0) ? atomicAdd(&bucketTotal[t], c) : 0;
        blockBase[t * nblk + blk] = old;
    }
}

__global__ void k_scan_park(const int* __restrict__ bucketTotal, int nbuckets,
                            int* __restrict__ bucketBase, int* __restrict__ rowptr,
                            int N, int E, const float2* __restrict__ pmean, int nblk,
                            float invE,
                            const float* __restrict__ We1, const float* __restrict__ ae1,
                            const float* __restrict__ We2, const float* __restrict__ ae2,
                            const float* __restrict__ We3, const float* __restrict__ ae3,
                            float* __restrict__ park) {
    __shared__ int tmp[256];
    __shared__ float2 sp[4];
    __shared__ float smean[2];
    int t = threadIdx.x;  // 256
    float ax = 0.f, ay = 0.f;
    for (int i = t; i < nblk; i += 256) {
        float2 z = pmean[i];
        ax += z.x; ay += z.y;
    }
    ax = wred_sum(ax); ay = wred_sum(ay);
    if ((t & 63) == 0) sp[t >> 6] = make_float2(ax, ay);
    int v = (t < nbuckets) ? bucketTotal[t] : 0;
    tmp[t] = v;
    __syncthreads();
    for (int off = 1; off < 256; off <<= 1) {
        int q = (t >= off) ? tmp[t - off] : 0;
        __syncthreads();
        tmp[t] += q;
        __syncthreads();
    }
    bucketBase[t] = tmp[t] - v;  // exclusive; entries >= nbuckets hold E
    if (t == 0) {
        bucketBase[256] = tmp[255];  // == E
        rowptr[N] = E;
        smean[0] = (sp[0].x + sp[1].x + sp[2].x + sp[3].x) * invE;
        smean[1] = (sp[0].y + sp[1].y + sp[2].y + sp[3].y) * invE;
    }
    __syncthreads();
    if (t < 192) {
        int l = t >> 6, q = t & 63;
        const float* We = (l == 0) ? We1 : ((l == 1) ? We2 : We3);
        const float* ae = (l == 0) ? ae1 : ((l == 1) ? ae2 : ae3);
        float p0 = We[q] * ae[q] + We[q + 64] * ae[q + 64];
        float p1 = We[H + q] * ae[q] + We[H + q + 64] * ae[q + 64];
        p0 = wred_sum(p0);
        p1 = wred_sum(p1);
        if (q == 0) {
            park[l * 3 + 0] = p0;
            park[l * 3 + 1] = p1;
            park[l * 3 + 2] = smean[0] * p0 + smean[1] * p1;
        }
    }
}

__global__ void k_place(const int* __restrict__ ei, const float* __restrict__ ea,
                        int E, int nblk, int nbuckets,
                        const int* __restrict__ bucketBase, const int* __restrict__ blockBase,
                        uint2* __restrict__ temp) {
    __shared__ int cnt[256];
    __shared__ int sbase[256];
    int t = threadIdx.x;  // 256
    int blk = blockIdx.x;
    cnt[t] = 0;
    if (t < nbuckets) sbase[t] = bucketBase[t] + blockBase[t * nblk + blk];
    __syncthreads();
    int base = blk * EPB;
#pragma unroll
    for (int i = 0; i < 16; ++i) {
        int e = base + i * 256 + t;
        if (e < E) {
            int s = ei[e];          // s < 65536 (N=50000)
            int d = ei[E + e];
            int b = d >> 8;
            int r = atomicAdd(&cnt[b], 1);
            const float2 z = *(const float2*)(ea + 2 * (size_t)e);
            uint w0 = (uint)s | ((uint)(d & 255) << 16);
            uint w1 = (uint)f2bf(z.x) | ((uint)f2bf(z.y) << 16);
            temp[sbase[b] + r] = make_uint2(w0, w1);
        }
    }
}

__global__ void k_fine(const uint2* __restrict__ temp, const int* __restrict__ bucketBase,
                       const float* __restrict__ park, int N,
                       int4* __restrict__ erec, int* __restrict__ rowptr) {
    __shared__ int hist[256];
    __shared__ int tmp[256];
    __shared__ int fb[256];
    __shared__ int cur[256];
    int b = blockIdx.x;
    int t = threadIdx.x;  // 256
    const int lo = bucketBase[b], hi = bucketBase[b + 1];
    hist[t] = 0;
    __syncthreads();
    for (int e = lo + t; e < hi; e += 256) {
        atomicAdd(&hist[(temp[e].x >> 16) & 255], 1);
    }
    __syncthreads();
    int v = hist[t];
    tmp[t] = v;
    __syncthreads();
    for (int off = 1; off < 256; off <<= 1) {
        int q = (t >= off) ? tmp[t - off] : 0;
        __syncthreads();
        tmp[t] += q;
        __syncthreads();
    }
    fb[t] = tmp[t] - v;  // exclusive within bucket
    cur[t] = 0;
    int dst = b * 256 + t;
    if (dst < N) rowptr[dst] = lo + fb[t];
    __syncthreads();
    const float c00 = park[0], c01 = park[1];
    const float c10 = park[3], c11 = park[4];
    const float c20 = park[6], c21 = park[7];
    for (int e = lo + t; e < hi; e += 256) {
        uint2 w = temp[e];
        int src = (int)(w.x & 0xFFFFu);
        int j = (int)((w.x >> 16) & 255u);
        float ex = __uint_as_float(w.y << 16);
        float ey = __uint_as_float(w.y & 0xffff0000u);
        int r = atomicAdd(&cur[j], 1);
        float f0 = c00 * ex + c01 * ey;
        float f1 = c10 * ex + c11 * ey;
        float f2 = c20 * ex + c21 * ey;
        erec[lo + fb[j] + r] = make_int4(src, __float_as_int(f0),
                                         __float_as_int(f1), __float_as_int(f2));
    }
}

// ---- encoder: h0 = relu((x @ enc_W + b) * bn_g*inv + bn_b) -----------------
__global__ void k_encoder(const float* __restrict__ x, const float* __restrict__ encW,
                          const float* __restrict__ encb, const float* __restrict__ bng,
                          const float* __restrict__ bnb, float* __restrict__ h0, int N) {
    __shared__ float xs[8 * NF];
    int tid = threadIdx.x;
    int nb = blockIdx.x * 8;
    if (tid < 64) {
        size_t idx = (size_t)nb * NF + tid;
        xs[tid] = (idx < (size_t)N * NF) ? x[idx] : 0.f;
    }
    __syncthreads();
    int jt = tid & 31, i = tid >> 5;
    int node = nb + i;
    int j4 = jt * 4;
    float ax = 0.f, ay = 0.f, az = 0.f, aw = 0.f;
#pragma unroll
    for (int k = 0; k < NF; ++k) {
        float hx = xs[i * NF + k];
        const float4 w = *(const float4*)(encW + k * H + j4);
        ax = fmaf(hx, w.x, ax); ay = fmaf(hx, w.y, ay);
        az = fmaf(hx, w.z, az); aw = fmaf(hx, w.w, aw);
    }
    if (node < N) {
        const float inv = 0.9999950000374997f;  // 1/sqrt(1+1e-5)
        const float4 eb = *(const float4*)(encb + j4);
        const float4 gg = *(const float4*)(bng + j4);
        const float4 bb = *(const float4*)(bnb + j4);
        float4 o;
        o.x = fmaxf(0.f, (ax + eb.x) * (gg.x * inv) + bb.x);
        o.y = fmaxf(0.f, (ay + eb.y) * (gg.y * inv) + bb.y);
        o.z = fmaxf(0.f, (az + eb.z) * (gg.z * inv) + bb.z);
        o.w = fmaxf(0.f, (aw + eb.w) * (gg.w * inv) + bb.w);
        *(float4*)(h0 + (size_t)node * H + j4) = o;
    }
}

// ---- per-layer GEMM: g = h @ W (bf16 out), register-blocked 8x4 ------------
__global__ void k_gemm(const float* __restrict__ h, const float* __restrict__ W,
                       const float* __restrict__ avs, const float* __restrict__ avd,
                       ushort* __restrict__ gb, float* __restrict__ a_src,
                       float* __restrict__ a_dst, int N) {
    __shared__ float hs[GR * H];  // 32 KB
    int tid = threadIdx.x;
    int nb = blockIdx.x * GR;
#pragma unroll
    for (int it = 0; it < 8; ++it) {
        int fi = it * 256 + tid;      // float4 index within 64x128 tile
        int r = fi >> 5;              // 32 float4 per row
        int c4 = (fi & 31) * 4;
        int node = nb + r;
        float4 v = make_float4(0.f, 0.f, 0.f, 0.f);
        if (node < N) v = *(const float4*)(h + (size_t)node * H + c4);
        *(float4*)(hs + r * H + c4) = v;
    }
    __syncthreads();
    const int jt = tid & 31;
    const int ig = tid >> 5;
    const int j4 = jt * 4;
    const int r0 = ig * 8;

    float acc[8][4];
#pragma unroll
    for (int r = 0; r < 8; ++r)
#pragma unroll
        for (int c = 0; c < 4; ++c) acc[r][c] = 0.f;

    for (int k = 0; k < H; k += 4) {
        const float4 w0 = *(const float4*)(W + (k + 0) * H + j4);
        const float4 w1 = *(const float4*)(W + (k + 1) * H + j4);
        const float4 w2 = *(const float4*)(W + (k + 2) * H + j4);
        const float4 w3 = *(const float4*)(W + (k + 3) * H + j4);
#pragma unroll
        for (int r = 0; r < 8; ++r) {
            const float4 hv = *(const float4*)(hs + (r0 + r) * H + k);
            acc[r][0] = fmaf(hv.x, w0.x, acc[r][0]);
            acc[r][1] = fmaf(hv.x, w0.y, acc[r][1]);
            acc[r][2] = fmaf(hv.x, w0.z, acc[r][2]);
            acc[r][3] = fmaf(hv.x, w0.w, acc[r][3]);
            acc[r][0] = fmaf(hv.y, w1.x, acc[r][0]);
            acc[r][1] = fmaf(hv.y, w1.y, acc[r][1]);
            acc[r][2] = fmaf(hv.y, w1.z, acc[r][2]);
            acc[r][3] = fmaf(hv.y, w1.w, acc[r][3]);
            acc[r][0] = fmaf(hv.z, w2.x, acc[r][0]);
            acc[r][1] = fmaf(hv.z, w2.y, acc[r][1]);
            acc[r][2] = fmaf(hv.z, w2.z, acc[r][2]);
            acc[r][3] = fmaf(hv.z, w2.w, acc[r][3]);
            acc[r][0] = fmaf(hv.w, w3.x, acc[r][0]);
            acc[r][1] = fmaf(hv.w, w3.y, acc[r][1]);
            acc[r][2] = fmaf(hv.w, w3.z, acc[r][2]);
            acc[r][3] = fmaf(hv.w, w3.w, acc[r][3]);
        }
    }

    const float4 s4 = *(const float4*)(avs + j4);
    const float4 d4 = *(const float4*)(avd + j4);
#pragma unroll
    for (int r = 0; r < 8; ++r) {
        int node = nb + r0 + r;
        float ps = acc[r][0] * s4.x + acc[r][1] * s4.y + acc[r][2] * s4.z + acc[r][3] * s4.w;
        float pd = acc[r][0] * d4.x + acc[r][1] * d4.y + acc[r][2] * d4.z + acc[r][3] * d4.w;
#pragma unroll
        for (int mm = 16; mm >= 1; mm >>= 1) {
            ps += __shfl_xor(ps, mm, 64);  // stays within 32-lane half (masks <32)
            pd += __shfl_xor(pd, mm, 64);
        }
        if (node < N) {
            ushort4 o;
            o.x = f2bf(acc[r][0]); o.y = f2bf(acc[r][1]);
            o.z = f2bf(acc[r][2]); o.w = f2bf(acc[r][3]);
            *(ushort4*)(gb + (size_t)node * H + j4) = o;
            if (jt == 0) {
                a_src[node] = ps;
                a_dst[node] = pd;
            }
        }
    }
}

// ---- aggregation: wave per node, online softmax, 16B-wide bf16 gather ------
// Serial phase: 4 edges/iteration; 16-lane group per edge row, 16B per lane.
template <int RELU, int ADDH0, int LAYER>
__global__ void k_agg(const ushort* __restrict__ gb, const float* __restrict__ a_src,
                      const float* __restrict__ a_dst, const int* __restrict__ rowptr,
                      const int4* __restrict__ erec, const float* __restrict__ park,
                      const float* __restrict__ bias, const float* __restrict__ h0,
                      float* __restrict__ out, int N) {
    int wv = threadIdx.x >> 6;
    int lane = threadIdx.x & 63;
    int v = blockIdx.x * 4 + wv;
    if (v >= N) return;

    const int grp = lane >> 4;   // which of 4 edges this lane serves
    const int sub = lane & 15;   // position within the 256B row
    const int ch8 = sub * 8;     // 8 bf16 channels per lane

    const float sa = park[LAYER * 3 + 2];
    const float adv = a_dst[v];
    float lself = a_src[v] + adv + sa;
    lself = (lself > 0.f) ? lself : 0.2f * lself;

    float m = lself;   // running max (self-loop included)
    float s = 1.f;     // running sum, w_self = exp(0) = 1
    float acc[8];
    {
        const uint4 q = *(const uint4*)(gb + (size_t)v * H + ch8);
        float sel = (grp == 0) ? 1.f : 0.f;  // self contribution counted once
        acc[0] = sel * __uint_as_float(q.x << 16);
        acc[1] = sel * __uint_as_float(q.x & 0xffff0000u);
        acc[2] = sel * __uint_as_float(q.y << 16);
        acc[3] = sel * __uint_as_float(q.y & 0xffff0000u);
        acc[4] = sel * __uint_as_float(q.z << 16);
        acc[5] = sel * __uint_as_float(q.z & 0xffff0000u);
        acc[6] = sel * __uint_as_float(q.w << 16);
        acc[7] = sel * __uint_as_float(q.w & 0xffff0000u);
    }

    const int rs = rowptr[v];
    const int re = rowptr[v + 1];
    for (int p0 = rs; p0 < re; p0 += 64) {
        int e = p0 + lane;
        bool val = e < re;
        int4 rec = val ? erec[e] : make_int4(0, 0, 0, 0);
        int sv = rec.x;
        float lg;
        if (val) {
            float aef = __int_as_float(LAYER == 0 ? rec.y : (LAYER == 1 ? rec.z : rec.w));
            lg = a_src[sv] + adv + aef;
            lg = (lg > 0.f) ? lg : 0.2f * lg;
        } else {
            lg = -INFINITY;
        }
        float cm = wred_max(lg);
        float nm = fmaxf(m, cm);
        float f = __expf(m - nm);
        float w = val ? __expf(lg - nm) : 0.f;
        float ws = wred_sum(w);
        s = s * f + ws;
#pragma unroll
        for (int k = 0; k < 8; ++k) acc[k] *= f;
        m = nm;
        int cnt = re - p0;
        if (cnt > 64) cnt = 64;
        int iters = (cnt + 3) >> 2;
        for (int i = 0; i < iters; ++i) {
            int j = i * 4 + grp;
            float wj = __shfl(w, j, 64);
            int sj = __shfl(sv, j, 64);
            if (j < cnt) {
                const uint4 q = *(const uint4*)(gb + (size_t)sj * H + ch8);
                acc[0] = fmaf(wj, __uint_as_float(q.x << 16), acc[0]);
                acc[1] = fmaf(wj, __uint_as_float(q.x & 0xffff0000u), acc[1]);
                acc[2] = fmaf(wj, __uint_as_float(q.y << 16), acc[2]);
                acc[3] = fmaf(wj, __uint_as_float(q.y & 0xffff0000u), acc[3]);
                acc[4] = fmaf(wj, __uint_as_float(q.z << 16), acc[4]);
                acc[5] = fmaf(wj, __uint_as_float(q.z & 0xffff0000u), acc[5]);
                acc[6] = fmaf(wj, __uint_as_float(q.w << 16), acc[6]);
                acc[7] = fmaf(wj, __uint_as_float(q.w & 0xffff0000u), acc[7]);
            }
        }
    }

    // combine the 4 group-partials (lanes sub, sub+16, sub+32, sub+48)
#pragma unroll
    for (int k = 0; k < 8; ++k) {
        acc[k] += __shfl_xor(acc[k], 16, 64);
        acc[k] += __shfl_xor(acc[k], 32, 64);
    }

    if (grp == 0) {
        const float is = 1.f / s;
        const float4 b0 = *(const float4*)(bias + ch8);
        const float4 b1 = *(const float4*)(bias + ch8 + 4);
        float o[8];
        o[0] = acc[0] * is + b0.x; o[1] = acc[1] * is + b0.y;
        o[2] = acc[2] * is + b0.z; o[3] = acc[3] * is + b0.w;
        o[4] = acc[4] * is + b1.x; o[5] = acc[5] * is + b1.y;
        o[6] = acc[6] * is + b1.z; o[7] = acc[7] * is + b1.w;
        if (ADDH0) {
            const float4 ha = *(const float4*)(h0 + (size_t)v * H + ch8);
            const float4 hb = *(const float4*)(h0 + (size_t)v * H + ch8 + 4);
            o[0] += ha.x; o[1] += ha.y; o[2] += ha.z; o[3] += ha.w;
            o[4] += hb.x; o[5] += hb.y; o[6] += hb.z; o[7] += hb.w;
        }
        if (RELU) {
#pragma unroll
            for (int k = 0; k < 8; ++k) o[k] = fmaxf(o[k], 0.f);
        }
        *(float4*)(out + (size_t)v * H + ch8) = make_float4(o[0], o[1], o[2], o[3]);
        *(float4*)(out + (size_t)v * H + ch8 + 4) = make_float4(o[4], o[5], o[6], o[7]);
    }
}

// ---------------------------------------------------------------------------

extern "C" void kernel_launch(void* const* d_in, const int* in_sizes, int n_in,
                              void* d_out, int out_size, void* d_ws, size_t ws_size,
                              hipStream_t stream) {
    const float* x    = (const float*)d_in[0];
    const int*   ei   = (const int*)d_in[1];
    const float* ea   = (const float*)d_in[2];
    const float* encW = (const float*)d_in[3];
    const float* encb = (const float*)d_in[4];
    const float* bng  = (const float*)d_in[5];
    const float* bnb  = (const float*)d_in[6];
    const float *W[3], *asrc[3], *adst[3], *We[3], *aev[3], *bias[3];
    for (int l = 0; l < 3; ++l) {
        W[l]    = (const float*)d_in[7 + l * 6 + 0];
        asrc[l] = (const float*)d_in[7 + l * 6 + 1];
        adst[l] = (const float*)d_in[7 + l * 6 + 2];
        We[l]   = (const float*)d_in[7 + l * 6 + 3];
        aev[l]  = (const float*)d_in[7 + l * 6 + 4];
        bias[l] = (const float*)d_in[7 + l * 6 + 5];
    }
    const int N = in_sizes[0] / NF;   // 50000 (< 65536: src packs in 16 bits)
    const int E = in_sizes[1] / 2;
    float* out = (float*)d_out;

    const int NBu  = (N + 255) >> 8;          // coarse buckets (196)
    const int nblk = (E + EPB - 1) / EPB;     // K1/K3 blocks (391)

    // workspace carve-up (256B aligned)
    char* wp = (char*)d_ws;
    auto alloc = [&](size_t bytes) -> char* {
        char* p = wp;
        wp += (bytes + 255) & ~(size_t)255;
        return p;
    };
    float*  h0       = (float*)alloc((size_t)N * H * 4);
    float*  hA       = (float*)alloc((size_t)N * H * 4);   // temp overlays here
    ushort* gb       = (ushort*)alloc((size_t)N * H * 2);
    float*  a_src    = (float*)alloc((size_t)N * 4);
    float*  a_dst    = (float*)alloc((size_t)N * 4);
    int*    rowptr   = (int*)alloc((size_t)(N + 1) * 4);
    float*  park     = (float*)alloc(64);
    int*    bucketTotal = (int*)alloc(256 * 4);
    int*    bucketBase  = (int*)alloc(257 * 4);
    int*    blockBase   = (int*)alloc((size_t)NBu * nblk * 4);
    int4*   erec     = (int4*)alloc((size_t)E * 16);
    float2* pmean    = (float2*)alloc((size_t)nblk * 8);
    uint2*  temp     = (uint2*)hA;  // E*8 bytes <= N*H*4; dead before hA is written

    hipMemsetAsync(bucketTotal, 0, 256 * 4, stream);

    k_count<<<nblk, 256, 0, stream>>>(ei, ea, E, nblk, NBu, bucketTotal, blockBase, pmean);
    k_scan_park<<<1, 256, 0, stream>>>(bucketTotal, NBu, bucketBase, rowptr, N, E,
                                       pmean, nblk, 1.0f / (float)E,
                                       We[0], aev[0], We[1], aev[1], We[2], aev[2], park);
    k_place<<<nblk, 256, 0, stream>>>(ei, ea, E, nblk, NBu, bucketBase, blockBase, temp);
    k_fine<<<NBu, 256, 0, stream>>>(temp, bucketBase, park, N, erec, rowptr);

    const int GB8 = (N + 7) / 8;
    const int GBR = (N + GR - 1) / GR;
    const int AB = (N + 3) / 4;
    k_encoder<<<GB8, 256, 0, stream>>>(x, encW, encb, bng, bnb, h0, N);

    // layer 1: h0 -> hA
    k_gemm<<<GBR, 256, 0, stream>>>(h0, W[0], asrc[0], adst[0], gb, a_src, a_dst, N);
    k_agg<1, 0, 0><<<AB, 256, 0, stream>>>(gb, a_src, a_dst, rowptr, erec, park,
                                           bias[0], nullptr, hA, N);
    // layer 2: hA -> hA
    k_gemm<<<GBR, 256, 0, stream>>>(hA, W[1], asrc[1], adst[1], gb, a_src, a_dst, N);
    k_agg<1, 0, 1><<<AB, 256, 0, stream>>>(gb, a_src, a_dst, rowptr, erec, park,
                                           bias[1], nullptr, hA, N);
    // layer 3: hA -> out (+h0, no relu)
    k_gemm<<<GBR, 256, 0, stream>>>(hA, W[2], asrc[2], adst[2], gb, a_src, a_dst, N);
    k_agg<0, 1, 2><<<AB, 256, 0, stream>>>(gb, a_src, a_dst, rowptr, erec, park,
                                           bias[2], h0, out, N);
}

// Round 7
// 356.449 us; speedup vs baseline: 4.0785x; 1.0227x over previous
//
#include <hip/hip_runtime.h>
#include <math.h>

// ---------------------------------------------------------------------------
// ImprovedCrossBorderGNN: 3-layer edge-conditioned GAT, N=50000, E=1.6M, H=128
// CSR (dst-grouped) built once; per layer: fp32 GEMM g=h@W (fused a_src/a_dst
// epilogue, bf16 g output), then wave-per-node online-softmax gather.
// R1: mean() via two-stage reduction (same-address fp32 atomics were 644us).
// R2: bf16 g gather payload; int4 edge record; parallel scans.
// R4: CSR via two-level counting sort (atomic-throughput-bound before).
// R5: register-blocked GEMM (was L1-BW-bound on 8x-redundant W reads).
// R6: gather 4 edges/iter, 16 lanes x 16B (was 4B/lane latency-bound).
// R7: gather was still latency-bound (40% VALU, 2.8 TB/s L3): 8 edges per
//     super-iter (2 streams) + 1-stage software prefetch -> 4 outstanding
//     wave-loads; predication replaced by clamp+w=0 so loads always issue.
// ---------------------------------------------------------------------------

#define H 128
#define NF 8
#define EPB 4096  // edges per block in K1/K3 (256 threads x 16)
#define GR 64     // rows per GEMM block

__device__ __forceinline__ float wred_sum(float x) {
#pragma unroll
    for (int m = 32; m >= 1; m >>= 1) x += __shfl_xor(x, m, 64);
    return x;
}
__device__ __forceinline__ float wred_max(float x) {
#pragma unroll
    for (int m = 32; m >= 1; m >>= 1) x = fmaxf(x, __shfl_xor(x, m, 64));
    return x;
}
__device__ __forceinline__ ushort f2bf(float f) {
    uint u = __float_as_uint(f);
    uint r = (u + 0x7FFFu + ((u >> 16) & 1u)) >> 16;  // round-to-nearest-even
    return (ushort)r;
}

// ---- CSR build: two-level counting sort (no per-edge global atomics) -------

__global__ void k_count(const int* __restrict__ ei, const float* __restrict__ ea,
                        int E, int nblk, int nbuckets, int* __restrict__ bucketTotal,
                        int* __restrict__ blockBase, float2* __restrict__ pmean) {
    __shared__ int hist[256];
    __shared__ float sx[4], sy[4];
    int t = threadIdx.x;  // 256
    int blk = blockIdx.x;
    hist[t] = 0;
    __syncthreads();
    int base = blk * EPB;
    float px = 0.f, py = 0.f;
#pragma unroll
    for (int i = 0; i < 16; ++i) {
        int e = base + i * 256 + t;
        if (e < E) {
            int d = ei[E + e];
            atomicAdd(&hist[d >> 8], 1);
            const float2 z = *(const float2*)(ea + 2 * (size_t)e);
            px += z.x; py += z.y;
        }
    }
    px = wred_sum(px); py = wred_sum(py);
    if ((t & 63) == 0) { sx[t >> 6] = px; sy[t >> 6] = py; }
    __syncthreads();
    if (t == 0) {
        pmean[blk] = make_float2(sx[0] + sx[1] + sx[2] + sx[3],
                                 sy[0] + sy[1] + sy[2] + sy[3]);
    }
    if (t < nbuckets) {
        int c = hist[t];
        int old = (c > 0) ? atomicAdd(&bucketTotal[t], c) : 0;
        blockBase[t * nblk + blk] = old;
    }
}

__global__ void k_scan_park(const int* __restrict__ bucketTotal, int nbuckets,
                            int* __restrict__ bucketBase, int* __restrict__ rowptr,
                            int N, int E, const float2* __restrict__ pmean, int nblk,
                            float invE,
                            const float* __restrict__ We1, const float* __restrict__ ae1,
                            const float* __restrict__ We2, const float* __restrict__ ae2,
                            const float* __restrict__ We3, const float* __restrict__ ae3,
                            float* __restrict__ park) {
    __shared__ int tmp[256];
    __shared__ float2 sp[4];
    __shared__ float smean[2];
    int t = threadIdx.x;  // 256
    float ax = 0.f, ay = 0.f;
    for (int i = t; i < nblk; i += 256) {
        float2 z = pmean[i];
        ax += z.x; ay += z.y;
    }
    ax = wred_sum(ax); ay = wred_sum(ay);
    if ((t & 63) == 0) sp[t >> 6] = make_float2(ax, ay);
    int v = (t < nbuckets) ? bucketTotal[t] : 0;
    tmp[t] = v;
    __syncthreads();
    for (int off = 1; off < 256; off <<= 1) {
        int q = (t >= off) ? tmp[t - off] : 0;
        __syncthreads();
        tmp[t] += q;
        __syncthreads();
    }
    bucketBase[t] = tmp[t] - v;  // exclusive; entries >= nbuckets hold E
    if (t == 0) {
        bucketBase[256] = tmp[255];  // == E
        rowptr[N] = E;
        smean[0] = (sp[0].x + sp[1].x + sp[2].x + sp[3].x) * invE;
        smean[1] = (sp[0].y + sp[1].y + sp[2].y + sp[3].y) * invE;
    }
    __syncthreads();
    if (t < 192) {
        int l = t >> 6, q = t & 63;
        const float* We = (l == 0) ? We1 : ((l == 1) ? We2 : We3);
        const float* ae = (l == 0) ? ae1 : ((l == 1) ? ae2 : ae3);
        float p0 = We[q] * ae[q] + We[q + 64] * ae[q + 64];
        float p1 = We[H + q] * ae[q] + We[H + q + 64] * ae[q + 64];
        p0 = wred_sum(p0);
        p1 = wred_sum(p1);
        if (q == 0) {
            park[l * 3 + 0] = p0;
            park[l * 3 + 1] = p1;
            park[l * 3 + 2] = smean[0] * p0 + smean[1] * p1;
        }
    }
}

__global__ void k_place(const int* __restrict__ ei, const float* __restrict__ ea,
                        int E, int nblk, int nbuckets,
                        const int* __restrict__ bucketBase, const int* __restrict__ blockBase,
                        uint2* __restrict__ temp) {
    __shared__ int cnt[256];
    __shared__ int sbase[256];
    int t = threadIdx.x;  // 256
    int blk = blockIdx.x;
    cnt[t] = 0;
    if (t < nbuckets) sbase[t] = bucketBase[t] + blockBase[t * nblk + blk];
    __syncthreads();
    int base = blk * EPB;
#pragma unroll
    for (int i = 0; i < 16; ++i) {
        int e = base + i * 256 + t;
        if (e < E) {
            int s = ei[e];          // s < 65536 (N=50000)
            int d = ei[E + e];
            int b = d >> 8;
            int r = atomicAdd(&cnt[b], 1);
            const float2 z = *(const float2*)(ea + 2 * (size_t)e);
            uint w0 = (uint)s | ((uint)(d & 255) << 16);
            uint w1 = (uint)f2bf(z.x) | ((uint)f2bf(z.y) << 16);
            temp[sbase[b] + r] = make_uint2(w0, w1);
        }
    }
}

__global__ void k_fine(const uint2* __restrict__ temp, const int* __restrict__ bucketBase,
                       const float* __restrict__ park, int N,
                       int4* __restrict__ erec, int* __restrict__ rowptr) {
    __shared__ int hist[256];
    __shared__ int tmp[256];
    __shared__ int fb[256];
    __shared__ int cur[256];
    int b = blockIdx.x;
    int t = threadIdx.x;  // 256
    const int lo = bucketBase[b], hi = bucketBase[b + 1];
    hist[t] = 0;
    __syncthreads();
    for (int e = lo + t; e < hi; e += 256) {
        atomicAdd(&hist[(temp[e].x >> 16) & 255], 1);
    }
    __syncthreads();
    int v = hist[t];
    tmp[t] = v;
    __syncthreads();
    for (int off = 1; off < 256; off <<= 1) {
        int q = (t >= off) ? tmp[t - off] : 0;
        __syncthreads();
        tmp[t] += q;
        __syncthreads();
    }
    fb[t] = tmp[t] - v;  // exclusive within bucket
    cur[t] = 0;
    int dst = b * 256 + t;
    if (dst < N) rowptr[dst] = lo + fb[t];
    __syncthreads();
    const float c00 = park[0], c01 = park[1];
    const float c10 = park[3], c11 = park[4];
    const float c20 = park[6], c21 = park[7];
    for (int e = lo + t; e < hi; e += 256) {
        uint2 w = temp[e];
        int src = (int)(w.x & 0xFFFFu);
        int j = (int)((w.x >> 16) & 255u);
        float ex = __uint_as_float(w.y << 16);
        float ey = __uint_as_float(w.y & 0xffff0000u);
        int r = atomicAdd(&cur[j], 1);
        float f0 = c00 * ex + c01 * ey;
        float f1 = c10 * ex + c11 * ey;
        float f2 = c20 * ex + c21 * ey;
        erec[lo + fb[j] + r] = make_int4(src, __float_as_int(f0),
                                         __float_as_int(f1), __float_as_int(f2));
    }
}

// ---- encoder: h0 = relu((x @ enc_W + b) * bn_g*inv + bn_b) -----------------
__global__ void k_encoder(const float* __restrict__ x, const float* __restrict__ encW,
                          const float* __restrict__ encb, const float* __restrict__ bng,
                          const float* __restrict__ bnb, float* __restrict__ h0, int N) {
    __shared__ float xs[8 * NF];
    int tid = threadIdx.x;
    int nb = blockIdx.x * 8;
    if (tid < 64) {
        size_t idx = (size_t)nb * NF + tid;
        xs[tid] = (idx < (size_t)N * NF) ? x[idx] : 0.f;
    }
    __syncthreads();
    int jt = tid & 31, i = tid >> 5;
    int node = nb + i;
    int j4 = jt * 4;
    float ax = 0.f, ay = 0.f, az = 0.f, aw = 0.f;
#pragma unroll
    for (int k = 0; k < NF; ++k) {
        float hx = xs[i * NF + k];
        const float4 w = *(const float4*)(encW + k * H + j4);
        ax = fmaf(hx, w.x, ax); ay = fmaf(hx, w.y, ay);
        az = fmaf(hx, w.z, az); aw = fmaf(hx, w.w, aw);
    }
    if (node < N) {
        const float inv = 0.9999950000374997f;  // 1/sqrt(1+1e-5)
        const float4 eb = *(const float4*)(encb + j4);
        const float4 gg = *(const float4*)(bng + j4);
        const float4 bb = *(const float4*)(bnb + j4);
        float4 o;
        o.x = fmaxf(0.f, (ax + eb.x) * (gg.x * inv) + bb.x);
        o.y = fmaxf(0.f, (ay + eb.y) * (gg.y * inv) + bb.y);
        o.z = fmaxf(0.f, (az + eb.z) * (gg.z * inv) + bb.z);
        o.w = fmaxf(0.f, (aw + eb.w) * (gg.w * inv) + bb.w);
        *(float4*)(h0 + (size_t)node * H + j4) = o;
    }
}

// ---- per-layer GEMM: g = h @ W (bf16 out), register-blocked 8x4 ------------
__global__ void k_gemm(const float* __restrict__ h, const float* __restrict__ W,
                       const float* __restrict__ avs, const float* __restrict__ avd,
                       ushort* __restrict__ gb, float* __restrict__ a_src,
                       float* __restrict__ a_dst, int N) {
    __shared__ float hs[GR * H];  // 32 KB
    int tid = threadIdx.x;
    int nb = blockIdx.x * GR;
#pragma unroll
    for (int it = 0; it < 8; ++it) {
        int fi = it * 256 + tid;      // float4 index within 64x128 tile
        int r = fi >> 5;              // 32 float4 per row
        int c4 = (fi & 31) * 4;
        int node = nb + r;
        float4 v = make_float4(0.f, 0.f, 0.f, 0.f);
        if (node < N) v = *(const float4*)(h + (size_t)node * H + c4);
        *(float4*)(hs + r * H + c4) = v;
    }
    __syncthreads();
    const int jt = tid & 31;
    const int ig = tid >> 5;
    const int j4 = jt * 4;
    const int r0 = ig * 8;

    float acc[8][4];
#pragma unroll
    for (int r = 0; r < 8; ++r)
#pragma unroll
        for (int c = 0; c < 4; ++c) acc[r][c] = 0.f;

    for (int k = 0; k < H; k += 4) {
        const float4 w0 = *(const float4*)(W + (k + 0) * H + j4);
        const float4 w1 = *(const float4*)(W + (k + 1) * H + j4);
        const float4 w2 = *(const float4*)(W + (k + 2) * H + j4);
        const float4 w3 = *(const float4*)(W + (k + 3) * H + j4);
#pragma unroll
        for (int r = 0; r < 8; ++r) {
            const float4 hv = *(const float4*)(hs + (r0 + r) * H + k);
            acc[r][0] = fmaf(hv.x, w0.x, acc[r][0]);
            acc[r][1] = fmaf(hv.x, w0.y, acc[r][1]);
            acc[r][2] = fmaf(hv.x, w0.z, acc[r][2]);
            acc[r][3] = fmaf(hv.x, w0.w, acc[r][3]);
            acc[r][0] = fmaf(hv.y, w1.x, acc[r][0]);
            acc[r][1] = fmaf(hv.y, w1.y, acc[r][1]);
            acc[r][2] = fmaf(hv.y, w1.z, acc[r][2]);
            acc[r][3] = fmaf(hv.y, w1.w, acc[r][3]);
            acc[r][0] = fmaf(hv.z, w2.x, acc[r][0]);
            acc[r][1] = fmaf(hv.z, w2.y, acc[r][1]);
            acc[r][2] = fmaf(hv.z, w2.z, acc[r][2]);
            acc[r][3] = fmaf(hv.z, w2.w, acc[r][3]);
            acc[r][0] = fmaf(hv.w, w3.x, acc[r][0]);
            acc[r][1] = fmaf(hv.w, w3.y, acc[r][1]);
            acc[r][2] = fmaf(hv.w, w3.z, acc[r][2]);
            acc[r][3] = fmaf(hv.w, w3.w, acc[r][3]);
        }
    }

    const float4 s4 = *(const float4*)(avs + j4);
    const float4 d4 = *(const float4*)(avd + j4);
#pragma unroll
    for (int r = 0; r < 8; ++r) {
        int node = nb + r0 + r;
        float ps = acc[r][0] * s4.x + acc[r][1] * s4.y + acc[r][2] * s4.z + acc[r][3] * s4.w;
        float pd = acc[r][0] * d4.x + acc[r][1] * d4.y + acc[r][2] * d4.z + acc[r][3] * d4.w;
#pragma unroll
        for (int mm = 16; mm >= 1; mm >>= 1) {
            ps += __shfl_xor(ps, mm, 64);  // stays within 32-lane half (masks <32)
            pd += __shfl_xor(pd, mm, 64);
        }
        if (node < N) {
            ushort4 o;
            o.x = f2bf(acc[r][0]); o.y = f2bf(acc[r][1]);
            o.z = f2bf(acc[r][2]); o.w = f2bf(acc[r][3]);
            *(ushort4*)(gb + (size_t)node * H + j4) = o;
            if (jt == 0) {
                a_src[node] = ps;
                a_dst[node] = pd;
            }
        }
    }
}

// ---- aggregation: wave per node, online softmax, pipelined 16B gather ------
// Serial phase: 8 edges per super-iteration (streams A,B of 4 edges each,
// 16-lane group per edge row, 16B per lane) + 1-stage software prefetch.
template <int RELU, int ADDH0, int LAYER>
__global__ void k_agg(const ushort* __restrict__ gb, const float* __restrict__ a_src,
                      const float* __restrict__ a_dst, const int* __restrict__ rowptr,
                      const int4* __restrict__ erec, const float* __restrict__ park,
                      const float* __restrict__ bias, const float* __restrict__ h0,
                      float* __restrict__ out, int N) {
    int wv = threadIdx.x >> 6;
    int lane = threadIdx.x & 63;
    int v = blockIdx.x * 4 + wv;
    if (v >= N) return;

    const int grp = lane >> 4;   // which of 4 edge-slots this lane serves
    const int sub = lane & 15;   // position within the 256B row
    const int ch8 = sub * 8;     // 8 bf16 channels per lane

    const float sa = park[LAYER * 3 + 2];
    const float adv = a_dst[v];
    float lself = a_src[v] + adv + sa;
    lself = (lself > 0.f) ? lself : 0.2f * lself;

    float m = lself;   // running max (self-loop included)
    float s = 1.f;     // running sum, w_self = exp(0) = 1
    float acc[8];
    {
        const uint4 q = *(const uint4*)(gb + (size_t)v * H + ch8);
        float sel = (grp == 0) ? 1.f : 0.f;  // self contribution counted once
        acc[0] = sel * __uint_as_float(q.x << 16);
        acc[1] = sel * __uint_as_float(q.x & 0xffff0000u);
        acc[2] = sel * __uint_as_float(q.y << 16);
        acc[3] = sel * __uint_as_float(q.y & 0xffff0000u);
        acc[4] = sel * __uint_as_float(q.z << 16);
        acc[5] = sel * __uint_as_float(q.z & 0xffff0000u);
        acc[6] = sel * __uint_as_float(q.w << 16);
        acc[7] = sel * __uint_as_float(q.w & 0xffff0000u);
    }

    const int rs = rowptr[v];
    const int re = rowptr[v + 1];
    for (int p0 = rs; p0 < re; p0 += 64) {
        int e = p0 + lane;
        bool val = e < re;
        int4 rec = val ? erec[e] : make_int4(0, 0, 0, 0);
        int sv = rec.x;
        float lg;
        if (val) {
            float aef = __int_as_float(LAYER == 0 ? rec.y : (LAYER == 1 ? rec.z : rec.w));
            lg = a_src[sv] + adv + aef;
            lg = (lg > 0.f) ? lg : 0.2f * lg;
        } else {
            lg = -INFINITY;
        }
        float cm = wred_max(lg);
        float nm = fmaxf(m, cm);
        float f = __expf(m - nm);
        float w = val ? __expf(lg - nm) : 0.f;
        float ws = wred_sum(w);
        s = s * f + ws;
#pragma unroll
        for (int k = 0; k < 8; ++k) acc[k] *= f;
        m = nm;

        int cnt = re - p0;
        if (cnt > 64) cnt = 64;
        const int cm1 = cnt - 1;
        const int iters = (cnt + 7) >> 3;  // 8 edges per super-iteration

        // prologue: stage 0 (edges grp and grp+4), clamped + w-zeroed
        int jA = grp, jB = grp + 4;
        int jAc = (jA <= cm1) ? jA : cm1;
        int jBc = (jB <= cm1) ? jB : cm1;
        float wA = __shfl(w, jAc, 64); if (jA > cm1) wA = 0.f;
        float wB = __shfl(w, jBc, 64); if (jB > cm1) wB = 0.f;
        int sA = __shfl(sv, jAc, 64);
        int sB = __shfl(sv, jBc, 64);
        uint4 qA = *(const uint4*)(gb + (size_t)sA * H + ch8);
        uint4 qB = *(const uint4*)(gb + (size_t)sB * H + ch8);

        for (int i = 0; i < iters; ++i) {
            // prefetch stage i+1 (clamped; harmless warm re-load past end)
            int jA1 = (i + 1) * 8 + grp, jB1 = jA1 + 4;
            int jA1c = (jA1 <= cm1) ? jA1 : cm1;
            int jB1c = (jB1 <= cm1) ? jB1 : cm1;
            float wA1 = __shfl(w, jA1c, 64); if (jA1 > cm1) wA1 = 0.f;
            float wB1 = __shfl(w, jB1c, 64); if (jB1 > cm1) wB1 = 0.f;
            int sA1 = __shfl(sv, jA1c, 64);
            int sB1 = __shfl(sv, jB1c, 64);
            uint4 qA1 = *(const uint4*)(gb + (size_t)sA1 * H + ch8);
            uint4 qB1 = *(const uint4*)(gb + (size_t)sB1 * H + ch8);

            // compute stage i
            acc[0] = fmaf(wA, __uint_as_float(qA.x << 16), acc[0]);
            acc[1] = fmaf(wA, __uint_as_float(qA.x & 0xffff0000u), acc[1]);
            acc[2] = fmaf(wA, __uint_as_float(qA.y << 16), acc[2]);
            acc[3] = fmaf(wA, __uint_as_float(qA.y & 0xffff0000u), acc[3]);
            acc[4] = fmaf(wA, __uint_as_float(qA.z << 16), acc[4]);
            acc[5] = fmaf(wA, __uint_as_float(qA.z & 0xffff0000u), acc[5]);
            acc[6] = fmaf(wA, __uint_as_float(qA.w << 16), acc[6]);
            acc[7] = fmaf(wA, __uint_as_float(qA.w & 0xffff0000u), acc[7]);
            acc[0] = fmaf(wB, __uint_as_float(qB.x << 16), acc[0]);
            acc[1] = fmaf(wB, __uint_as_float(qB.x & 0xffff0000u), acc[1]);
            acc[2] = fmaf(wB, __uint_as_float(qB.y << 16), acc[2]);
            acc[3] = fmaf(wB, __uint_as_float(qB.y & 0xffff0000u), acc[3]);
            acc[4] = fmaf(wB, __uint_as_float(qB.z << 16), acc[4]);
            acc[5] = fmaf(wB, __uint_as_float(qB.z & 0xffff0000u), acc[5]);
            acc[6] = fmaf(wB, __uint_as_float(qB.w << 16), acc[6]);
            acc[7] = fmaf(wB, __uint_as_float(qB.w & 0xffff0000u), acc[7]);

            wA = wA1; wB = wB1; qA = qA1; qB = qB1;
        }
    }

    // combine the 4 group-partials (lanes sub, sub+16, sub+32, sub+48)
#pragma unroll
    for (int k = 0; k < 8; ++k) {
        acc[k] += __shfl_xor(acc[k], 16, 64);
        acc[k] += __shfl_xor(acc[k], 32, 64);
    }

    if (grp == 0) {
        const float is = 1.f / s;
        const float4 b0 = *(const float4*)(bias + ch8);
        const float4 b1 = *(const float4*)(bias + ch8 + 4);
        float o[8];
        o[0] = acc[0] * is + b0.x; o[1] = acc[1] * is + b0.y;
        o[2] = acc[2] * is + b0.z; o[3] = acc[3] * is + b0.w;
        o[4] = acc[4] * is + b1.x; o[5] = acc[5] * is + b1.y;
        o[6] = acc[6] * is + b1.z; o[7] = acc[7] * is + b1.w;
        if (ADDH0) {
            const float4 ha = *(const float4*)(h0 + (size_t)v * H + ch8);
            const float4 hb = *(const float4*)(h0 + (size_t)v * H + ch8 + 4);
            o[0] += ha.x; o[1] += ha.y; o[2] += ha.z; o[3] += ha.w;
            o[4] += hb.x; o[5] += hb.y; o[6] += hb.z; o[7] += hb.w;
        }
        if (RELU) {
#pragma unroll
            for (int k = 0; k < 8; ++k) o[k] = fmaxf(o[k], 0.f);
        }
        *(float4*)(out + (size_t)v * H + ch8) = make_float4(o[0], o[1], o[2], o[3]);
        *(float4*)(out + (size_t)v * H + ch8 + 4) = make_float4(o[4], o[5], o[6], o[7]);
    }
}

// ---------------------------------------------------------------------------

extern "C" void kernel_launch(void* const* d_in, const int* in_sizes, int n_in,
                              void* d_out, int out_size, void* d_ws, size_t ws_size,
                              hipStream_t stream) {
    const float* x    = (const float*)d_in[0];
    const int*   ei   = (const int*)d_in[1];
    const float* ea   = (const float*)d_in[2];
    const float* encW = (const float*)d_in[3];
    const float* encb = (const float*)d_in[4];
    const float* bng  = (const float*)d_in[5];
    const float* bnb  = (const float*)d_in[6];
    const float *W[3], *asrc[3], *adst[3], *We[3], *aev[3], *bias[3];
    for (int l = 0; l < 3; ++l) {
        W[l]    = (const float*)d_in[7 + l * 6 + 0];
        asrc[l] = (const float*)d_in[7 + l * 6 + 1];
        adst[l] = (const float*)d_in[7 + l * 6 + 2];
        We[l]   = (const float*)d_in[7 + l * 6 + 3];
        aev[l]  = (const float*)d_in[7 + l * 6 + 4];
        bias[l] = (const float*)d_in[7 + l * 6 + 5];
    }
    const int N = in_sizes[0] / NF;   // 50000 (< 65536: src packs in 16 bits)
    const int E = in_sizes[1] / 2;
    float* out = (float*)d_out;

    const int NBu  = (N + 255) >> 8;          // coarse buckets (196)
    const int nblk = (E + EPB - 1) / EPB;     // K1/K3 blocks (391)

    // workspace carve-up (256B aligned)
    char* wp = (char*)d_ws;
    auto alloc = [&](size_t bytes) -> char* {
        char* p = wp;
        wp += (bytes + 255) & ~(size_t)255;
        return p;
    };
    float*  h0       = (float*)alloc((size_t)N * H * 4);
    float*  hA       = (float*)alloc((size_t)N * H * 4);   // temp overlays here
    ushort* gb       = (ushort*)alloc((size_t)N * H * 2);
    float*  a_src    = (float*)alloc((size_t)N * 4);
    float*  a_dst    = (float*)alloc((size_t)N * 4);
    int*    rowptr   = (int*)alloc((size_t)(N + 1) * 4);
    float*  park     = (float*)alloc(64);
    int*    bucketTotal = (int*)alloc(256 * 4);
    int*    bucketBase  = (int*)alloc(257 * 4);
    int*    blockBase   = (int*)alloc((size_t)NBu * nblk * 4);
    int4*   erec     = (int4*)alloc((size_t)E * 16);
    float2* pmean    = (float2*)alloc((size_t)nblk * 8);
    uint2*  temp     = (uint2*)hA;  // E*8 bytes <= N*H*4; dead before hA is written

    hipMemsetAsync(bucketTotal, 0, 256 * 4, stream);

    k_count<<<nblk, 256, 0, stream>>>(ei, ea, E, nblk, NBu, bucketTotal, blockBase, pmean);
    k_scan_park<<<1, 256, 0, stream>>>(bucketTotal, NBu, bucketBase, rowptr, N, E,
                                       pmean, nblk, 1.0f / (float)E,
                                       We[0], aev[0], We[1], aev[1], We[2], aev[2], park);
    k_place<<<nblk, 256, 0, stream>>>(ei, ea, E, nblk, NBu, bucketBase, blockBase, temp);
    k_fine<<<NBu, 256, 0, stream>>>(temp, bucketBase, park, N, erec, rowptr);

    const int GB8 = (N + 7) / 8;
    const int GBR = (N + GR - 1) / GR;
    const int AB = (N + 3) / 4;
    k_encoder<<<GB8, 256, 0, stream>>>(x, encW, encb, bng, bnb, h0, N);

    // layer 1: h0 -> hA
    k_gemm<<<GBR, 256, 0, stream>>>(h0, W[0], asrc[0], adst[0], gb, a_src, a_dst, N);
    k_agg<1, 0, 0><<<AB, 256, 0, stream>>>(gb, a_src, a_dst, rowptr, erec, park,
                                           bias[0], nullptr, hA, N);
    // layer 2: hA -> hA
    k_gemm<<<GBR, 256, 0, stream>>>(hA, W[1], asrc[1], adst[1], gb, a_src, a_dst, N);
    k_agg<1, 0, 1><<<AB, 256, 0, stream>>>(gb, a_src, a_dst, rowptr, erec, park,
                                           bias[1], nullptr, hA, N);
    // layer 3: hA -> out (+h0, no relu)
    k_gemm<<<GBR, 256, 0, stream>>>(hA, W[2], asrc[2], adst[2], gb, a_src, a_dst, N);
    k_agg<0, 1, 2><<<AB, 256, 0, stream>>>(gb, a_src, a_dst, rowptr, erec, park,
                                           bias[2], h0, out, N);
}

// Round 8
// 313.091 us; speedup vs baseline: 4.6433x; 1.1385x over previous
//
#include <hip/hip_runtime.h>
#include <math.h>

// ---------------------------------------------------------------------------
// ImprovedCrossBorderGNN: 3-layer edge-conditioned GAT, N=50000, E=1.6M, H=128
// CSR (dst-grouped) built once; per layer: bf16 MFMA GEMM g=h@W (fused
// a_src/a_dst epilogue), then wave-per-node online-softmax gather.
// R1: mean() via two-stage reduction. R2: bf16 g; parallel scans.
// R4: CSR via two-level counting sort. R5: register-blocked GEMM.
// R6/R7: 16B-wide pipelined gather; agg now at the ~2.9TB/s random-gather
//        fabric ceiling (12.8MB table vs 4MB/XCD L2).
// R8: (1) MFMA bf16 GEMM (fp32 VALU GEMM was 27us vs 10.4us fp32 floor;
//     MFMA is memory-bound ~8-10us). W pre-packed to fragment layout.
//     (2) 4B/edge/layer records {src:16,ae:bf16} (was 16B int4).
//     (3) bf16 hidden states between layers (halves inter-layer traffic).
// ---------------------------------------------------------------------------

#define H 128
#define NF 8
#define EPB 4096  // edges per block in K1/K3 (256 threads x 16)

typedef __attribute__((ext_vector_type(8))) short short8v;
typedef __attribute__((ext_vector_type(4))) float f32x4;

__device__ __forceinline__ float wred_sum(float x) {
#pragma unroll
    for (int m = 32; m >= 1; m >>= 1) x += __shfl_xor(x, m, 64);
    return x;
}
__device__ __forceinline__ float wred_max(float x) {
#pragma unroll
    for (int m = 32; m >= 1; m >>= 1) x = fmaxf(x, __shfl_xor(x, m, 64));
    return x;
}
__device__ __forceinline__ ushort f2bf(float f) {
    uint u = __float_as_uint(f);
    uint r = (u + 0x7FFFu + ((u >> 16) & 1u)) >> 16;  // round-to-nearest-even
    return (ushort)r;
}

// ---- CSR build: two-level counting sort (no per-edge global atomics) -------

__global__ void k_count(const int* __restrict__ ei, const float* __restrict__ ea,
                        int E, int nblk, int nbuckets, int* __restrict__ bucketTotal,
                        int* __restrict__ blockBase, float2* __restrict__ pmean) {
    __shared__ int hist[256];
    __shared__ float sx[4], sy[4];
    int t = threadIdx.x;  // 256
    int blk = blockIdx.x;
    hist[t] = 0;
    __syncthreads();
    int base = blk * EPB;
    float px = 0.f, py = 0.f;
#pragma unroll
    for (int i = 0; i < 16; ++i) {
        int e = base + i * 256 + t;
        if (e < E) {
            int d = ei[E + e];
            atomicAdd(&hist[d >> 8], 1);
            const float2 z = *(const float2*)(ea + 2 * (size_t)e);
            px += z.x; py += z.y;
        }
    }
    px = wred_sum(px); py = wred_sum(py);
    if ((t & 63) == 0) { sx[t >> 6] = px; sy[t >> 6] = py; }
    __syncthreads();
    if (t == 0) {
        pmean[blk] = make_float2(sx[0] + sx[1] + sx[2] + sx[3],
                                 sy[0] + sy[1] + sy[2] + sy[3]);
    }
    if (t < nbuckets) {
        int c = hist[t];
        int old = (c > 0) ? atomicAdd(&bucketTotal[t], c) : 0;
        blockBase[t * nblk + blk] = old;
    }
}

__global__ void k_scan_park(const int* __restrict__ bucketTotal, int nbuckets,
                            int* __restrict__ bucketBase, int* __restrict__ rowptr,
                            int N, int E, const float2* __restrict__ pmean, int nblk,
                            float invE,
                            const float* __restrict__ We1, const float* __restrict__ ae1,
                            const float* __restrict__ We2, const float* __restrict__ ae2,
                            const float* __restrict__ We3, const float* __restrict__ ae3,
                            float* __restrict__ park) {
    __shared__ int tmp[256];
    __shared__ float2 sp[4];
    __shared__ float smean[2];
    int t = threadIdx.x;  // 256
    float ax = 0.f, ay = 0.f;
    for (int i = t; i < nblk; i += 256) {
        float2 z = pmean[i];
        ax += z.x; ay += z.y;
    }
    ax = wred_sum(ax); ay = wred_sum(ay);
    if ((t & 63) == 0) sp[t >> 6] = make_float2(ax, ay);
    int v = (t < nbuckets) ? bucketTotal[t] : 0;
    tmp[t] = v;
    __syncthreads();
    for (int off = 1; off < 256; off <<= 1) {
        int q = (t >= off) ? tmp[t - off] : 0;
        __syncthreads();
        tmp[t] += q;
        __syncthreads();
    }
    bucketBase[t] = tmp[t] - v;  // exclusive; entries >= nbuckets hold E
    if (t == 0) {
        bucketBase[256] = tmp[255];  // == E
        rowptr[N] = E;
        smean[0] = (sp[0].x + sp[1].x + sp[2].x + sp[3].x) * invE;
        smean[1] = (sp[0].y + sp[1].y + sp[2].y + sp[3].y) * invE;
    }
    __syncthreads();
    if (t < 192) {
        int l = t >> 6, q = t & 63;
        const float* We = (l == 0) ? We1 : ((l == 1) ? We2 : We3);
        const float* ae = (l == 0) ? ae1 : ((l == 1) ? ae2 : ae3);
        float p0 = We[q] * ae[q] + We[q + 64] * ae[q + 64];
        float p1 = We[H + q] * ae[q] + We[H + q + 64] * ae[q + 64];
        p0 = wred_sum(p0);
        p1 = wred_sum(p1);
        if (q == 0) {
            park[l * 3 + 0] = p0;
            park[l * 3 + 1] = p1;
            park[l * 3 + 2] = smean[0] * p0 + smean[1] * p1;
        }
    }
}

__global__ void k_place(const int* __restrict__ ei, const float* __restrict__ ea,
                        int E, int nblk, int nbuckets,
                        const int* __restrict__ bucketBase, const int* __restrict__ blockBase,
                        uint2* __restrict__ temp) {
    __shared__ int cnt[256];
    __shared__ int sbase[256];
    int t = threadIdx.x;  // 256
    int blk = blockIdx.x;
    cnt[t] = 0;
    if (t < nbuckets) sbase[t] = bucketBase[t] + blockBase[t * nblk + blk];
    __syncthreads();
    int base = blk * EPB;
#pragma unroll
    for (int i = 0; i < 16; ++i) {
        int e = base + i * 256 + t;
        if (e < E) {
            int s = ei[e];          // s < 65536 (N=50000)
            int d = ei[E + e];
            int b = d >> 8;
            int r = atomicAdd(&cnt[b], 1);
            const float2 z = *(const float2*)(ea + 2 * (size_t)e);
            uint w0 = (uint)s | ((uint)(d & 255) << 16);
            uint w1 = (uint)f2bf(z.x) | ((uint)f2bf(z.y) << 16);
            temp[sbase[b] + r] = make_uint2(w0, w1);
        }
    }
}

// K4: per-bucket fine CSR; emit rowptr + 3 per-layer 4B records {src, bf16 ae}
__global__ void k_fine(const uint2* __restrict__ temp, const int* __restrict__ bucketBase,
                       const float* __restrict__ park, int N,
                       uint* __restrict__ er0, uint* __restrict__ er1,
                       uint* __restrict__ er2, int* __restrict__ rowptr) {
    __shared__ int hist[256];
    __shared__ int tmp[256];
    __shared__ int fb[256];
    __shared__ int cur[256];
    int b = blockIdx.x;
    int t = threadIdx.x;  // 256
    const int lo = bucketBase[b], hi = bucketBase[b + 1];
    hist[t] = 0;
    __syncthreads();
    for (int e = lo + t; e < hi; e += 256) {
        atomicAdd(&hist[(temp[e].x >> 16) & 255], 1);
    }
    __syncthreads();
    int v = hist[t];
    tmp[t] = v;
    __syncthreads();
    for (int off = 1; off < 256; off <<= 1) {
        int q = (t >= off) ? tmp[t - off] : 0;
        __syncthreads();
        tmp[t] += q;
        __syncthreads();
    }
    fb[t] = tmp[t] - v;  // exclusive within bucket
    cur[t] = 0;
    int dst = b * 256 + t;
    if (dst < N) rowptr[dst] = lo + fb[t];
    __syncthreads();
    const float c00 = park[0], c01 = park[1];
    const float c10 = park[3], c11 = park[4];
    const float c20 = park[6], c21 = park[7];
    for (int e = lo + t; e < hi; e += 256) {
        uint2 w = temp[e];
        uint src = w.x & 0xFFFFu;
        int j = (int)((w.x >> 16) & 255u);
        float ex = __uint_as_float(w.y << 16);
        float ey = __uint_as_float(w.y & 0xffff0000u);
        int r = atomicAdd(&cur[j], 1);
        int p = lo + fb[j] + r;
        er0[p] = src | ((uint)f2bf(c00 * ex + c01 * ey) << 16);
        er1[p] = src | ((uint)f2bf(c10 * ex + c11 * ey) << 16);
        er2[p] = src | ((uint)f2bf(c20 * ex + c21 * ey) << 16);
    }
}

// ---- W fragment packer: Wp[layer][nt][kt][lane][8] bf16 --------------------
__global__ void k_wpack(const float* __restrict__ W1, const float* __restrict__ W2,
                        const float* __restrict__ W3, ushort* __restrict__ Wp) {
    int layer = blockIdx.x;
    const float* W = (layer == 0) ? W1 : ((layer == 1) ? W2 : W3);
    for (int idx = threadIdx.x; idx < 16384; idx += 256) {
        int i = idx & 7;
        int lane = (idx >> 3) & 63;
        int ft = idx >> 9;
        int kt = ft & 3, nt = ft >> 2;
        int k = kt * 32 + (lane >> 4) * 8 + i;
        int n = nt * 16 + (lane & 15);
        Wp[layer * 16384 + idx] = f2bf(W[k * H + n]);
    }
}

// ---- encoder: h0 = relu((x @ enc_W + b) * bn_g*inv + bn_b); fp32 + bf16 ----
__global__ void k_encoder(const float* __restrict__ x, const float* __restrict__ encW,
                          const float* __restrict__ encb, const float* __restrict__ bng,
                          const float* __restrict__ bnb, float* __restrict__ h0,
                          ushort* __restrict__ hb, int N) {
    __shared__ float xs[8 * NF];
    int tid = threadIdx.x;
    int nb = blockIdx.x * 8;
    if (tid < 64) {
        size_t idx = (size_t)nb * NF + tid;
        xs[tid] = (idx < (size_t)N * NF) ? x[idx] : 0.f;
    }
    __syncthreads();
    int jt = tid & 31, i = tid >> 5;
    int node = nb + i;
    int j4 = jt * 4;
    float ax = 0.f, ay = 0.f, az = 0.f, aw = 0.f;
#pragma unroll
    for (int k = 0; k < NF; ++k) {
        float hx = xs[i * NF + k];
        const float4 w = *(const float4*)(encW + k * H + j4);
        ax = fmaf(hx, w.x, ax); ay = fmaf(hx, w.y, ay);
        az = fmaf(hx, w.z, az); aw = fmaf(hx, w.w, aw);
    }
    if (node < N) {
        const float inv = 0.9999950000374997f;  // 1/sqrt(1+1e-5)
        const float4 eb = *(const float4*)(encb + j4);
        const float4 gg = *(const float4*)(bng + j4);
        const float4 bb = *(const float4*)(bnb + j4);
        float4 o;
        o.x = fmaxf(0.f, (ax + eb.x) * (gg.x * inv) + bb.x);
        o.y = fmaxf(0.f, (ay + eb.y) * (gg.y * inv) + bb.y);
        o.z = fmaxf(0.f, (az + eb.z) * (gg.z * inv) + bb.z);
        o.w = fmaxf(0.f, (aw + eb.w) * (gg.w * inv) + bb.w);
        *(float4*)(h0 + (size_t)node * H + j4) = o;
        uint2 ob;
        ob.x = (uint)f2bf(o.x) | ((uint)f2bf(o.y) << 16);
        ob.y = (uint)f2bf(o.z) | ((uint)f2bf(o.w) << 16);
        *(uint2*)(hb + (size_t)node * H + j4) = ob;
    }
}

// ---- per-layer GEMM: g = h @ W via bf16 MFMA, fused a_src/a_dst epilogue ---
// Block: 64 rows, 4 waves (16 rows each). A in LDS (pad 136 -> 2-way alias).
// MFMA 16x16x32 bf16; C layout col=lane&15, row=(lane>>4)*4+reg [HW-verified].
__global__ void k_gemm_mfma(const ushort* __restrict__ hb, const ushort* __restrict__ Wp,
                            const float* __restrict__ avs, const float* __restrict__ avd,
                            ushort* __restrict__ gb, float* __restrict__ a_src,
                            float* __restrict__ a_dst, int N) {
    __shared__ ushort hs[64 * 136];
    int tid = threadIdx.x;
    int nb = blockIdx.x * 64;
#pragma unroll
    for (int it = 0; it < 4; ++it) {
        int fi = it * 256 + tid;  // 1024 8-elem fragments in the 64x128 tile
        int r = fi >> 4;
        int c8 = (fi & 15) * 8;
        int node = nb + r;
        uint4 v = make_uint4(0, 0, 0, 0);
        if (node < N) v = *(const uint4*)(hb + (size_t)node * H + c8);
        *(uint4*)(hs + r * 136 + c8) = v;
    }
    __syncthreads();
    const int l = tid & 63;
    const int w = tid >> 6;
    const int cl = l & 15;        // A-row within wave tile / C-col within ntile
    const int kg = l >> 4;        // k-group
    const ushort* hrow = hs + (w * 16 + cl) * 136 + kg * 8;
    short8v a0 = *(const short8v*)(hrow + 0);
    short8v a1 = *(const short8v*)(hrow + 32);
    short8v a2 = *(const short8v*)(hrow + 64);
    short8v a3 = *(const short8v*)(hrow + 96);

    f32x4 acc[8];
#pragma unroll
    for (int nt = 0; nt < 8; ++nt) {
        const short8v* bp = (const short8v*)(Wp + ((size_t)(nt * 4) * 64 + l) * 8);
        f32x4 c = {0.f, 0.f, 0.f, 0.f};
        c = __builtin_amdgcn_mfma_f32_16x16x32_bf16(a0, bp[0], c, 0, 0, 0);
        c = __builtin_amdgcn_mfma_f32_16x16x32_bf16(a1, bp[64], c, 0, 0, 0);
        c = __builtin_amdgcn_mfma_f32_16x16x32_bf16(a2, bp[128], c, 0, 0, 0);
        c = __builtin_amdgcn_mfma_f32_16x16x32_bf16(a3, bp[192], c, 0, 0, 0);
        acc[nt] = c;
    }

    // epilogue: attention dots. lane holds rows kg*4+reg, cols nt*16+cl.
    float ps0 = 0.f, ps1 = 0.f, ps2 = 0.f, ps3 = 0.f;
    float pd0 = 0.f, pd1 = 0.f, pd2 = 0.f, pd3 = 0.f;
#pragma unroll
    for (int nt = 0; nt < 8; ++nt) {
        float vs = avs[cl + 16 * nt];
        float vd = avd[cl + 16 * nt];
        ps0 = fmaf(acc[nt].x, vs, ps0); pd0 = fmaf(acc[nt].x, vd, pd0);
        ps1 = fmaf(acc[nt].y, vs, ps1); pd1 = fmaf(acc[nt].y, vd, pd1);
        ps2 = fmaf(acc[nt].z, vs, ps2); pd2 = fmaf(acc[nt].z, vd, pd2);
        ps3 = fmaf(acc[nt].w, vs, ps3); pd3 = fmaf(acc[nt].w, vd, pd3);
    }
#pragma unroll
    for (int m = 8; m >= 1; m >>= 1) {
        ps0 += __shfl_xor(ps0, m, 64); pd0 += __shfl_xor(pd0, m, 64);
        ps1 += __shfl_xor(ps1, m, 64); pd1 += __shfl_xor(pd1, m, 64);
        ps2 += __shfl_xor(ps2, m, 64); pd2 += __shfl_xor(pd2, m, 64);
        ps3 += __shfl_xor(ps3, m, 64); pd3 += __shfl_xor(pd3, m, 64);
    }
    int r0 = nb + w * 16 + kg * 4;
    if (cl == 0) {
        if (r0 + 0 < N) { a_src[r0 + 0] = ps0; a_dst[r0 + 0] = pd0; }
        if (r0 + 1 < N) { a_src[r0 + 1] = ps1; a_dst[r0 + 1] = pd1; }
        if (r0 + 2 < N) { a_src[r0 + 2] = ps2; a_dst[r0 + 2] = pd2; }
        if (r0 + 3 < N) { a_src[r0 + 3] = ps3; a_dst[r0 + 3] = pd3; }
    }
    // g store (bf16 scalar; 12.8 MB total volume)
#pragma unroll
    for (int nt = 0; nt < 8; ++nt) {
        int col = nt * 16 + cl;
        if (r0 + 0 < N) gb[(size_t)(r0 + 0) * H + col] = f2bf(acc[nt].x);
        if (r0 + 1 < N) gb[(size_t)(r0 + 1) * H + col] = f2bf(acc[nt].y);
        if (r0 + 2 < N) gb[(size_t)(r0 + 2) * H + col] = f2bf(acc[nt].z);
        if (r0 + 3 < N) gb[(size_t)(r0 + 3) * H + col] = f2bf(acc[nt].w);
    }
}

// ---- aggregation: wave per node, online softmax, pipelined 16B gather ------
// MODE 0: relu, bf16 out (hidden layers). MODE 1: +h0 residual, fp32 out.
template <int MODE>
__global__ void k_agg(const ushort* __restrict__ gb, const float* __restrict__ a_src,
                      const float* __restrict__ a_dst, const int* __restrict__ rowptr,
                      const uint* __restrict__ erecL, const float* __restrict__ park,
                      int layer, const float* __restrict__ bias,
                      const float* __restrict__ h0, float* __restrict__ outf,
                      ushort* __restrict__ outb, int N) {
    int wv = threadIdx.x >> 6;
    int lane = threadIdx.x & 63;
    int v = blockIdx.x * 4 + wv;
    if (v >= N) return;

    const int grp = lane >> 4;   // which of 4 edge-slots this lane serves
    const int sub = lane & 15;   // position within the 256B row
    const int ch8 = sub * 8;     // 8 bf16 channels per lane

    const float sa = park[layer * 3 + 2];
    const float adv = a_dst[v];
    float lself = a_src[v] + adv + sa;
    lself = (lself > 0.f) ? lself : 0.2f * lself;

    float m = lself;   // running max (self-loop included)
    float s = 1.f;     // running sum, w_self = exp(0) = 1
    float acc[8];
    {
        const uint4 q = *(const uint4*)(gb + (size_t)v * H + ch8);
        float sel = (grp == 0) ? 1.f : 0.f;  // self contribution counted once
        acc[0] = sel * __uint_as_float(q.x << 16);
        acc[1] = sel * __uint_as_float(q.x & 0xffff0000u);
        acc[2] = sel * __uint_as_float(q.y << 16);
        acc[3] = sel * __uint_as_float(q.y & 0xffff0000u);
        acc[4] = sel * __uint_as_float(q.z << 16);
        acc[5] = sel * __uint_as_float(q.z & 0xffff0000u);
        acc[6] = sel * __uint_as_float(q.w << 16);
        acc[7] = sel * __uint_as_float(q.w & 0xffff0000u);
    }

    const int rs = rowptr[v];
    const int re = rowptr[v + 1];
    for (int p0 = rs; p0 < re; p0 += 64) {
        int e = p0 + lane;
        bool val = e < re;
        uint rec = val ? erecL[e] : 0u;
        int sv = (int)(rec & 0xFFFFu);
        float lg;
        if (val) {
            float aef = __uint_as_float(rec & 0xffff0000u);
            lg = a_src[sv] + adv + aef;
            lg = (lg > 0.f) ? lg : 0.2f * lg;
        } else {
            lg = -INFINITY;
        }
        float cm = wred_max(lg);
        float nm = fmaxf(m, cm);
        float f = __expf(m - nm);
        float w = val ? __expf(lg - nm) : 0.f;
        float ws = wred_sum(w);
        s = s * f + ws;
#pragma unroll
        for (int k = 0; k < 8; ++k) acc[k] *= f;
        m = nm;

        int cnt = re - p0;
        if (cnt > 64) cnt = 64;
        const int cm1 = cnt - 1;
        const int iters = (cnt + 7) >> 3;  // 8 edges per super-iteration

        int jA = grp, jB = grp + 4;
        int jAc = (jA <= cm1) ? jA : cm1;
        int jBc = (jB <= cm1) ? jB : cm1;
        float wA = __shfl(w, jAc, 64); if (jA > cm1) wA = 0.f;
        float wB = __shfl(w, jBc, 64); if (jB > cm1) wB = 0.f;
        int sA = __shfl(sv, jAc, 64);
        int sB = __shfl(sv, jBc, 64);
        uint4 qA = *(const uint4*)(gb + (size_t)sA * H + ch8);
        uint4 qB = *(const uint4*)(gb + (size_t)sB * H + ch8);

        for (int i = 0; i < iters; ++i) {
            int jA1 = (i + 1) * 8 + grp, jB1 = jA1 + 4;
            int jA1c = (jA1 <= cm1) ? jA1 : cm1;
            int jB1c = (jB1 <= cm1) ? jB1 : cm1;
            float wA1 = __shfl(w, jA1c, 64); if (jA1 > cm1) wA1 = 0.f;
            float wB1 = __shfl(w, jB1c, 64); if (jB1 > cm1) wB1 = 0.f;
            int sA1 = __shfl(sv, jA1c, 64);
            int sB1 = __shfl(sv, jB1c, 64);
            uint4 qA1 = *(const uint4*)(gb + (size_t)sA1 * H + ch8);
            uint4 qB1 = *(const uint4*)(gb + (size_t)sB1 * H + ch8);

            acc[0] = fmaf(wA, __uint_as_float(qA.x << 16), acc[0]);
            acc[1] = fmaf(wA, __uint_as_float(qA.x & 0xffff0000u), acc[1]);
            acc[2] = fmaf(wA, __uint_as_float(qA.y << 16), acc[2]);
            acc[3] = fmaf(wA, __uint_as_float(qA.y & 0xffff0000u), acc[3]);
            acc[4] = fmaf(wA, __uint_as_float(qA.z << 16), acc[4]);
            acc[5] = fmaf(wA, __uint_as_float(qA.z & 0xffff0000u), acc[5]);
            acc[6] = fmaf(wA, __uint_as_float(qA.w << 16), acc[6]);
            acc[7] = fmaf(wA, __uint_as_float(qA.w & 0xffff0000u), acc[7]);
            acc[0] = fmaf(wB, __uint_as_float(qB.x << 16), acc[0]);
            acc[1] = fmaf(wB, __uint_as_float(qB.x & 0xffff0000u), acc[1]);
            acc[2] = fmaf(wB, __uint_as_float(qB.y << 16), acc[2]);
            acc[3] = fmaf(wB, __uint_as_float(qB.y & 0xffff0000u), acc[3]);
            acc[4] = fmaf(wB, __uint_as_float(qB.z << 16), acc[4]);
            acc[5] = fmaf(wB, __uint_as_float(qB.z & 0xffff0000u), acc[5]);
            acc[6] = fmaf(wB, __uint_as_float(qB.w << 16), acc[6]);
            acc[7] = fmaf(wB, __uint_as_float(qB.w & 0xffff0000u), acc[7]);

            wA = wA1; wB = wB1; qA = qA1; qB = qB1;
        }
    }

#pragma unroll
    for (int k = 0; k < 8; ++k) {
        acc[k] += __shfl_xor(acc[k], 16, 64);
        acc[k] += __shfl_xor(acc[k], 32, 64);
    }

    if (grp == 0) {
        const float is = 1.f / s;
        const float4 b0 = *(const float4*)(bias + ch8);
        const float4 b1 = *(const float4*)(bias + ch8 + 4);
        float o[8];
        o[0] = acc[0] * is + b0.x; o[1] = acc[1] * is + b0.y;
        o[2] = acc[2] * is + b0.z; o[3] = acc[3] * is + b0.w;
        o[4] = acc[4] * is + b1.x; o[5] = acc[5] * is + b1.y;
        o[6] = acc[6] * is + b1.z; o[7] = acc[7] * is + b1.w;
        if (MODE == 0) {
#pragma unroll
            for (int k = 0; k < 8; ++k) o[k] = fmaxf(o[k], 0.f);
            uint4 ob;
            ob.x = (uint)f2bf(o[0]) | ((uint)f2bf(o[1]) << 16);
            ob.y = (uint)f2bf(o[2]) | ((uint)f2bf(o[3]) << 16);
            ob.z = (uint)f2bf(o[4]) | ((uint)f2bf(o[5]) << 16);
            ob.w = (uint)f2bf(o[6]) | ((uint)f2bf(o[7]) << 16);
            *(uint4*)(outb + (size_t)v * H + ch8) = ob;
        } else {
            const float4 ha = *(const float4*)(h0 + (size_t)v * H + ch8);
            const float4 hb4 = *(const float4*)(h0 + (size_t)v * H + ch8 + 4);
            o[0] += ha.x; o[1] += ha.y; o[2] += ha.z; o[3] += ha.w;
            o[4] += hb4.x; o[5] += hb4.y; o[6] += hb4.z; o[7] += hb4.w;
            *(float4*)(outf + (size_t)v * H + ch8) = make_float4(o[0], o[1], o[2], o[3]);
            *(float4*)(outf + (size_t)v * H + ch8 + 4) = make_float4(o[4], o[5], o[6], o[7]);
        }
    }
}

// ---------------------------------------------------------------------------

extern "C" void kernel_launch(void* const* d_in, const int* in_sizes, int n_in,
                              void* d_out, int out_size, void* d_ws, size_t ws_size,
                              hipStream_t stream) {
    const float* x    = (const float*)d_in[0];
    const int*   ei   = (const int*)d_in[1];
    const float* ea   = (const float*)d_in[2];
    const float* encW = (const float*)d_in[3];
    const float* encb = (const float*)d_in[4];
    const float* bng  = (const float*)d_in[5];
    const float* bnb  = (const float*)d_in[6];
    const float *W[3], *asrc[3], *adst[3], *We[3], *aev[3], *bias[3];
    for (int l = 0; l < 3; ++l) {
        W[l]    = (const float*)d_in[7 + l * 6 + 0];
        asrc[l] = (const float*)d_in[7 + l * 6 + 1];
        adst[l] = (const float*)d_in[7 + l * 6 + 2];
        We[l]   = (const float*)d_in[7 + l * 6 + 3];
        aev[l]  = (const float*)d_in[7 + l * 6 + 4];
        bias[l] = (const float*)d_in[7 + l * 6 + 5];
    }
    const int N = in_sizes[0] / NF;   // 50000 (< 65536: src packs in 16 bits)
    const int E = in_sizes[1] / 2;
    float* out = (float*)d_out;

    const int NBu  = (N + 255) >> 8;          // coarse buckets (196)
    const int nblk = (E + EPB - 1) / EPB;     // K1/K3 blocks (391)

    // workspace carve-up (256B aligned)
    char* wp = (char*)d_ws;
    auto alloc = [&](size_t bytes) -> char* {
        char* p = wp;
        wp += (bytes + 255) & ~(size_t)255;
        return p;
    };
    float*  h0       = (float*)alloc((size_t)N * H * 4);   // temp overlays here
    ushort* hb       = (ushort*)alloc((size_t)N * H * 2);
    ushort* gb       = (ushort*)alloc((size_t)N * H * 2);
    ushort* Wp       = (ushort*)alloc((size_t)3 * 16384 * 2);
    float*  a_src    = (float*)alloc((size_t)N * 4);
    float*  a_dst    = (float*)alloc((size_t)N * 4);
    int*    rowptr   = (int*)alloc((size_t)(N + 1) * 4);
    float*  park     = (float*)alloc(64);
    int*    bucketTotal = (int*)alloc(256 * 4);
    int*    bucketBase  = (int*)alloc(257 * 4);
    int*    blockBase   = (int*)alloc((size_t)NBu * nblk * 4);
    uint*   er0      = (uint*)alloc((size_t)E * 4);
    uint*   er1      = (uint*)alloc((size_t)E * 4);
    uint*   er2      = (uint*)alloc((size_t)E * 4);
    float2* pmean    = (float2*)alloc((size_t)nblk * 8);
    uint2*  temp     = (uint2*)h0;  // E*8 <= N*H*4; dead before encoder writes h0

    hipMemsetAsync(bucketTotal, 0, 256 * 4, stream);

    k_count<<<nblk, 256, 0, stream>>>(ei, ea, E, nblk, NBu, bucketTotal, blockBase, pmean);
    k_scan_park<<<1, 256, 0, stream>>>(bucketTotal, NBu, bucketBase, rowptr, N, E,
                                       pmean, nblk, 1.0f / (float)E,
                                       We[0], aev[0], We[1], aev[1], We[2], aev[2], park);
    k_place<<<nblk, 256, 0, stream>>>(ei, ea, E, nblk, NBu, bucketBase, blockBase, temp);
    k_fine<<<NBu, 256, 0, stream>>>(temp, bucketBase, park, N, er0, er1, er2, rowptr);
    k_wpack<<<3, 256, 0, stream>>>(W[0], W[1], W[2], Wp);

    const int GB8 = (N + 7) / 8;
    const int GBM = (N + 63) / 64;
    const int AB = (N + 3) / 4;
    k_encoder<<<GB8, 256, 0, stream>>>(x, encW, encb, bng, bnb, h0, hb, N);

    // layer 1: hb -> gb -> hb
    k_gemm_mfma<<<GBM, 256, 0, stream>>>(hb, Wp + 0 * 16384, asrc[0], adst[0],
                                         gb, a_src, a_dst, N);
    k_agg<0><<<AB, 256, 0, stream>>>(gb, a_src, a_dst, rowptr, er0, park, 0,
                                     bias[0], nullptr, nullptr, hb, N);
    // layer 2: hb -> gb -> hb
    k_gemm_mfma<<<GBM, 256, 0, stream>>>(hb, Wp + 1 * 16384, asrc[1], adst[1],
                                         gb, a_src, a_dst, N);
    k_agg<0><<<AB, 256, 0, stream>>>(gb, a_src, a_dst, rowptr, er1, park, 1,
                                     bias[1], nullptr, nullptr, hb, N);
    // layer 3: hb -> gb -> out (+h0, no relu, fp32)
    k_gemm_mfma<<<GBM, 256, 0, stream>>>(hb, Wp + 2 * 16384, asrc[2], adst[2],
                                         gb, a_src, a_dst, N);
    k_agg<1><<<AB, 256, 0, stream>>>(gb, a_src, a_dst, rowptr, er2, park, 2,
                                     bias[2], h0, out, nullptr, N);
}

// Round 9
// 298.817 us; speedup vs baseline: 4.8651x; 1.0478x over previous
//
#include <hip/hip_runtime.h>
#include <math.h>

// ---------------------------------------------------------------------------
// ImprovedCrossBorderGNN: 3-layer edge-conditioned GAT, N=50000, E=1.6M, H=128
// CSR (dst-grouped) built once; per layer: bf16 MFMA GEMM g=h@W (fused
// a_src/a_dst epilogue), then wave-per-node online-softmax gather.
// R1: mean() via two-stage reduction. R2: bf16 g; parallel scans.
// R4: CSR via two-level counting sort. R5: register-blocked GEMM.
// R6/R7: 16B-wide pipelined gather; agg at the ~2.9TB/s random-gather
//        fabric ceiling (12.8MB table vs 4MB/XCD L2).
// R8: MFMA bf16 GEMM; 4B/edge/layer records; bf16 hidden states.
// R9: serial-chain fusion: A = count||encoder||wpack, B = place||gemm1
//     (block-role fusion of independent dispatches; 12->10 launches).
//     agg: f32x2 + elementwise_fma -> v_pk_fma_f32; nontemporal erec loads.
//     temp no longer overlays h0 (encoder now runs before place).
// ---------------------------------------------------------------------------

#define H 128
#define NF 8
#define EPB 4096  // edges per block in count/place (256 threads x 16)

typedef __attribute__((ext_vector_type(8))) short short8v;
typedef __attribute__((ext_vector_type(4))) float f32x4;
typedef __attribute__((ext_vector_type(2))) float f32x2;

__device__ __forceinline__ float wred_sum(float x) {
#pragma unroll
    for (int m = 32; m >= 1; m >>= 1) x += __shfl_xor(x, m, 64);
    return x;
}
__device__ __forceinline__ float wred_max(float x) {
#pragma unroll
    for (int m = 32; m >= 1; m >>= 1) x = fmaxf(x, __shfl_xor(x, m, 64));
    return x;
}
__device__ __forceinline__ ushort f2bf(float f) {
    uint u = __float_as_uint(f);
    uint r = (u + 0x7FFFu + ((u >> 16) & 1u)) >> 16;  // round-to-nearest-even
    return (ushort)r;
}
__device__ __forceinline__ f32x2 bfpair(uint q) {
    f32x2 r;
    r.x = __uint_as_float(q << 16);
    r.y = __uint_as_float(q & 0xffff0000u);
    return r;
}

// ---- Kernel A: count || encoder || wpack (independent roles) ---------------
__global__ void k_fusedA(const int* __restrict__ ei, const float* __restrict__ ea,
                         int E, int nblk, int nbuckets, int* __restrict__ bucketTotal,
                         int* __restrict__ blockBase, float2* __restrict__ pmean,
                         const float* __restrict__ x, const float* __restrict__ encW,
                         const float* __restrict__ encb, const float* __restrict__ bng,
                         const float* __restrict__ bnb, float* __restrict__ h0,
                         ushort* __restrict__ hb, int N, int GB8,
                         const float* __restrict__ W1, const float* __restrict__ W2,
                         const float* __restrict__ W3, ushort* __restrict__ Wp) {
    __shared__ int hist[256];
    __shared__ float sx[4], sy[4];
    __shared__ float xs[8 * NF];
    const int bx = blockIdx.x;
    const int t = threadIdx.x;  // 256

    if (bx < nblk) {
        // ---- degree count + edge_attr partial sums ----
        int blk = bx;
        hist[t] = 0;
        __syncthreads();
        int base = blk * EPB;
        float px = 0.f, py = 0.f;
#pragma unroll
        for (int i = 0; i < 16; ++i) {
            int e = base + i * 256 + t;
            if (e < E) {
                int d = ei[E + e];
                atomicAdd(&hist[d >> 8], 1);
                const float2 z = *(const float2*)(ea + 2 * (size_t)e);
                px += z.x; py += z.y;
            }
        }
        px = wred_sum(px); py = wred_sum(py);
        if ((t & 63) == 0) { sx[t >> 6] = px; sy[t >> 6] = py; }
        __syncthreads();
        if (t == 0) {
            pmean[blk] = make_float2(sx[0] + sx[1] + sx[2] + sx[3],
                                     sy[0] + sy[1] + sy[2] + sy[3]);
        }
        if (t < nbuckets) {
            int c = hist[t];
            int old = (c > 0) ? atomicAdd(&bucketTotal[t], c) : 0;
            blockBase[t * nblk + blk] = old;
        }
    } else if (bx < nblk + GB8) {
        // ---- encoder: h0 = relu((x@encW+b)*bn_g*inv + bn_b); fp32 + bf16 ----
        int nb = (bx - nblk) * 8;
        if (t < 64) {
            size_t idx = (size_t)nb * NF + t;
            xs[t] = (idx < (size_t)N * NF) ? x[idx] : 0.f;
        }
        __syncthreads();
        int jt = t & 31, i = t >> 5;
        int node = nb + i;
        int j4 = jt * 4;
        float ax = 0.f, ay = 0.f, az = 0.f, aw = 0.f;
#pragma unroll
        for (int k = 0; k < NF; ++k) {
            float hx = xs[i * NF + k];
            const float4 w = *(const float4*)(encW + k * H + j4);
            ax = fmaf(hx, w.x, ax); ay = fmaf(hx, w.y, ay);
            az = fmaf(hx, w.z, az); aw = fmaf(hx, w.w, aw);
        }
        if (node < N) {
            const float inv = 0.9999950000374997f;  // 1/sqrt(1+1e-5)
            const float4 eb = *(const float4*)(encb + j4);
            const float4 gg = *(const float4*)(bng + j4);
            const float4 bb = *(const float4*)(bnb + j4);
            float4 o;
            o.x = fmaxf(0.f, (ax + eb.x) * (gg.x * inv) + bb.x);
            o.y = fmaxf(0.f, (ay + eb.y) * (gg.y * inv) + bb.y);
            o.z = fmaxf(0.f, (az + eb.z) * (gg.z * inv) + bb.z);
            o.w = fmaxf(0.f, (aw + eb.w) * (gg.w * inv) + bb.w);
            *(float4*)(h0 + (size_t)node * H + j4) = o;
            uint2 ob;
            ob.x = (uint)f2bf(o.x) | ((uint)f2bf(o.y) << 16);
            ob.y = (uint)f2bf(o.z) | ((uint)f2bf(o.w) << 16);
            *(uint2*)(hb + (size_t)node * H + j4) = ob;
        }
    } else {
        // ---- W fragment packer: Wp[layer][nt][kt][lane][8] bf16 ----
        int layer = bx - nblk - GB8;
        const float* W = (layer == 0) ? W1 : ((layer == 1) ? W2 : W3);
        for (int idx = t; idx < 16384; idx += 256) {
            int i = idx & 7;
            int lane = (idx >> 3) & 63;
            int ft = idx >> 9;
            int kt = ft & 3, nt = ft >> 2;
            int k = kt * 32 + (lane >> 4) * 8 + i;
            int n = nt * 16 + (lane & 15);
            Wp[layer * 16384 + idx] = f2bf(W[k * H + n]);
        }
    }
}

// ---- scan + park (1 block) -------------------------------------------------
__global__ void k_scan_park(const int* __restrict__ bucketTotal, int nbuckets,
                            int* __restrict__ bucketBase, int* __restrict__ rowptr,
                            int N, int E, const float2* __restrict__ pmean, int nblk,
                            float invE,
                            const float* __restrict__ We1, const float* __restrict__ ae1,
                            const float* __restrict__ We2, const float* __restrict__ ae2,
                            const float* __restrict__ We3, const float* __restrict__ ae3,
                            float* __restrict__ park) {
    __shared__ int tmp[256];
    __shared__ float2 sp[4];
    __shared__ float smean[2];
    int t = threadIdx.x;  // 256
    float ax = 0.f, ay = 0.f;
    for (int i = t; i < nblk; i += 256) {
        float2 z = pmean[i];
        ax += z.x; ay += z.y;
    }
    ax = wred_sum(ax); ay = wred_sum(ay);
    if ((t & 63) == 0) sp[t >> 6] = make_float2(ax, ay);
    int v = (t < nbuckets) ? bucketTotal[t] : 0;
    tmp[t] = v;
    __syncthreads();
    for (int off = 1; off < 256; off <<= 1) {
        int q = (t >= off) ? tmp[t - off] : 0;
        __syncthreads();
        tmp[t] += q;
        __syncthreads();
    }
    bucketBase[t] = tmp[t] - v;  // exclusive; entries >= nbuckets hold E
    if (t == 0) {
        bucketBase[256] = tmp[255];  // == E
        rowptr[N] = E;
        smean[0] = (sp[0].x + sp[1].x + sp[2].x + sp[3].x) * invE;
        smean[1] = (sp[0].y + sp[1].y + sp[2].y + sp[3].y) * invE;
    }
    __syncthreads();
    if (t < 192) {
        int l = t >> 6, q = t & 63;
        const float* We = (l == 0) ? We1 : ((l == 1) ? We2 : We3);
        const float* ae = (l == 0) ? ae1 : ((l == 1) ? ae2 : ae3);
        float p0 = We[q] * ae[q] + We[q + 64] * ae[q + 64];
        float p1 = We[H + q] * ae[q] + We[H + q + 64] * ae[q + 64];
        p0 = wred_sum(p0);
        p1 = wred_sum(p1);
        if (q == 0) {
            park[l * 3 + 0] = p0;
            park[l * 3 + 1] = p1;
            park[l * 3 + 2] = smean[0] * p0 + smean[1] * p1;
        }
    }
}

// ---- Kernel B: place || gemm(layer 1) (independent roles) ------------------
__global__ void k_fusedB(const int* __restrict__ ei, const float* __restrict__ ea,
                         int E, int nblk, int nbuckets,
                         const int* __restrict__ bucketBase, const int* __restrict__ blockBase,
                         uint2* __restrict__ temp,
                         const ushort* __restrict__ hb, const ushort* __restrict__ Wp,
                         const float* __restrict__ avs, const float* __restrict__ avd,
                         ushort* __restrict__ gb, float* __restrict__ a_src,
                         float* __restrict__ a_dst, int N) {
    __shared__ int cnt[256];
    __shared__ int sbase[256];
    __shared__ ushort hs[64 * 136];
    const int tid = threadIdx.x;  // 256

    if (blockIdx.x < nblk) {
        // ---- place ----
        int blk = blockIdx.x;
        cnt[tid] = 0;
        if (tid < nbuckets) sbase[tid] = bucketBase[tid] + blockBase[tid * nblk + blk];
        __syncthreads();
        int base = blk * EPB;
#pragma unroll
        for (int i = 0; i < 16; ++i) {
            int e = base + i * 256 + tid;
            if (e < E) {
                int s = ei[e];          // s < 65536 (N=50000)
                int d = ei[E + e];
                int b = d >> 8;
                int r = atomicAdd(&cnt[b], 1);
                const float2 z = *(const float2*)(ea + 2 * (size_t)e);
                uint w0 = (uint)s | ((uint)(d & 255) << 16);
                uint w1 = (uint)f2bf(z.x) | ((uint)f2bf(z.y) << 16);
                temp[sbase[b] + r] = make_uint2(w0, w1);
            }
        }
        return;
    }

    // ---- gemm layer 1: g = hb @ Wp, MFMA 16x16x32 bf16 ----
    int nb = (blockIdx.x - nblk) * 64;
#pragma unroll
    for (int it = 0; it < 4; ++it) {
        int fi = it * 256 + tid;
        int r = fi >> 4;
        int c8 = (fi & 15) * 8;
        int node = nb + r;
        uint4 v = make_uint4(0, 0, 0, 0);
        if (node < N) v = *(const uint4*)(hb + (size_t)node * H + c8);
        *(uint4*)(hs + r * 136 + c8) = v;
    }
    __syncthreads();
    const int l = tid & 63;
    const int w = tid >> 6;
    const int cl = l & 15;
    const int kg = l >> 4;
    const ushort* hrow = hs + (w * 16 + cl) * 136 + kg * 8;
    short8v a0 = *(const short8v*)(hrow + 0);
    short8v a1 = *(const short8v*)(hrow + 32);
    short8v a2 = *(const short8v*)(hrow + 64);
    short8v a3 = *(const short8v*)(hrow + 96);

    f32x4 acc[8];
#pragma unroll
    for (int nt = 0; nt < 8; ++nt) {
        const short8v* bp = (const short8v*)(Wp + ((size_t)(nt * 4) * 64 + l) * 8);
        f32x4 c = {0.f, 0.f, 0.f, 0.f};
        c = __builtin_amdgcn_mfma_f32_16x16x32_bf16(a0, bp[0], c, 0, 0, 0);
        c = __builtin_amdgcn_mfma_f32_16x16x32_bf16(a1, bp[64], c, 0, 0, 0);
        c = __builtin_amdgcn_mfma_f32_16x16x32_bf16(a2, bp[128], c, 0, 0, 0);
        c = __builtin_amdgcn_mfma_f32_16x16x32_bf16(a3, bp[192], c, 0, 0, 0);
        acc[nt] = c;
    }

    float ps0 = 0.f, ps1 = 0.f, ps2 = 0.f, ps3 = 0.f;
    float pd0 = 0.f, pd1 = 0.f, pd2 = 0.f, pd3 = 0.f;
#pragma unroll
    for (int nt = 0; nt < 8; ++nt) {
        float vs = avs[cl + 16 * nt];
        float vd = avd[cl + 16 * nt];
        ps0 = fmaf(acc[nt].x, vs, ps0); pd0 = fmaf(acc[nt].x, vd, pd0);
        ps1 = fmaf(acc[nt].y, vs, ps1); pd1 = fmaf(acc[nt].y, vd, pd1);
        ps2 = fmaf(acc[nt].z, vs, ps2); pd2 = fmaf(acc[nt].z, vd, pd2);
        ps3 = fmaf(acc[nt].w, vs, ps3); pd3 = fmaf(acc[nt].w, vd, pd3);
    }
#pragma unroll
    for (int m = 8; m >= 1; m >>= 1) {
        ps0 += __shfl_xor(ps0, m, 64); pd0 += __shfl_xor(pd0, m, 64);
        ps1 += __shfl_xor(ps1, m, 64); pd1 += __shfl_xor(pd1, m, 64);
        ps2 += __shfl_xor(ps2, m, 64); pd2 += __shfl_xor(pd2, m, 64);
        ps3 += __shfl_xor(ps3, m, 64); pd3 += __shfl_xor(pd3, m, 64);
    }
    int r0 = nb + w * 16 + kg * 4;
    if (cl == 0) {
        if (r0 + 0 < N) { a_src[r0 + 0] = ps0; a_dst[r0 + 0] = pd0; }
        if (r0 + 1 < N) { a_src[r0 + 1] = ps1; a_dst[r0 + 1] = pd1; }
        if (r0 + 2 < N) { a_src[r0 + 2] = ps2; a_dst[r0 + 2] = pd2; }
        if (r0 + 3 < N) { a_src[r0 + 3] = ps3; a_dst[r0 + 3] = pd3; }
    }
#pragma unroll
    for (int nt = 0; nt < 8; ++nt) {
        int col = nt * 16 + cl;
        if (r0 + 0 < N) gb[(size_t)(r0 + 0) * H + col] = f2bf(acc[nt].x);
        if (r0 + 1 < N) gb[(size_t)(r0 + 1) * H + col] = f2bf(acc[nt].y);
        if (r0 + 2 < N) gb[(size_t)(r0 + 2) * H + col] = f2bf(acc[nt].z);
        if (r0 + 3 < N) gb[(size_t)(r0 + 3) * H + col] = f2bf(acc[nt].w);
    }
}

// K4: per-bucket fine CSR; emit rowptr + 3 per-layer 4B records {src, bf16 ae}
__global__ void k_fine(const uint2* __restrict__ temp, const int* __restrict__ bucketBase,
                       const float* __restrict__ park, int N,
                       uint* __restrict__ er0, uint* __restrict__ er1,
                       uint* __restrict__ er2, int* __restrict__ rowptr) {
    __shared__ int hist[256];
    __shared__ int tmp[256];
    __shared__ int fb[256];
    __shared__ int cur[256];
    int b = blockIdx.x;
    int t = threadIdx.x;  // 256
    const int lo = bucketBase[b], hi = bucketBase[b + 1];
    hist[t] = 0;
    __syncthreads();
    for (int e = lo + t; e < hi; e += 256) {
        atomicAdd(&hist[(temp[e].x >> 16) & 255], 1);
    }
    __syncthreads();
    int v = hist[t];
    tmp[t] = v;
    __syncthreads();
    for (int off = 1; off < 256; off <<= 1) {
        int q = (t >= off) ? tmp[t - off] : 0;
        __syncthreads();
        tmp[t] += q;
        __syncthreads();
    }
    fb[t] = tmp[t] - v;  // exclusive within bucket
    cur[t] = 0;
    int dst = b * 256 + t;
    if (dst < N) rowptr[dst] = lo + fb[t];
    __syncthreads();
    const float c00 = park[0], c01 = park[1];
    const float c10 = park[3], c11 = park[4];
    const float c20 = park[6], c21 = park[7];
    for (int e = lo + t; e < hi; e += 256) {
        uint2 w = temp[e];
        uint src = w.x & 0xFFFFu;
        int j = (int)((w.x >> 16) & 255u);
        float ex = __uint_as_float(w.y << 16);
        float ey = __uint_as_float(w.y & 0xffff0000u);
        int r = atomicAdd(&cur[j], 1);
        int p = lo + fb[j] + r;
        er0[p] = src | ((uint)f2bf(c00 * ex + c01 * ey) << 16);
        er1[p] = src | ((uint)f2bf(c10 * ex + c11 * ey) << 16);
        er2[p] = src | ((uint)f2bf(c20 * ex + c21 * ey) << 16);
    }
}

// ---- per-layer GEMM (standalone, layers 2/3) -------------------------------
__global__ void k_gemm_mfma(const ushort* __restrict__ hb, const ushort* __restrict__ Wp,
                            const float* __restrict__ avs, const float* __restrict__ avd,
                            ushort* __restrict__ gb, float* __restrict__ a_src,
                            float* __restrict__ a_dst, int N) {
    __shared__ ushort hs[64 * 136];
    int tid = threadIdx.x;
    int nb = blockIdx.x * 64;
#pragma unroll
    for (int it = 0; it < 4; ++it) {
        int fi = it * 256 + tid;
        int r = fi >> 4;
        int c8 = (fi & 15) * 8;
        int node = nb + r;
        uint4 v = make_uint4(0, 0, 0, 0);
        if (node < N) v = *(const uint4*)(hb + (size_t)node * H + c8);
        *(uint4*)(hs + r * 136 + c8) = v;
    }
    __syncthreads();
    const int l = tid & 63;
    const int w = tid >> 6;
    const int cl = l & 15;
    const int kg = l >> 4;
    const ushort* hrow = hs + (w * 16 + cl) * 136 + kg * 8;
    short8v a0 = *(const short8v*)(hrow + 0);
    short8v a1 = *(const short8v*)(hrow + 32);
    short8v a2 = *(const short8v*)(hrow + 64);
    short8v a3 = *(const short8v*)(hrow + 96);

    f32x4 acc[8];
#pragma unroll
    for (int nt = 0; nt < 8; ++nt) {
        const short8v* bp = (const short8v*)(Wp + ((size_t)(nt * 4) * 64 + l) * 8);
        f32x4 c = {0.f, 0.f, 0.f, 0.f};
        c = __builtin_amdgcn_mfma_f32_16x16x32_bf16(a0, bp[0], c, 0, 0, 0);
        c = __builtin_amdgcn_mfma_f32_16x16x32_bf16(a1, bp[64], c, 0, 0, 0);
        c = __builtin_amdgcn_mfma_f32_16x16x32_bf16(a2, bp[128], c, 0, 0, 0);
        c = __builtin_amdgcn_mfma_f32_16x16x32_bf16(a3, bp[192], c, 0, 0, 0);
        acc[nt] = c;
    }

    float ps0 = 0.f, ps1 = 0.f, ps2 = 0.f, ps3 = 0.f;
    float pd0 = 0.f, pd1 = 0.f, pd2 = 0.f, pd3 = 0.f;
#pragma unroll
    for (int nt = 0; nt < 8; ++nt) {
        float vs = avs[cl + 16 * nt];
        float vd = avd[cl + 16 * nt];
        ps0 = fmaf(acc[nt].x, vs, ps0); pd0 = fmaf(acc[nt].x, vd, pd0);
        ps1 = fmaf(acc[nt].y, vs, ps1); pd1 = fmaf(acc[nt].y, vd, pd1);
        ps2 = fmaf(acc[nt].z, vs, ps2); pd2 = fmaf(acc[nt].z, vd, pd2);
        ps3 = fmaf(acc[nt].w, vs, ps3); pd3 = fmaf(acc[nt].w, vd, pd3);
    }
#pragma unroll
    for (int m = 8; m >= 1; m >>= 1) {
        ps0 += __shfl_xor(ps0, m, 64); pd0 += __shfl_xor(pd0, m, 64);
        ps1 += __shfl_xor(ps1, m, 64); pd1 += __shfl_xor(pd1, m, 64);
        ps2 += __shfl_xor(ps2, m, 64); pd2 += __shfl_xor(pd2, m, 64);
        ps3 += __shfl_xor(ps3, m, 64); pd3 += __shfl_xor(pd3, m, 64);
    }
    int r0 = nb + w * 16 + kg * 4;
    if (cl == 0) {
        if (r0 + 0 < N) { a_src[r0 + 0] = ps0; a_dst[r0 + 0] = pd0; }
        if (r0 + 1 < N) { a_src[r0 + 1] = ps1; a_dst[r0 + 1] = pd1; }
        if (r0 + 2 < N) { a_src[r0 + 2] = ps2; a_dst[r0 + 2] = pd2; }
        if (r0 + 3 < N) { a_src[r0 + 3] = ps3; a_dst[r0 + 3] = pd3; }
    }
#pragma unroll
    for (int nt = 0; nt < 8; ++nt) {
        int col = nt * 16 + cl;
        if (r0 + 0 < N) gb[(size_t)(r0 + 0) * H + col] = f2bf(acc[nt].x);
        if (r0 + 1 < N) gb[(size_t)(r0 + 1) * H + col] = f2bf(acc[nt].y);
        if (r0 + 2 < N) gb[(size_t)(r0 + 2) * H + col] = f2bf(acc[nt].z);
        if (r0 + 3 < N) gb[(size_t)(r0 + 3) * H + col] = f2bf(acc[nt].w);
    }
}

// ---- aggregation: wave per node, online softmax, pipelined 16B gather ------
// MODE 0: relu, bf16 out (hidden layers). MODE 1: +h0 residual, fp32 out.
template <int MODE>
__global__ void k_agg(const ushort* __restrict__ gb, const float* __restrict__ a_src,
                      const float* __restrict__ a_dst, const int* __restrict__ rowptr,
                      const uint* __restrict__ erecL, const float* __restrict__ park,
                      int layer, const float* __restrict__ bias,
                      const float* __restrict__ h0, float* __restrict__ outf,
                      ushort* __restrict__ outb, int N) {
    int wv = threadIdx.x >> 6;
    int lane = threadIdx.x & 63;
    int v = blockIdx.x * 4 + wv;
    if (v >= N) return;

    const int grp = lane >> 4;   // which of 4 edge-slots this lane serves
    const int sub = lane & 15;   // position within the 256B row
    const int ch8 = sub * 8;     // 8 bf16 channels per lane

    const float sa = park[layer * 3 + 2];
    const float adv = a_dst[v];
    float lself = a_src[v] + adv + sa;
    lself = (lself > 0.f) ? lself : 0.2f * lself;

    float m = lself;   // running max (self-loop included)
    float s = 1.f;     // running sum, w_self = exp(0) = 1
    f32x2 acc2[4];
    {
        const uint4 q = *(const uint4*)(gb + (size_t)v * H + ch8);
        float sel = (grp == 0) ? 1.f : 0.f;  // self contribution counted once
        acc2[0] = bfpair(q.x) * sel;
        acc2[1] = bfpair(q.y) * sel;
        acc2[2] = bfpair(q.z) * sel;
        acc2[3] = bfpair(q.w) * sel;
    }

    const int rs = rowptr[v];
    const int re = rowptr[v + 1];
    for (int p0 = rs; p0 < re; p0 += 64) {
        int e = p0 + lane;
        bool val = e < re;
        uint rec = val ? __builtin_nontemporal_load(erecL + e) : 0u;
        int sv = (int)(rec & 0xFFFFu);
        float lg;
        if (val) {
            float aef = __uint_as_float(rec & 0xffff0000u);
            lg = a_src[sv] + adv + aef;
            lg = (lg > 0.f) ? lg : 0.2f * lg;
        } else {
            lg = -INFINITY;
        }
        float cm = wred_max(lg);
        float nm = fmaxf(m, cm);
        float f = __expf(m - nm);
        float w = val ? __expf(lg - nm) : 0.f;
        float ws = wred_sum(w);
        s = s * f + ws;
#pragma unroll
        for (int k = 0; k < 4; ++k) acc2[k] *= f;
        m = nm;

        int cnt = re - p0;
        if (cnt > 64) cnt = 64;
        const int cm1 = cnt - 1;
        const int iters = (cnt + 7) >> 3;  // 8 edges per super-iteration

        int jA = grp, jB = grp + 4;
        int jAc = (jA <= cm1) ? jA : cm1;
        int jBc = (jB <= cm1) ? jB : cm1;
        float wA = __shfl(w, jAc, 64); if (jA > cm1) wA = 0.f;
        float wB = __shfl(w, jBc, 64); if (jB > cm1) wB = 0.f;
        int sA = __shfl(sv, jAc, 64);
        int sB = __shfl(sv, jBc, 64);
        uint4 qA = *(const uint4*)(gb + (size_t)sA * H + ch8);
        uint4 qB = *(const uint4*)(gb + (size_t)sB * H + ch8);

        for (int i = 0; i < iters; ++i) {
            int jA1 = (i + 1) * 8 + grp, jB1 = jA1 + 4;
            int jA1c = (jA1 <= cm1) ? jA1 : cm1;
            int jB1c = (jB1 <= cm1) ? jB1 : cm1;
            float wA1 = __shfl(w, jA1c, 64); if (jA1 > cm1) wA1 = 0.f;
            float wB1 = __shfl(w, jB1c, 64); if (jB1 > cm1) wB1 = 0.f;
            int sA1 = __shfl(sv, jA1c, 64);
            int sB1 = __shfl(sv, jB1c, 64);
            uint4 qA1 = *(const uint4*)(gb + (size_t)sA1 * H + ch8);
            uint4 qB1 = *(const uint4*)(gb + (size_t)sB1 * H + ch8);

            f32x2 wAv = {wA, wA};
            f32x2 wBv = {wB, wB};
            acc2[0] = __builtin_elementwise_fma(wAv, bfpair(qA.x), acc2[0]);
            acc2[1] = __builtin_elementwise_fma(wAv, bfpair(qA.y), acc2[1]);
            acc2[2] = __builtin_elementwise_fma(wAv, bfpair(qA.z), acc2[2]);
            acc2[3] = __builtin_elementwise_fma(wAv, bfpair(qA.w), acc2[3]);
            acc2[0] = __builtin_elementwise_fma(wBv, bfpair(qB.x), acc2[0]);
            acc2[1] = __builtin_elementwise_fma(wBv, bfpair(qB.y), acc2[1]);
            acc2[2] = __builtin_elementwise_fma(wBv, bfpair(qB.z), acc2[2]);
            acc2[3] = __builtin_elementwise_fma(wBv, bfpair(qB.w), acc2[3]);

            wA = wA1; wB = wB1; qA = qA1; qB = qB1;
        }
    }

    float acc[8];
    acc[0] = acc2[0].x; acc[1] = acc2[0].y;
    acc[2] = acc2[1].x; acc[3] = acc2[1].y;
    acc[4] = acc2[2].x; acc[5] = acc2[2].y;
    acc[6] = acc2[3].x; acc[7] = acc2[3].y;
#pragma unroll
    for (int k = 0; k < 8; ++k) {
        acc[k] += __shfl_xor(acc[k], 16, 64);
        acc[k] += __shfl_xor(acc[k], 32, 64);
    }

    if (grp == 0) {
        const float is = 1.f / s;
        const float4 b0 = *(const float4*)(bias + ch8);
        const float4 b1 = *(const float4*)(bias + ch8 + 4);
        float o[8];
        o[0] = acc[0] * is + b0.x; o[1] = acc[1] * is + b0.y;
        o[2] = acc[2] * is + b0.z; o[3] = acc[3] * is + b0.w;
        o[4] = acc[4] * is + b1.x; o[5] = acc[5] * is + b1.y;
        o[6] = acc[6] * is + b1.z; o[7] = acc[7] * is + b1.w;
        if (MODE == 0) {
#pragma unroll
            for (int k = 0; k < 8; ++k) o[k] = fmaxf(o[k], 0.f);
            uint4 ob;
            ob.x = (uint)f2bf(o[0]) | ((uint)f2bf(o[1]) << 16);
            ob.y = (uint)f2bf(o[2]) | ((uint)f2bf(o[3]) << 16);
            ob.z = (uint)f2bf(o[4]) | ((uint)f2bf(o[5]) << 16);
            ob.w = (uint)f2bf(o[6]) | ((uint)f2bf(o[7]) << 16);
            *(uint4*)(outb + (size_t)v * H + ch8) = ob;
        } else {
            const float4 ha = *(const float4*)(h0 + (size_t)v * H + ch8);
            const float4 hb4 = *(const float4*)(h0 + (size_t)v * H + ch8 + 4);
            o[0] += ha.x; o[1] += ha.y; o[2] += ha.z; o[3] += ha.w;
            o[4] += hb4.x; o[5] += hb4.y; o[6] += hb4.z; o[7] += hb4.w;
            *(float4*)(outf + (size_t)v * H + ch8) = make_float4(o[0], o[1], o[2], o[3]);
            *(float4*)(outf + (size_t)v * H + ch8 + 4) = make_float4(o[4], o[5], o[6], o[7]);
        }
    }
}

// ---------------------------------------------------------------------------

extern "C" void kernel_launch(void* const* d_in, const int* in_sizes, int n_in,
                              void* d_out, int out_size, void* d_ws, size_t ws_size,
                              hipStream_t stream) {
    const float* x    = (const float*)d_in[0];
    const int*   ei   = (const int*)d_in[1];
    const float* ea   = (const float*)d_in[2];
    const float* encW = (const float*)d_in[3];
    const float* encb = (const float*)d_in[4];
    const float* bng  = (const float*)d_in[5];
    const float* bnb  = (const float*)d_in[6];
    const float *W[3], *asrc[3], *adst[3], *We[3], *aev[3], *bias[3];
    for (int l = 0; l < 3; ++l) {
        W[l]    = (const float*)d_in[7 + l * 6 + 0];
        asrc[l] = (const float*)d_in[7 + l * 6 + 1];
        adst[l] = (const float*)d_in[7 + l * 6 + 2];
        We[l]   = (const float*)d_in[7 + l * 6 + 3];
        aev[l]  = (const float*)d_in[7 + l * 6 + 4];
        bias[l] = (const float*)d_in[7 + l * 6 + 5];
    }
    const int N = in_sizes[0] / NF;   // 50000 (< 65536: src packs in 16 bits)
    const int E = in_sizes[1] / 2;
    float* out = (float*)d_out;

    const int NBu  = (N + 255) >> 8;          // coarse buckets (196)
    const int nblk = (E + EPB - 1) / EPB;     // count/place blocks (391)
    const int GB8  = (N + 7) / 8;             // encoder blocks (6250)
    const int GBM  = (N + 63) / 64;           // gemm blocks (782)
    const int AB   = (N + 3) / 4;             // agg blocks

    // workspace carve-up (256B aligned)
    char* wp = (char*)d_ws;
    auto alloc = [&](size_t bytes) -> char* {
        char* p = wp;
        wp += (bytes + 255) & ~(size_t)255;
        return p;
    };
    float*  h0       = (float*)alloc((size_t)N * H * 4);
    ushort* hb       = (ushort*)alloc((size_t)N * H * 2);
    ushort* gb       = (ushort*)alloc((size_t)N * H * 2);
    ushort* Wp       = (ushort*)alloc((size_t)3 * 16384 * 2);
    float*  a_src    = (float*)alloc((size_t)N * 4);
    float*  a_dst    = (float*)alloc((size_t)N * 4);
    int*    rowptr   = (int*)alloc((size_t)(N + 1) * 4);
    float*  park     = (float*)alloc(64);
    int*    bucketTotal = (int*)alloc(256 * 4);
    int*    bucketBase  = (int*)alloc(257 * 4);
    int*    blockBase   = (int*)alloc((size_t)NBu * nblk * 4);
    uint*   er0      = (uint*)alloc((size_t)E * 4);
    uint*   er1      = (uint*)alloc((size_t)E * 4);
    uint*   er2      = (uint*)alloc((size_t)E * 4);
    float2* pmean    = (float2*)alloc((size_t)nblk * 8);
    uint2*  temp     = (uint2*)alloc((size_t)E * 8);  // own slot (h0 now live early)

    hipMemsetAsync(bucketTotal, 0, 256 * 4, stream);

    // A: count || encoder || wpack
    k_fusedA<<<nblk + GB8 + 3, 256, 0, stream>>>(
        ei, ea, E, nblk, NBu, bucketTotal, blockBase, pmean,
        x, encW, encb, bng, bnb, h0, hb, N, GB8,
        W[0], W[1], W[2], Wp);
    k_scan_park<<<1, 256, 0, stream>>>(bucketTotal, NBu, bucketBase, rowptr, N, E,
                                       pmean, nblk, 1.0f / (float)E,
                                       We[0], aev[0], We[1], aev[1], We[2], aev[2], park);
    // B: place || gemm layer 1
    k_fusedB<<<nblk + GBM, 256, 0, stream>>>(
        ei, ea, E, nblk, NBu, bucketBase, blockBase, temp,
        hb, Wp + 0 * 16384, asrc[0], adst[0], gb, a_src, a_dst, N);
    k_fine<<<NBu, 256, 0, stream>>>(temp, bucketBase, park, N, er0, er1, er2, rowptr);

    // layer 1 aggregate: gb -> hb
    k_agg<0><<<AB, 256, 0, stream>>>(gb, a_src, a_dst, rowptr, er0, park, 0,
                                     bias[0], nullptr, nullptr, hb, N);
    // layer 2
    k_gemm_mfma<<<GBM, 256, 0, stream>>>(hb, Wp + 1 * 16384, asrc[1], adst[1],
                                         gb, a_src, a_dst, N);
    k_agg<0><<<AB, 256, 0, stream>>>(gb, a_src, a_dst, rowptr, er1, park, 1,
                                     bias[1], nullptr, nullptr, hb, N);
    // layer 3: out = agg + h0 (fp32)
    k_gemm_mfma<<<GBM, 256, 0, stream>>>(hb, Wp + 2 * 16384, asrc[2], adst[2],
                                         gb, a_src, a_dst, N);
    k_agg<1><<<AB, 256, 0, stream>>>(gb, a_src, a_dst, rowptr, er2, park, 2,
                                     bias[2], h0, out, nullptr, N);
}